// Round 1
// baseline (4352.331 us; speedup 1.0000x reference)
//
#include <hip/hip_runtime.h>
#include <float.h>

constexpr int NB   = 8;      // batches
constexpr int NP   = 2048;   // points per batch
constexpr int BN   = NB * NP;
constexpr int KNN  = 20;     // neighbors
constexpr int FSTR = 512;    // feats row stride (64+64+128+256)

// ---------------------------------------------------------------- sq = |h|^2
template<int C>
__global__ __launch_bounds__(256) void sq_kernel(const float* __restrict__ h,
                                                 int istr,
                                                 float* __restrict__ sq) {
    int i = blockIdx.x * 256 + threadIdx.x;
    if (i >= BN) return;
    const float* p = h + (size_t)i * istr;
    float s = 0.f;
    #pragma unroll
    for (int c = 0; c < C; ++c) { float v = p[c]; s += v * v; }
    sq[i] = s;
}

// ---------------------------------------------------------------- kNN top-20
// Block handles GI=4 rows of one batch. Phase A: neg_d row into LDS.
// Phase B: each wave does 20x argmax (min-index tie-break) for its row.
template<int C>
__global__ __launch_bounds__(256) void knn_kernel(const float* __restrict__ h,
                                                  int istr,
                                                  const float* __restrict__ sq,
                                                  int* __restrict__ knn_idx) {
    constexpr int GI = 4;
    __shared__ float negd[GI][NP];          // 32 KB
    const int t    = threadIdx.x;
    const int r0   = blockIdx.x * GI;       // first global row of block
    const int base = (r0 >> 11) << 11;      // batch base row (NP = 2048)

    if constexpr (C == 3) {
        float hi[GI][3], sqi[GI];
        #pragma unroll
        for (int g = 0; g < GI; ++g) {
            const float* p = h + (size_t)(r0 + g) * istr;
            hi[g][0] = p[0]; hi[g][1] = p[1]; hi[g][2] = p[2];
            sqi[g] = sq[r0 + g];
        }
        for (int j = t; j < NP; j += 256) {
            const float* pj = h + (size_t)(base + j) * istr;
            float x0 = pj[0], x1 = pj[1], x2 = pj[2];
            float sqj = sq[base + j];
            #pragma unroll
            for (int g = 0; g < GI; ++g) {
                float d = hi[g][0]*x0 + hi[g][1]*x1 + hi[g][2]*x2;
                negd[g][j] = 2.f * d - sqi[g] - sqj;
            }
        }
    } else {
        constexpr int CQ   = C / 4;         // per-quarter channels
        constexpr int QSTR = CQ + 4;        // padded quarter stride (x4 floats, 16B aligned)
        constexpr int GSTR = 4 * QSTR;
        __shared__ float hi_s[GI * GSTR];
        for (int e = t; e < GI * C; e += 256) {
            int g = e / C, c = e - g * C;
            int q = c / CQ, cc = c - q * CQ;
            hi_s[g * GSTR + q * QSTR + cc] = h[(size_t)(r0 + g) * istr + c];
        }
        float sqi[GI];
        #pragma unroll
        for (int g = 0; g < GI; ++g) sqi[g] = sq[r0 + g];
        __syncthreads();

        const int jl = t >> 2;              // 0..63 : neighbor within tile
        const int q  = t & 3;               // channel quarter
        for (int jt = 0; jt < NP; jt += 64) {
            const float* pj = h + (size_t)(base + jt + jl) * istr + q * CQ;
            float4 hj[CQ / 4];
            #pragma unroll
            for (int u = 0; u < CQ / 4; ++u) hj[u] = *(const float4*)(pj + 4 * u);
            float p[GI];
            #pragma unroll
            for (int g = 0; g < GI; ++g) {
                const float* hs = &hi_s[g * GSTR + q * QSTR];
                float s = 0.f;
                #pragma unroll
                for (int u = 0; u < CQ / 4; ++u) {
                    float4 a = *(const float4*)(hs + 4 * u);
                    s += a.x*hj[u].x + a.y*hj[u].y + a.z*hj[u].z + a.w*hj[u].w;
                }
                p[g] = s;
            }
            #pragma unroll
            for (int g = 0; g < GI; ++g) {
                p[g] += __shfl_xor(p[g], 1);
                p[g] += __shfl_xor(p[g], 2);
            }
            if (q == 0) {
                int j = jt + jl;
                float sqj = sq[base + j];
                #pragma unroll
                for (int g = 0; g < GI; ++g)
                    negd[g][j] = 2.f * p[g] - sqi[g] - sqj;
            }
        }
    }
    __syncthreads();

    // ---- phase B: wave w owns row w
    const int w = t >> 6;
    const int l = t & 63;
    float* row = &negd[w][0];
    for (int it = 0; it < KNN; ++it) {
        float bv = -FLT_MAX; int bi = NP;
        for (int j = l; j < NP; j += 64) {
            float v = row[j];
            if (v > bv) { bv = v; bi = j; }
        }
        #pragma unroll
        for (int off = 1; off < 64; off <<= 1) {
            float ov = __shfl_xor(bv, off);
            int   oi = __shfl_xor(bi, off);
            if (ov > bv || (ov == bv && oi < bi)) { bv = ov; bi = oi; }
        }
        if (l == 0) knn_idx[(size_t)(r0 + w) * KNN + it] = bi;
        if (l == (bi & 63)) row[bi] = -FLT_MAX;   // owner lane marks; same lane rescans it
    }
}

// ---------------------------------------------------------------- EdgeConv
// out[i][o] = lrelu( max_k ( W[o,0:C]·(h_j - h_i) + W[o,C:2C]·h_i + b[o] ) )
template<int CIN, int COUT>
__global__ __launch_bounds__(64) void edge_kernel(const float* __restrict__ hin,
                                                  int istr,
                                                  const float* __restrict__ W,
                                                  const float* __restrict__ bias,
                                                  const int* __restrict__ knn_idx,
                                                  float* __restrict__ hout) {
    constexpr int OPT = COUT / 64;
    __shared__ float diff[KNN][CIN];
    __shared__ float hi[CIN];
    __shared__ int   nj[KNN];
    const int t    = threadIdx.x;
    const int r    = blockIdx.x;
    const int base = (r >> 11) << 11;

    if (t < KNN) nj[t] = knn_idx[(size_t)r * KNN + t];
    for (int c = t; c < CIN; c += 64) hi[c] = hin[(size_t)r * istr + c];
    __syncthreads();
    for (int e = t; e < KNN * CIN; e += 64) {
        int kk = e / CIN, c = e - kk * CIN;
        int j = nj[kk];
        diff[kk][c] = hin[(size_t)(base + j) * istr + c] - hi[c];
    }
    __syncthreads();

    float ctr[OPT];
    #pragma unroll
    for (int qq = 0; qq < OPT; ++qq) {
        int o = t + 64 * qq;
        float s = bias[o];
        for (int c = 0; c < CIN; ++c)
            s += W[(size_t)o * (2 * CIN) + CIN + c] * hi[c];
        ctr[qq] = s;
    }

    float acc[OPT][KNN];
    #pragma unroll
    for (int qq = 0; qq < OPT; ++qq)
        #pragma unroll
        for (int kk = 0; kk < KNN; ++kk) acc[qq][kk] = 0.f;

    if constexpr (CIN % 4 == 0) {
        for (int c = 0; c < CIN; c += 4) {
            float4 wv[OPT];
            #pragma unroll
            for (int qq = 0; qq < OPT; ++qq)
                wv[qq] = *(const float4*)&W[(size_t)(t + 64 * qq) * (2 * CIN) + c];
            #pragma unroll
            for (int kk = 0; kk < KNN; ++kk) {
                float4 d = *(const float4*)&diff[kk][c];
                #pragma unroll
                for (int qq = 0; qq < OPT; ++qq)
                    acc[qq][kk] += wv[qq].x*d.x + wv[qq].y*d.y + wv[qq].z*d.z + wv[qq].w*d.w;
            }
        }
    } else {
        for (int c = 0; c < CIN; ++c) {
            float wv[OPT];
            #pragma unroll
            for (int qq = 0; qq < OPT; ++qq)
                wv[qq] = W[(size_t)(t + 64 * qq) * (2 * CIN) + c];
            #pragma unroll
            for (int kk = 0; kk < KNN; ++kk) {
                float d = diff[kk][c];
                #pragma unroll
                for (int qq = 0; qq < OPT; ++qq) acc[qq][kk] += wv[qq] * d;
            }
        }
    }

    #pragma unroll
    for (int qq = 0; qq < OPT; ++qq) {
        float m = -FLT_MAX;
        #pragma unroll
        for (int kk = 0; kk < KNN; ++kk) m = fmaxf(m, acc[qq][kk] + ctr[qq]);
        float res = m > 0.f ? m : 0.2f * m;        // lrelu after max == max of lrelu
        hout[(size_t)r * FSTR + t + 64 * qq] = res;
    }
}

// ---------------------------------------------------------------- final GEMM + max over n
__global__ __launch_bounds__(256) void final_partial(const float* __restrict__ f,
                                                     const float* __restrict__ Wf,
                                                     float* __restrict__ partial) {
    __shared__ float fs[8][512];                 // 16 KB
    const int t = threadIdx.x;
    const int bx = blockIdx.x;                   // 0..511
    const int b = bx >> 6, chunk = bx & 63;
    const int n0 = chunk * 32;
    float mx[4] = {-FLT_MAX, -FLT_MAX, -FLT_MAX, -FLT_MAX};
    for (int sub = 0; sub < 4; ++sub) {
        for (int e = t; e < 8 * 128; e += 256) {
            int row = e >> 7, c4 = e & 127;
            *(float4*)&fs[row][c4 * 4] =
                *(const float4*)&f[((size_t)(b * NP + n0 + sub * 8 + row)) * FSTR + c4 * 4];
        }
        __syncthreads();
        float acc[4][8];
        #pragma unroll
        for (int q = 0; q < 4; ++q)
            #pragma unroll
            for (int n = 0; n < 8; ++n) acc[q][n] = 0.f;
        for (int c = 0; c < 512; c += 4) {
            float4 wv[4];
            #pragma unroll
            for (int q = 0; q < 4; ++q)
                wv[q] = *(const float4*)&Wf[(size_t)(t + 256 * q) * 512 + c];
            #pragma unroll
            for (int n = 0; n < 8; ++n) {
                float4 fv = *(const float4*)&fs[n][c];
                #pragma unroll
                for (int q = 0; q < 4; ++q)
                    acc[q][n] += wv[q].x*fv.x + wv[q].y*fv.y + wv[q].z*fv.z + wv[q].w*fv.w;
            }
        }
        #pragma unroll
        for (int q = 0; q < 4; ++q)
            #pragma unroll
            for (int n = 0; n < 8; ++n) mx[q] = fmaxf(mx[q], acc[q][n]);
        __syncthreads();
    }
    #pragma unroll
    for (int q = 0; q < 4; ++q)
        partial[(size_t)bx * 1024 + t + 256 * q] = mx[q];
}

__global__ __launch_bounds__(256) void final_reduce(const float* __restrict__ partial,
                                                    const float* __restrict__ bf,
                                                    float* __restrict__ out) {
    int g = blockIdx.x * 256 + threadIdx.x;      // 8192
    int b = g >> 10, o = g & 1023;
    float m = -FLT_MAX;
    for (int ch = 0; ch < 64; ++ch)
        m = fmaxf(m, partial[((size_t)(b * 64 + ch)) * 1024 + o]);
    out[g] = m + bf[o];
}

// ---------------------------------------------------------------- launch
extern "C" void kernel_launch(void* const* d_in, const int* in_sizes, int n_in,
                              void* d_out, int out_size, void* d_ws, size_t ws_size,
                              hipStream_t stream) {
    const float* x  = (const float*)d_in[0];
    const float* W0 = (const float*)d_in[1];
    const float* b0 = (const float*)d_in[2];
    const float* W1 = (const float*)d_in[3];
    const float* b1 = (const float*)d_in[4];
    const float* W2 = (const float*)d_in[5];
    const float* b2 = (const float*)d_in[6];
    const float* W3 = (const float*)d_in[7];
    const float* b3 = (const float*)d_in[8];
    const float* Wf = (const float*)d_in[9];
    const float* bf = (const float*)d_in[10];
    (void)in_sizes; (void)n_in; (void)out_size; (void)ws_size;

    char* ws = (char*)d_ws;
    float* feats   = (float*)ws;                                   // BN*512 f32 = 32 MB
    size_t off     = (size_t)BN * FSTR * 4;
    float* sq      = (float*)(ws + off);  off += (size_t)BN * 4;   // 64 KB
    int*   idx     = (int*)  (ws + off);  off += (size_t)BN * KNN * 4; // 1.25 MB
    float* partial = (float*)(ws + off);                           // 512*1024 f32 = 2 MB

    // Layer 0: C=3 -> 64 @ feats[0:64]
    sq_kernel<3><<<BN / 256, 256, 0, stream>>>(x, 3, sq);
    knn_kernel<3><<<BN / 4, 256, 0, stream>>>(x, 3, sq, idx);
    edge_kernel<3, 64><<<BN, 64, 0, stream>>>(x, 3, W0, b0, idx, feats + 0);

    // Layer 1: 64 -> 64 @ feats[64:128]
    sq_kernel<64><<<BN / 256, 256, 0, stream>>>(feats + 0, FSTR, sq);
    knn_kernel<64><<<BN / 4, 256, 0, stream>>>(feats + 0, FSTR, sq, idx);
    edge_kernel<64, 64><<<BN, 64, 0, stream>>>(feats + 0, FSTR, W1, b1, idx, feats + 64);

    // Layer 2: 64 -> 128 @ feats[128:256]
    sq_kernel<64><<<BN / 256, 256, 0, stream>>>(feats + 64, FSTR, sq);
    knn_kernel<64><<<BN / 4, 256, 0, stream>>>(feats + 64, FSTR, sq, idx);
    edge_kernel<64, 128><<<BN, 64, 0, stream>>>(feats + 64, FSTR, W2, b2, idx, feats + 128);

    // Layer 3: 128 -> 256 @ feats[256:512]
    sq_kernel<128><<<BN / 256, 256, 0, stream>>>(feats + 128, FSTR, sq);
    knn_kernel<128><<<BN / 4, 256, 0, stream>>>(feats + 128, FSTR, sq, idx);
    edge_kernel<128, 256><<<BN, 64, 0, stream>>>(feats + 128, FSTR, W3, b3, idx, feats + 256);

    // Final 512 -> 1024 + global max pool
    final_partial<<<512, 256, 0, stream>>>(feats, Wf, partial);
    final_reduce<<<32, 256, 0, stream>>>(partial, bf, (float*)d_out);
}

// Round 3
// 4184.513 us; speedup vs baseline: 1.0401x; 1.0401x over previous
//
#include <hip/hip_runtime.h>
#include <float.h>

constexpr int NB   = 8;      // batches
constexpr int NP   = 2048;   // points per batch
constexpr int BN   = NB * NP;
constexpr int KNN  = 20;     // neighbors
constexpr int FSTR = 512;    // feats row stride (64+64+128+256)

// ---------------------------------------------------------------- sq = |h|^2
template<int C>
__global__ __launch_bounds__(256) void sq_kernel(const float* __restrict__ h,
                                                 int istr,
                                                 float* __restrict__ sq) {
    int i = blockIdx.x * 256 + threadIdx.x;
    if (i >= BN) return;
    const float* p = h + (size_t)i * istr;
    float s = 0.f;
    #pragma unroll
    for (int c = 0; c < C; ++c) { float v = p[c]; s += v * v; }
    sq[i] = s;
}

// ---------------------------------------------------------------- kNN top-20
// Block handles GI=4 rows of one batch. Phase A: neg_d row into LDS.
// Phase B: each wave does 20x argmax (min-index tie-break) for its row.
template<int C>
__global__ __launch_bounds__(256) void knn_kernel(const float* __restrict__ h,
                                                  int istr,
                                                  const float* __restrict__ sq,
                                                  int* __restrict__ knn_idx) {
    constexpr int GI = 4;
    __shared__ float negd[GI][NP];          // 32 KB
    const int t    = threadIdx.x;
    const int r0   = blockIdx.x * GI;       // first global row of block
    const int base = (r0 >> 11) << 11;      // batch base row (NP = 2048)

    if constexpr (C == 3) {
        float hi[GI][3], sqi[GI];
        #pragma unroll
        for (int g = 0; g < GI; ++g) {
            const float* p = h + (size_t)(r0 + g) * istr;
            hi[g][0] = p[0]; hi[g][1] = p[1]; hi[g][2] = p[2];
            sqi[g] = sq[r0 + g];
        }
        for (int j = t; j < NP; j += 256) {
            const float* pj = h + (size_t)(base + j) * istr;
            float x0 = pj[0], x1 = pj[1], x2 = pj[2];
            float sqj = sq[base + j];
            #pragma unroll
            for (int g = 0; g < GI; ++g) {
                float d = hi[g][0]*x0 + hi[g][1]*x1 + hi[g][2]*x2;
                negd[g][j] = 2.f * d - sqi[g] - sqj;
            }
        }
    } else {
        constexpr int CQ   = C / 4;         // per-quarter channels
        constexpr int QSTR = CQ + 4;        // padded quarter stride
        constexpr int GSTR = 4 * QSTR;
        __shared__ float hi_s[GI * GSTR];
        for (int e = t; e < GI * C; e += 256) {
            int g = e / C, c = e - g * C;
            int q = c / CQ, cc = c - q * CQ;
            hi_s[g * GSTR + q * QSTR + cc] = h[(size_t)(r0 + g) * istr + c];
        }
        float sqi[GI];
        #pragma unroll
        for (int g = 0; g < GI; ++g) sqi[g] = sq[r0 + g];
        __syncthreads();

        const int jl = t >> 2;              // 0..63 : neighbor within tile
        const int q  = t & 3;               // channel quarter
        for (int jt = 0; jt < NP; jt += 64) {
            const float* pj = h + (size_t)(base + jt + jl) * istr + q * CQ;
            float4 hj[CQ / 4];
            #pragma unroll
            for (int u = 0; u < CQ / 4; ++u) hj[u] = *(const float4*)(pj + 4 * u);
            float p[GI];
            #pragma unroll
            for (int g = 0; g < GI; ++g) {
                const float* hs = &hi_s[g * GSTR + q * QSTR];
                float s = 0.f;
                #pragma unroll
                for (int u = 0; u < CQ / 4; ++u) {
                    float4 a = *(const float4*)(hs + 4 * u);
                    s += a.x*hj[u].x + a.y*hj[u].y + a.z*hj[u].z + a.w*hj[u].w;
                }
                p[g] = s;
            }
            #pragma unroll
            for (int g = 0; g < GI; ++g) {
                p[g] += __shfl_xor(p[g], 1);
                p[g] += __shfl_xor(p[g], 2);
            }
            if (q == 0) {
                int j = jt + jl;
                float sqj = sq[base + j];
                #pragma unroll
                for (int g = 0; g < GI; ++g)
                    negd[g][j] = 2.f * p[g] - sqi[g] - sqj;
            }
        }
    }
    __syncthreads();

    // ---- phase B: wave w owns row w
    const int w = t >> 6;
    const int l = t & 63;
    float* row = &negd[w][0];
    for (int it = 0; it < KNN; ++it) {
        float bv = -FLT_MAX; int bi = NP;
        for (int j = l; j < NP; j += 64) {
            float v = row[j];
            if (v > bv) { bv = v; bi = j; }
        }
        #pragma unroll
        for (int off = 1; off < 64; off <<= 1) {
            float ov = __shfl_xor(bv, off);
            int   oi = __shfl_xor(bi, off);
            if (ov > bv || (ov == bv && oi < bi)) { bv = ov; bi = oi; }
        }
        if (l == 0) knn_idx[(size_t)(r0 + w) * KNN + it] = bi;
        if (l == (bi & 63)) row[bi] = -FLT_MAX;
    }
}

// ---------------------------------------------------------------- EdgeConv
// Thread owns (point p, output channels o and o+COUT/2). 256 threads/block.
// acc[2][KNN] running accumulators; diff tile LDS-broadcast per wave.
template<int CIN, int COUT, int PPB>
__global__ __launch_bounds__(256) void edge_kernel(const float* __restrict__ hin,
                                                   int istr,
                                                   const float* __restrict__ W,
                                                   const float* __restrict__ bias,
                                                   const int* __restrict__ knn_idx,
                                                   float* __restrict__ hout) {
    constexpr int TPP = COUT / 2;            // threads per point
    static_assert(PPB * TPP == 256, "block must be 256 threads");
    __shared__ float diff[PPB][KNN][CIN];
    __shared__ float hi[PPB][CIN];
    __shared__ int   nj[PPB][KNN];

    const int t    = threadIdx.x;
    const int r0   = blockIdx.x * PPB;
    const int base = (r0 >> 11) << 11;

    for (int e = t; e < PPB * KNN; e += 256) {
        int p = e / KNN, kk = e - p * KNN;
        nj[p][kk] = knn_idx[(size_t)(r0 + p) * KNN + kk];
    }
    for (int e = t; e < PPB * CIN; e += 256) {
        int p = e / CIN, c = e - p * CIN;
        hi[p][c] = hin[(size_t)(r0 + p) * istr + c];
    }
    __syncthreads();
    for (int e = t; e < PPB * KNN * CIN; e += 256) {
        int p  = e / (KNN * CIN);
        int rm = e - p * (KNN * CIN);
        int kk = rm / CIN, c = rm - kk * CIN;
        int j  = nj[p][kk];
        diff[p][kk][c] = hin[(size_t)(base + j) * istr + c] - hi[p][c];
    }
    __syncthreads();

    const int p  = t / TPP;
    const int oo = t - p * TPP;              // o0 = oo, o1 = oo + TPP
    const float* W0 = W + (size_t)oo * (2 * CIN);
    const float* W1 = W + (size_t)(oo + TPP) * (2 * CIN);

    float ctr0 = bias[oo], ctr1 = bias[oo + TPP];
    float acc[2][KNN];
    #pragma unroll
    for (int kk = 0; kk < KNN; ++kk) { acc[0][kk] = 0.f; acc[1][kk] = 0.f; }

    if constexpr (CIN % 4 == 0) {
        for (int c = 0; c < CIN; c += 4) {
            float4 hv = *(const float4*)&hi[p][c];
            float4 u0 = *(const float4*)(W0 + CIN + c);
            float4 u1 = *(const float4*)(W1 + CIN + c);
            ctr0 += u0.x*hv.x + u0.y*hv.y + u0.z*hv.z + u0.w*hv.w;
            ctr1 += u1.x*hv.x + u1.y*hv.y + u1.z*hv.z + u1.w*hv.w;
        }
        for (int c = 0; c < CIN; c += 4) {
            float4 w0 = *(const float4*)(W0 + c);
            float4 w1 = *(const float4*)(W1 + c);
            #pragma unroll
            for (int kk = 0; kk < KNN; ++kk) {
                float4 d = *(const float4*)&diff[p][kk][c];
                acc[0][kk] += w0.x*d.x + w0.y*d.y + w0.z*d.z + w0.w*d.w;
                acc[1][kk] += w1.x*d.x + w1.y*d.y + w1.z*d.z + w1.w*d.w;
            }
        }
    } else {
        for (int c = 0; c < CIN; ++c) {
            float hv = hi[p][c];
            ctr0 += W0[CIN + c] * hv;
            ctr1 += W1[CIN + c] * hv;
        }
        for (int c = 0; c < CIN; ++c) {
            float w0 = W0[c], w1 = W1[c];
            #pragma unroll
            for (int kk = 0; kk < KNN; ++kk) {
                float d = diff[p][kk][c];
                acc[0][kk] += w0 * d;
                acc[1][kk] += w1 * d;
            }
        }
    }

    float m0 = -FLT_MAX, m1 = -FLT_MAX;
    #pragma unroll
    for (int kk = 0; kk < KNN; ++kk) {
        m0 = fmaxf(m0, acc[0][kk] + ctr0);
        m1 = fmaxf(m1, acc[1][kk] + ctr1);
    }
    float r0v = m0 > 0.f ? m0 : 0.2f * m0;   // lrelu after max == max of lrelu
    float r1v = m1 > 0.f ? m1 : 0.2f * m1;
    hout[(size_t)(r0 + p) * FSTR + oo]       = r0v;
    hout[(size_t)(r0 + p) * FSTR + oo + TPP] = r1v;
}

// ---------------------------------------------------------------- final GEMM + max over n
__global__ __launch_bounds__(256) void final_partial(const float* __restrict__ f,
                                                     const float* __restrict__ Wf,
                                                     float* __restrict__ partial) {
    __shared__ float fs[8][512];                 // 16 KB
    const int t = threadIdx.x;
    const int bx = blockIdx.x;                   // 0..511
    const int b = bx >> 6, chunk = bx & 63;
    const int n0 = chunk * 32;
    float mx[4] = {-FLT_MAX, -FLT_MAX, -FLT_MAX, -FLT_MAX};
    for (int sub = 0; sub < 4; ++sub) {
        for (int e = t; e < 8 * 128; e += 256) {
            int row = e >> 7, c4 = e & 127;
            *(float4*)&fs[row][c4 * 4] =
                *(const float4*)&f[((size_t)(b * NP + n0 + sub * 8 + row)) * FSTR + c4 * 4];
        }
        __syncthreads();
        float acc[4][8];
        #pragma unroll
        for (int q = 0; q < 4; ++q)
            #pragma unroll
            for (int n = 0; n < 8; ++n) acc[q][n] = 0.f;
        for (int c = 0; c < 512; c += 4) {
            float4 wv[4];
            #pragma unroll
            for (int q = 0; q < 4; ++q)
                wv[q] = *(const float4*)&Wf[(size_t)(t + 256 * q) * 512 + c];
            #pragma unroll
            for (int n = 0; n < 8; ++n) {
                float4 fv = *(const float4*)&fs[n][c];
                #pragma unroll
                for (int q = 0; q < 4; ++q)
                    acc[q][n] += wv[q].x*fv.x + wv[q].y*fv.y + wv[q].z*fv.z + wv[q].w*fv.w;
            }
        }
        #pragma unroll
        for (int q = 0; q < 4; ++q)
            #pragma unroll
            for (int n = 0; n < 8; ++n) mx[q] = fmaxf(mx[q], acc[q][n]);
        __syncthreads();
    }
    #pragma unroll
    for (int q = 0; q < 4; ++q)
        partial[(size_t)bx * 1024 + t + 256 * q] = mx[q];
}

__global__ __launch_bounds__(256) void final_reduce(const float* __restrict__ partial,
                                                    const float* __restrict__ bf,
                                                    float* __restrict__ out) {
    int g = blockIdx.x * 256 + threadIdx.x;      // 8192
    int b = g >> 10, o = g & 1023;
    float m = -FLT_MAX;
    for (int ch = 0; ch < 64; ++ch)
        m = fmaxf(m, partial[((size_t)(b * 64 + ch)) * 1024 + o]);
    out[g] = m + bf[o];
}

// ---------------------------------------------------------------- launch
extern "C" void kernel_launch(void* const* d_in, const int* in_sizes, int n_in,
                              void* d_out, int out_size, void* d_ws, size_t ws_size,
                              hipStream_t stream) {
    const float* x  = (const float*)d_in[0];
    const float* W0 = (const float*)d_in[1];
    const float* b0 = (const float*)d_in[2];
    const float* W1 = (const float*)d_in[3];
    const float* b1 = (const float*)d_in[4];
    const float* W2 = (const float*)d_in[5];
    const float* b2 = (const float*)d_in[6];
    const float* W3 = (const float*)d_in[7];
    const float* b3 = (const float*)d_in[8];
    const float* Wf = (const float*)d_in[9];
    const float* bf = (const float*)d_in[10];
    (void)in_sizes; (void)n_in; (void)out_size; (void)ws_size;

    char* ws = (char*)d_ws;
    float* feats   = (float*)ws;                                   // BN*512 f32 = 32 MB
    size_t off     = (size_t)BN * FSTR * 4;
    float* sq      = (float*)(ws + off);  off += (size_t)BN * 4;   // 64 KB
    int*   idx     = (int*)  (ws + off);  off += (size_t)BN * KNN * 4; // 1.25 MB
    float* partial = (float*)(ws + off);                           // 512*1024 f32 = 2 MB

    // Layer 0: C=3 -> 64 @ feats[0:64]
    sq_kernel<3><<<BN / 256, 256, 0, stream>>>(x, 3, sq);
    knn_kernel<3><<<BN / 4, 256, 0, stream>>>(x, 3, sq, idx);
    edge_kernel<3, 64, 8><<<BN / 8, 256, 0, stream>>>(x, 3, W0, b0, idx, feats + 0);

    // Layer 1: 64 -> 64 @ feats[64:128]
    sq_kernel<64><<<BN / 256, 256, 0, stream>>>(feats + 0, FSTR, sq);
    knn_kernel<64><<<BN / 4, 256, 0, stream>>>(feats + 0, FSTR, sq, idx);
    edge_kernel<64, 64, 8><<<BN / 8, 256, 0, stream>>>(feats + 0, FSTR, W1, b1, idx, feats + 64);

    // Layer 2: 64 -> 128 @ feats[128:256]
    sq_kernel<64><<<BN / 256, 256, 0, stream>>>(feats + 64, FSTR, sq);
    knn_kernel<64><<<BN / 4, 256, 0, stream>>>(feats + 64, FSTR, sq, idx);
    edge_kernel<64, 128, 4><<<BN / 4, 256, 0, stream>>>(feats + 64, FSTR, W2, b2, idx, feats + 128);

    // Layer 3: 128 -> 256 @ feats[256:512]
    sq_kernel<128><<<BN / 256, 256, 0, stream>>>(feats + 128, FSTR, sq);
    knn_kernel<128><<<BN / 4, 256, 0, stream>>>(feats + 128, FSTR, sq, idx);
    edge_kernel<128, 256, 2><<<BN / 2, 256, 0, stream>>>(feats + 128, FSTR, W3, b3, idx, feats + 256);

    // Final 512 -> 1024 + global max pool
    final_partial<<<512, 256, 0, stream>>>(feats, Wf, partial);
    final_reduce<<<32, 256, 0, stream>>>(partial, bf, (float*)d_out);
}

// Round 5
// 3431.200 us; speedup vs baseline: 1.2685x; 1.2195x over previous
//
#include <hip/hip_runtime.h>
#include <float.h>

constexpr int NB   = 8;      // batches
constexpr int NP   = 2048;   // points per batch
constexpr int BN   = NB * NP;
constexpr int KNN  = 20;     // neighbors
constexpr int FSTR = 512;    // feats row stride (64+64+128+256)

typedef short short8 __attribute__((ext_vector_type(8)));
typedef float f32x4  __attribute__((ext_vector_type(4)));

__device__ __forceinline__ unsigned f2bf_rne(float x) {
    unsigned u = __float_as_uint(x);
    unsigned r = (u >> 16) & 1;
    return (u + 0x7fffu + r) >> 16;
}
__device__ __forceinline__ float bf2f(unsigned h) { return __uint_as_float(h << 16); }

// ---------------------------------------------------------------- sq = |h|^2
template<int C>
__global__ __launch_bounds__(256) void sq_kernel(const float* __restrict__ h,
                                                 int istr,
                                                 float* __restrict__ sq) {
    int i = blockIdx.x * 256 + threadIdx.x;
    if (i >= BN) return;
    const float* p = h + (size_t)i * istr;
    float s = 0.f;
    #pragma unroll
    for (int c = 0; c < C; ++c) { float v = p[c]; s += v * v; }
    sq[i] = s;
}

// ---------------------------------------------------------------- kNN top-20
template<int C>
__global__ __launch_bounds__(256) void knn_kernel(const float* __restrict__ h,
                                                  int istr,
                                                  const float* __restrict__ sq,
                                                  int* __restrict__ knn_idx) {
    constexpr int GI = 4;
    __shared__ float negd[GI][NP];          // 32 KB
    const int t    = threadIdx.x;
    const int r0   = blockIdx.x * GI;
    const int base = (r0 >> 11) << 11;

    if constexpr (C == 3) {
        float hi[GI][3], sqi[GI];
        #pragma unroll
        for (int g = 0; g < GI; ++g) {
            const float* p = h + (size_t)(r0 + g) * istr;
            hi[g][0] = p[0]; hi[g][1] = p[1]; hi[g][2] = p[2];
            sqi[g] = sq[r0 + g];
        }
        for (int j = t; j < NP; j += 256) {
            const float* pj = h + (size_t)(base + j) * istr;
            float x0 = pj[0], x1 = pj[1], x2 = pj[2];
            float sqj = sq[base + j];
            #pragma unroll
            for (int g = 0; g < GI; ++g) {
                float d = hi[g][0]*x0 + hi[g][1]*x1 + hi[g][2]*x2;
                negd[g][j] = 2.f * d - sqi[g] - sqj;
            }
        }
    } else {
        constexpr int CQ   = C / 4;
        constexpr int QSTR = CQ + 4;
        constexpr int GSTR = 4 * QSTR;
        __shared__ float hi_s[GI * GSTR];
        for (int e = t; e < GI * C; e += 256) {
            int g = e / C, c = e - g * C;
            int q = c / CQ, cc = c - q * CQ;
            hi_s[g * GSTR + q * QSTR + cc] = h[(size_t)(r0 + g) * istr + c];
        }
        float sqi[GI];
        #pragma unroll
        for (int g = 0; g < GI; ++g) sqi[g] = sq[r0 + g];
        __syncthreads();

        const int jl = t >> 2;
        const int q  = t & 3;
        for (int jt = 0; jt < NP; jt += 64) {
            const float* pj = h + (size_t)(base + jt + jl) * istr + q * CQ;
            float4 hj[CQ / 4];
            #pragma unroll
            for (int u = 0; u < CQ / 4; ++u) hj[u] = *(const float4*)(pj + 4 * u);
            float p[GI];
            #pragma unroll
            for (int g = 0; g < GI; ++g) {
                const float* hs = &hi_s[g * GSTR + q * QSTR];
                float s = 0.f;
                #pragma unroll
                for (int u = 0; u < CQ / 4; ++u) {
                    float4 a = *(const float4*)(hs + 4 * u);
                    s += a.x*hj[u].x + a.y*hj[u].y + a.z*hj[u].z + a.w*hj[u].w;
                }
                p[g] = s;
            }
            #pragma unroll
            for (int g = 0; g < GI; ++g) {
                p[g] += __shfl_xor(p[g], 1);
                p[g] += __shfl_xor(p[g], 2);
            }
            if (q == 0) {
                int j = jt + jl;
                float sqj = sq[base + j];
                #pragma unroll
                for (int g = 0; g < GI; ++g)
                    negd[g][j] = 2.f * p[g] - sqi[g] - sqj;
            }
        }
    }
    __syncthreads();

    const int w = t >> 6;
    const int l = t & 63;
    float* row = &negd[w][0];
    for (int it = 0; it < KNN; ++it) {
        float bv = -FLT_MAX; int bi = NP;
        for (int j = l; j < NP; j += 64) {
            float v = row[j];
            if (v > bv) { bv = v; bi = j; }
        }
        #pragma unroll
        for (int off = 1; off < 64; off <<= 1) {
            float ov = __shfl_xor(bv, off);
            int   oi = __shfl_xor(bi, off);
            if (ov > bv || (ov == bv && oi < bi)) { bv = ov; bi = oi; }
        }
        if (l == 0) knn_idx[(size_t)(r0 + w) * KNN + it] = bi;
        if (l == (bi & 63)) row[bi] = -FLT_MAX;
    }
}

// ---------------------------------------------------------------- W hi/lo prep
__global__ __launch_bounds__(256) void wprep_kernel(const float* __restrict__ W,
                                                    int cin, int total,
                                                    short* __restrict__ whi,
                                                    short* __restrict__ wlo) {
    int e = blockIdx.x * 256 + threadIdx.x;
    if (e >= total) return;
    int o = e / cin, c = e - o * cin;
    float v = W[(size_t)o * (2 * cin) + c];
    unsigned h = f2bf_rne(v);
    float fh = bf2f(h);
    unsigned lo = __float_as_uint(v - fh) >> 16;   // truncate
    whi[e] = (short)h;
    wlo[e] = (short)lo;
}

// ---------------------------------------------------------------- ctr = W[:,C:2C]*h_i + b  (exact fp32)
template<int CIN, int COUT>
__global__ __launch_bounds__(256) void ctr_kernel(const float* __restrict__ h, int istr,
                                                  const float* __restrict__ W,
                                                  const float* __restrict__ bias,
                                                  float* __restrict__ ctr) {
    constexpr int PP = 256 / COUT;       // points per pass
    constexpr int R  = 4 / PP;           // passes
    __shared__ float hs[4][CIN];
    const int t  = threadIdx.x;
    const int r0 = blockIdx.x * 4;
    for (int e = t; e < 4 * CIN; e += 256) {
        int p = e / CIN, c = e - p * CIN;
        hs[p][c] = h[(size_t)(r0 + p) * istr + c];
    }
    __syncthreads();
    const int o  = t % COUT;
    const int pi = t / COUT;
    const float  bb = bias[o];
    const float* wr = W + (size_t)o * (2 * CIN) + CIN;
    #pragma unroll
    for (int rep = 0; rep < R; ++rep) {
        int p = rep * PP + pi;
        float s = bb;
        for (int c = 0; c < CIN; c += 4) {
            float4 wv = *(const float4*)(wr + c);
            float4 hv = *(const float4*)&hs[p][c];
            s += wv.x*hv.x + wv.y*hv.y + wv.z*hv.z + wv.w*hv.w;
        }
        ctr[(size_t)(r0 + p) * COUT + o] = s;
    }
}

// ---------------------------------------------------------------- EdgeConv via MFMA (bf16 hi/lo, 3-term)
// Block: 4 points x 20 nbrs = 80 rows = 5 M-tiles; COLS output cols (blockIdx.y slices COUT).
// LDS: Dhi/Dlo planes, XOR-swizzled (byte ^= (row&7)<<4) for conflict-free ds_read_b128.
template<int CIN, int COLS, int NTW>     // NTW = COLS/16/4 (N-tiles per wave)
__global__ __launch_bounds__(256) void edge_mfma(const float* __restrict__ hin, int istr,
                                                 const short* __restrict__ whi,
                                                 const short* __restrict__ wlo,
                                                 const float* __restrict__ ctr, int coutFull,
                                                 const int* __restrict__ knn_idx,
                                                 float* __restrict__ hout) {
    constexpr int ROWS  = 80;
    constexpr int PLANE = ROWS * CIN * 2;          // bytes per plane
    __shared__ short D[2 * ROWS * CIN];            // hi plane then lo plane
    __shared__ float hpt[4][CIN];
    __shared__ int   nj[4][KNN];

    const int t       = threadIdx.x;
    const int r0      = blockIdx.x * 4;
    const int base    = (r0 >> 11) << 11;
    const int colbase = blockIdx.y * COLS;

    for (int e = t; e < 4 * KNN; e += 256)
        nj[e / KNN][e % KNN] = knn_idx[(size_t)(r0 + e / KNN) * KNN + (e % KNN)];
    for (int e = t; e < 4 * CIN; e += 256)
        hpt[e / CIN][e % CIN] = hin[(size_t)(r0 + e / CIN) * istr + (e % CIN)];
    __syncthreads();

    constexpr int CP = CIN / 2;                    // float2 units per row
    char* Db = (char*)D;
    for (int u = t; u < ROWS * CP; u += 256) {
        int row = u / CP, cp = u - row * CP;
        int p = row / KNN, kk = row - p * KNN;
        const float* src = &hin[(size_t)(base + nj[p][kk]) * istr + cp * 2];
        float d0 = src[0] - hpt[p][cp * 2];
        float d1 = src[1] - hpt[p][cp * 2 + 1];
        unsigned h0 = f2bf_rne(d0), h1 = f2bf_rne(d1);
        unsigned l0 = __float_as_uint(d0 - bf2f(h0)) >> 16;
        unsigned l1 = __float_as_uint(d1 - bf2f(h1)) >> 16;
        int byte = row * (CIN * 2) + cp * 4;
        byte ^= ((row & 7) << 4);
        *(unsigned*)(Db + byte)         = h0 | (h1 << 16);
        *(unsigned*)(Db + PLANE + byte) = l0 | (l1 << 16);
    }
    __syncthreads();

    const int l = t & 63, w = t >> 6, g = l >> 4, cl = l & 15;

    f32x4 acc[5][NTW];
    #pragma unroll
    for (int mt = 0; mt < 5; ++mt)
        #pragma unroll
        for (int nt = 0; nt < NTW; ++nt)
            acc[mt][nt] = (f32x4){0.f, 0.f, 0.f, 0.f};

    #pragma unroll 1
    for (int term = 0; term < 3; ++term) {
        const char*  Ab = Db + (term == 2 ? PLANE : 0);
        const short* Bs = (term == 1) ? wlo : whi;
        #pragma unroll 1
        for (int kc = 0; kc < CIN / 32; ++kc) {
            const int k0 = kc * 32 + g * 8;
            short8 a[5];
            #pragma unroll
            for (int mt = 0; mt < 5; ++mt) {
                int row  = mt * 16 + cl;
                int byte = row * (CIN * 2) + k0 * 2;
                byte ^= ((row & 7) << 4);
                a[mt] = *(const short8*)(Ab + byte);
            }
            short8 bfr[NTW];
            #pragma unroll
            for (int nt = 0; nt < NTW; ++nt) {
                int o = colbase + (w * NTW + nt) * 16 + cl;
                bfr[nt] = *(const short8*)(Bs + (size_t)o * CIN + k0);
            }
            #pragma unroll
            for (int mt = 0; mt < 5; ++mt)
                #pragma unroll
                for (int nt = 0; nt < NTW; ++nt)
                    acc[mt][nt] = __builtin_amdgcn_mfma_f32_16x16x32_bf16(
                        a[mt], bfr[nt], acc[mt][nt], 0, 0, 0);
        }
    }

    // ---- epilogue: max over each point's 20 rows, + ctr, lrelu, store.
    // Lane owns rows {mt*16 + g*4 + r}; chunk (4mt+g) of 4 rows -> point (4mt+g)/5.
    #pragma unroll
    for (int nt = 0; nt < NTW; ++nt) {
        float cm[5];
        #pragma unroll
        for (int mt = 0; mt < 5; ++mt) {
            f32x4 v = acc[mt][nt];
            cm[mt] = fmaxf(fmaxf(v[0], v[1]), fmaxf(v[2], v[3]));
        }
        float pm0 = -FLT_MAX, pm1 = -FLT_MAX, pm2 = -FLT_MAX, pm3 = -FLT_MAX;
        #pragma unroll
        for (int mt = 0; mt < 5; ++mt) {
            int p = (4 * mt + g) / 5;
            pm0 = (p == 0) ? fmaxf(pm0, cm[mt]) : pm0;
            pm1 = (p == 1) ? fmaxf(pm1, cm[mt]) : pm1;
            pm2 = (p == 2) ? fmaxf(pm2, cm[mt]) : pm2;
            pm3 = (p == 3) ? fmaxf(pm3, cm[mt]) : pm3;
        }
        pm0 = fmaxf(pm0, __shfl_xor(pm0, 16)); pm0 = fmaxf(pm0, __shfl_xor(pm0, 32));
        pm1 = fmaxf(pm1, __shfl_xor(pm1, 16)); pm1 = fmaxf(pm1, __shfl_xor(pm1, 32));
        pm2 = fmaxf(pm2, __shfl_xor(pm2, 16)); pm2 = fmaxf(pm2, __shfl_xor(pm2, 32));
        pm3 = fmaxf(pm3, __shfl_xor(pm3, 16)); pm3 = fmaxf(pm3, __shfl_xor(pm3, 32));
        float pm  = (g == 0) ? pm0 : (g == 1) ? pm1 : (g == 2) ? pm2 : pm3;
        int   col = colbase + (w * NTW + nt) * 16 + cl;
        float val = pm + ctr[(size_t)(r0 + g) * coutFull + col];
        val = val > 0.f ? val : 0.2f * val;
        hout[(size_t)(r0 + g) * FSTR + col] = val;
    }
}

// ---------------------------------------------------------------- EdgeConv L0 (CIN=3, fp32 VALU)
template<int CIN, int COUT, int PPB>
__global__ __launch_bounds__(256) void edge_kernel(const float* __restrict__ hin,
                                                   int istr,
                                                   const float* __restrict__ W,
                                                   const float* __restrict__ bias,
                                                   const int* __restrict__ knn_idx,
                                                   float* __restrict__ hout) {
    constexpr int TPP = COUT / 2;
    static_assert(PPB * TPP == 256, "block must be 256 threads");
    __shared__ float diff[PPB][KNN][CIN];
    __shared__ float hi[PPB][CIN];
    __shared__ int   nj[PPB][KNN];

    const int t    = threadIdx.x;
    const int r0   = blockIdx.x * PPB;
    const int base = (r0 >> 11) << 11;

    for (int e = t; e < PPB * KNN; e += 256) {
        int p = e / KNN, kk = e - p * KNN;
        nj[p][kk] = knn_idx[(size_t)(r0 + p) * KNN + kk];
    }
    for (int e = t; e < PPB * CIN; e += 256) {
        int p = e / CIN, c = e - p * CIN;
        hi[p][c] = hin[(size_t)(r0 + p) * istr + c];
    }
    __syncthreads();
    for (int e = t; e < PPB * KNN * CIN; e += 256) {
        int p  = e / (KNN * CIN);
        int rm = e - p * (KNN * CIN);
        int kk = rm / CIN, c = rm - kk * CIN;
        diff[p][kk][c] = hin[(size_t)(base + nj[p][kk]) * istr + c] - hi[p][c];
    }
    __syncthreads();

    const int p  = t / TPP;
    const int oo = t - p * TPP;
    const float* W0 = W + (size_t)oo * (2 * CIN);
    const float* W1 = W + (size_t)(oo + TPP) * (2 * CIN);

    float ctr0 = bias[oo], ctr1 = bias[oo + TPP];
    float acc[2][KNN];
    #pragma unroll
    for (int kk = 0; kk < KNN; ++kk) { acc[0][kk] = 0.f; acc[1][kk] = 0.f; }

    for (int c = 0; c < CIN; ++c) {
        float hv = hi[p][c];
        ctr0 += W0[CIN + c] * hv;
        ctr1 += W1[CIN + c] * hv;
    }
    for (int c = 0; c < CIN; ++c) {
        float w0 = W0[c], w1 = W1[c];
        #pragma unroll
        for (int kk = 0; kk < KNN; ++kk) {
            float d = diff[p][kk][c];
            acc[0][kk] += w0 * d;
            acc[1][kk] += w1 * d;
        }
    }

    float m0 = -FLT_MAX, m1 = -FLT_MAX;
    #pragma unroll
    for (int kk = 0; kk < KNN; ++kk) {
        m0 = fmaxf(m0, acc[0][kk] + ctr0);
        m1 = fmaxf(m1, acc[1][kk] + ctr1);
    }
    float r0v = m0 > 0.f ? m0 : 0.2f * m0;
    float r1v = m1 > 0.f ? m1 : 0.2f * m1;
    hout[(size_t)(r0 + p) * FSTR + oo]       = r0v;
    hout[(size_t)(r0 + p) * FSTR + oo + TPP] = r1v;
}

// ---------------------------------------------------------------- final GEMM + max over n
__global__ __launch_bounds__(256) void final_partial(const float* __restrict__ f,
                                                     const float* __restrict__ Wf,
                                                     float* __restrict__ partial) {
    __shared__ float fs[8][512];
    const int t = threadIdx.x;
    const int bx = blockIdx.x;
    const int b = bx >> 6, chunk = bx & 63;
    const int n0 = chunk * 32;
    float mx[4] = {-FLT_MAX, -FLT_MAX, -FLT_MAX, -FLT_MAX};
    for (int sub = 0; sub < 4; ++sub) {
        for (int e = t; e < 8 * 128; e += 256) {
            int row = e >> 7, c4 = e & 127;
            *(float4*)&fs[row][c4 * 4] =
                *(const float4*)&f[((size_t)(b * NP + n0 + sub * 8 + row)) * FSTR + c4 * 4];
        }
        __syncthreads();
        float acc[4][8];
        #pragma unroll
        for (int q = 0; q < 4; ++q)
            #pragma unroll
            for (int n = 0; n < 8; ++n) acc[q][n] = 0.f;
        for (int c = 0; c < 512; c += 4) {
            float4 wv[4];
            #pragma unroll
            for (int q = 0; q < 4; ++q)
                wv[q] = *(const float4*)&Wf[(size_t)(t + 256 * q) * 512 + c];
            #pragma unroll
            for (int n = 0; n < 8; ++n) {
                float4 fv = *(const float4*)&fs[n][c];
                #pragma unroll
                for (int q = 0; q < 4; ++q)
                    acc[q][n] += wv[q].x*fv.x + wv[q].y*fv.y + wv[q].z*fv.z + wv[q].w*fv.w;
            }
        }
        #pragma unroll
        for (int q = 0; q < 4; ++q)
            #pragma unroll
            for (int n = 0; n < 8; ++n) mx[q] = fmaxf(mx[q], acc[q][n]);
        __syncthreads();
    }
    #pragma unroll
    for (int q = 0; q < 4; ++q)
        partial[(size_t)bx * 1024 + t + 256 * q] = mx[q];
}

__global__ __launch_bounds__(256) void final_reduce(const float* __restrict__ partial,
                                                    const float* __restrict__ bf,
                                                    float* __restrict__ out) {
    int g = blockIdx.x * 256 + threadIdx.x;
    int b = g >> 10, o = g & 1023;
    float m = -FLT_MAX;
    for (int ch = 0; ch < 64; ++ch)
        m = fmaxf(m, partial[((size_t)(b * 64 + ch)) * 1024 + o]);
    out[g] = m + bf[o];
}

// ---------------------------------------------------------------- launch
extern "C" void kernel_launch(void* const* d_in, const int* in_sizes, int n_in,
                              void* d_out, int out_size, void* d_ws, size_t ws_size,
                              hipStream_t stream) {
    const float* x  = (const float*)d_in[0];
    const float* W0 = (const float*)d_in[1];
    const float* b0 = (const float*)d_in[2];
    const float* W1 = (const float*)d_in[3];
    const float* b1 = (const float*)d_in[4];
    const float* W2 = (const float*)d_in[5];
    const float* b2 = (const float*)d_in[6];
    const float* W3 = (const float*)d_in[7];
    const float* b3 = (const float*)d_in[8];
    const float* Wf = (const float*)d_in[9];
    const float* bf = (const float*)d_in[10];
    (void)in_sizes; (void)n_in; (void)out_size; (void)ws_size;

    char* ws = (char*)d_ws;
    size_t off = 0;
    float* feats   = (float*)(ws + off); off += (size_t)BN * FSTR * 4;      // 32 MB
    float* sq      = (float*)(ws + off); off += (size_t)BN * 4;             // 64 KB
    int*   idx     = (int*)  (ws + off); off += (size_t)BN * KNN * 4;       // 1.25 MB
    float* partial = (float*)(ws + off); off += (size_t)512 * 1024 * 4;     // 2 MB
    float* ctrbuf  = (float*)(ws + off); off += (size_t)BN * 256 * 4;       // 16 MB
    short* whi     = (short*)(ws + off); off += (size_t)45056 * 2;          // W hi planes
    short* wlo     = (short*)(ws + off); off += (size_t)45056 * 2;          // W lo planes
    short* w1hi = whi,          *w1lo = wlo;                                // 64x64
    short* w2hi = whi + 4096,   *w2lo = wlo + 4096;                         // 128x64
    short* w3hi = whi + 12288,  *w3lo = wlo + 12288;                        // 256x128

    // W hi/lo prep (first halves of W1..W3)
    wprep_kernel<<<16, 256, 0, stream>>>(W1, 64, 64 * 64, w1hi, w1lo);
    wprep_kernel<<<32, 256, 0, stream>>>(W2, 64, 128 * 64, w2hi, w2lo);
    wprep_kernel<<<128, 256, 0, stream>>>(W3, 128, 256 * 128, w3hi, w3lo);

    // Layer 0: C=3 -> 64 @ feats[0:64]  (fp32 VALU)
    sq_kernel<3><<<BN / 256, 256, 0, stream>>>(x, 3, sq);
    knn_kernel<3><<<BN / 4, 256, 0, stream>>>(x, 3, sq, idx);
    edge_kernel<3, 64, 8><<<BN / 8, 256, 0, stream>>>(x, 3, W0, b0, idx, feats + 0);

    // Layer 1: 64 -> 64 @ feats[64:128]
    sq_kernel<64><<<BN / 256, 256, 0, stream>>>(feats + 0, FSTR, sq);
    knn_kernel<64><<<BN / 4, 256, 0, stream>>>(feats + 0, FSTR, sq, idx);
    ctr_kernel<64, 64><<<BN / 4, 256, 0, stream>>>(feats + 0, FSTR, W1, b1, ctrbuf);
    edge_mfma<64, 64, 1><<<dim3(BN / 4, 1), 256, 0, stream>>>(
        feats + 0, FSTR, w1hi, w1lo, ctrbuf, 64, idx, feats + 64);

    // Layer 2: 64 -> 128 @ feats[128:256]
    sq_kernel<64><<<BN / 256, 256, 0, stream>>>(feats + 64, FSTR, sq);
    knn_kernel<64><<<BN / 4, 256, 0, stream>>>(feats + 64, FSTR, sq, idx);
    ctr_kernel<64, 128><<<BN / 4, 256, 0, stream>>>(feats + 64, FSTR, W2, b2, ctrbuf);
    edge_mfma<64, 128, 2><<<dim3(BN / 4, 1), 256, 0, stream>>>(
        feats + 64, FSTR, w2hi, w2lo, ctrbuf, 128, idx, feats + 128);

    // Layer 3: 128 -> 256 @ feats[256:512]
    sq_kernel<128><<<BN / 256, 256, 0, stream>>>(feats + 128, FSTR, sq);
    knn_kernel<128><<<BN / 4, 256, 0, stream>>>(feats + 128, FSTR, sq, idx);
    ctr_kernel<128, 256><<<BN / 4, 256, 0, stream>>>(feats + 128, FSTR, W3, b3, ctrbuf);
    edge_mfma<128, 128, 2><<<dim3(BN / 4, 2), 256, 0, stream>>>(
        feats + 128, FSTR, w3hi, w3lo, ctrbuf, 256, idx, feats + 256);

    // Final 512 -> 1024 + global max pool
    final_partial<<<512, 256, 0, stream>>>(feats, Wf, partial);
    final_reduce<<<32, 256, 0, stream>>>(partial, bf, (float*)d_out);
}

// Round 7
// 2596.376 us; speedup vs baseline: 1.6763x; 1.3215x over previous
//
#include <hip/hip_runtime.h>
#include <float.h>

constexpr int NB   = 8;      // batches
constexpr int NP   = 2048;   // points per batch
constexpr int BN   = NB * NP;
constexpr int KNN  = 20;     // neighbors
constexpr int FSTR = 512;    // feats row stride (64+64+128+256)

typedef short short8 __attribute__((ext_vector_type(8)));
typedef float f32x4  __attribute__((ext_vector_type(4)));

__device__ __forceinline__ unsigned f2bf_rne(float x) {
    unsigned u = __float_as_uint(x);
    unsigned r = (u >> 16) & 1;
    return (u + 0x7fffu + r) >> 16;
}
__device__ __forceinline__ float bf2f(unsigned h) { return __uint_as_float(h << 16); }

// ---------------------------------------------------------------- sq = |h|^2
template<int C>
__global__ __launch_bounds__(256) void sq_kernel(const float* __restrict__ h,
                                                 int istr,
                                                 float* __restrict__ sq) {
    int i = blockIdx.x * 256 + threadIdx.x;
    if (i >= BN) return;
    const float* p = h + (size_t)i * istr;
    float s = 0.f;
    #pragma unroll
    for (int c = 0; c < C; ++c) { float v = p[c]; s += v * v; }
    sq[i] = s;
}

// ---------------------------------------------------------------- kNN top-20
template<int C>
__global__ __launch_bounds__(256) void knn_kernel(const float* __restrict__ h,
                                                  int istr,
                                                  const float* __restrict__ sq,
                                                  int* __restrict__ knn_idx) {
    constexpr int GI = 4;
    __shared__ float negd[GI][NP];          // 32 KB
    const int t    = threadIdx.x;
    const int r0   = blockIdx.x * GI;
    const int base = (r0 >> 11) << 11;

    if constexpr (C == 3) {
        float hi[GI][3], sqi[GI];
        #pragma unroll
        for (int g = 0; g < GI; ++g) {
            const float* p = h + (size_t)(r0 + g) * istr;
            hi[g][0] = p[0]; hi[g][1] = p[1]; hi[g][2] = p[2];
            sqi[g] = sq[r0 + g];
        }
        for (int j = t; j < NP; j += 256) {
            const float* pj = h + (size_t)(base + j) * istr;
            float x0 = pj[0], x1 = pj[1], x2 = pj[2];
            float sqj = sq[base + j];
            #pragma unroll
            for (int g = 0; g < GI; ++g) {
                float d = hi[g][0]*x0 + hi[g][1]*x1 + hi[g][2]*x2;
                negd[g][j] = 2.f * d - sqi[g] - sqj;
            }
        }
    } else {
        constexpr int CQ   = C / 4;
        constexpr int QSTR = CQ + 4;
        constexpr int GSTR = 4 * QSTR;
        __shared__ float hi_s[GI * GSTR];
        for (int e = t; e < GI * C; e += 256) {
            int g = e / C, c = e - g * C;
            int q = c / CQ, cc = c - q * CQ;
            hi_s[g * GSTR + q * QSTR + cc] = h[(size_t)(r0 + g) * istr + c];
        }
        float sqi[GI];
        #pragma unroll
        for (int g = 0; g < GI; ++g) sqi[g] = sq[r0 + g];
        __syncthreads();

        const int jl = t >> 2;
        const int q  = t & 3;
        for (int jt = 0; jt < NP; jt += 64) {
            const float* pj = h + (size_t)(base + jt + jl) * istr + q * CQ;
            float4 hj[CQ / 4];
            #pragma unroll
            for (int u = 0; u < CQ / 4; ++u) hj[u] = *(const float4*)(pj + 4 * u);
            float p[GI];
            #pragma unroll
            for (int g = 0; g < GI; ++g) {
                const float* hs = &hi_s[g * GSTR + q * QSTR];
                float s = 0.f;
                #pragma unroll
                for (int u = 0; u < CQ / 4; ++u) {
                    float4 a = *(const float4*)(hs + 4 * u);
                    s += a.x*hj[u].x + a.y*hj[u].y + a.z*hj[u].z + a.w*hj[u].w;
                }
                p[g] = s;
            }
            #pragma unroll
            for (int g = 0; g < GI; ++g) {
                p[g] += __shfl_xor(p[g], 1);
                p[g] += __shfl_xor(p[g], 2);
            }
            if (q == 0) {
                int j = jt + jl;
                float sqj = sq[base + j];
                #pragma unroll
                for (int g = 0; g < GI; ++g)
                    negd[g][j] = 2.f * p[g] - sqi[g] - sqj;
            }
        }
    }
    __syncthreads();

    const int w = t >> 6;
    const int l = t & 63;
    float* row = &negd[w][0];
    for (int it = 0; it < KNN; ++it) {
        float bv = -FLT_MAX; int bi = NP;
        for (int j = l; j < NP; j += 64) {
            float v = row[j];
            if (v > bv) { bv = v; bi = j; }
        }
        #pragma unroll
        for (int off = 1; off < 64; off <<= 1) {
            float ov = __shfl_xor(bv, off);
            int   oi = __shfl_xor(bi, off);
            if (ov > bv || (ov == bv && oi < bi)) { bv = ov; bi = oi; }
        }
        if (l == 0) knn_idx[(size_t)(r0 + w) * KNN + it] = bi;
        if (l == (bi & 63)) row[bi] = -FLT_MAX;
    }
}

// ---------------------------------------------------------------- W hi/lo prep (edge W first halves)
__global__ __launch_bounds__(256) void wprep_kernel(const float* __restrict__ W,
                                                    int cin, int total,
                                                    short* __restrict__ whi,
                                                    short* __restrict__ wlo) {
    int e = blockIdx.x * 256 + threadIdx.x;
    if (e >= total) return;
    int o = e / cin, c = e - o * cin;
    float v = W[(size_t)o * (2 * cin) + c];
    unsigned h = f2bf_rne(v);
    float fh = bf2f(h);
    unsigned lo = __float_as_uint(v - fh) >> 16;   // truncate
    whi[e] = (short)h;
    wlo[e] = (short)lo;
}

// ---------------------------------------------------------------- Wf hi/lo prep (flat)
__global__ __launch_bounds__(256) void wfprep_kernel(const float* __restrict__ Wf,
                                                     short* __restrict__ whi,
                                                     short* __restrict__ wlo) {
    int e = blockIdx.x * 256 + threadIdx.x;        // < 1024*512
    float v = Wf[e];
    unsigned h = f2bf_rne(v);
    float fh = bf2f(h);
    unsigned lo = __float_as_uint(v - fh) >> 16;
    whi[e] = (short)h;
    wlo[e] = (short)lo;
}

// ---------------------------------------------------------------- ctr = W[:,C:2C]*h_i + b  (exact fp32)
template<int CIN, int COUT>
__global__ __launch_bounds__(256) void ctr_kernel(const float* __restrict__ h, int istr,
                                                  const float* __restrict__ W,
                                                  const float* __restrict__ bias,
                                                  float* __restrict__ ctr) {
    constexpr int PP = 256 / COUT;       // points per pass
    constexpr int R  = 4 / PP;           // passes
    __shared__ float hs[4][CIN];
    const int t  = threadIdx.x;
    const int r0 = blockIdx.x * 4;
    for (int e = t; e < 4 * CIN; e += 256) {
        int p = e / CIN, c = e - p * CIN;
        hs[p][c] = h[(size_t)(r0 + p) * istr + c];
    }
    __syncthreads();
    const int o  = t % COUT;
    const int pi = t / COUT;
    const float  bb = bias[o];
    const float* wr = W + (size_t)o * (2 * CIN) + CIN;
    #pragma unroll
    for (int rep = 0; rep < R; ++rep) {
        int p = rep * PP + pi;
        float s = bb;
        for (int c = 0; c < CIN; c += 4) {
            float4 wv = *(const float4*)(wr + c);
            float4 hv = *(const float4*)&hs[p][c];
            s += wv.x*hv.x + wv.y*hv.y + wv.z*hv.z + wv.w*hv.w;
        }
        ctr[(size_t)(r0 + p) * COUT + o] = s;
    }
}

// ---------------------------------------------------------------- EdgeConv via MFMA (bf16 hi/lo, 3-term)
template<int CIN, int COLS, int NTW>     // NTW = COLS/16/4 (N-tiles per wave)
__global__ __launch_bounds__(256) void edge_mfma(const float* __restrict__ hin, int istr,
                                                 const short* __restrict__ whi,
                                                 const short* __restrict__ wlo,
                                                 const float* __restrict__ ctr, int coutFull,
                                                 const int* __restrict__ knn_idx,
                                                 float* __restrict__ hout) {
    constexpr int ROWS  = 80;
    constexpr int PLANE = ROWS * CIN * 2;          // bytes per plane
    __shared__ short D[2 * ROWS * CIN];            // hi plane then lo plane
    __shared__ float hpt[4][CIN];
    __shared__ int   nj[4][KNN];

    const int t       = threadIdx.x;
    const int r0      = blockIdx.x * 4;
    const int base    = (r0 >> 11) << 11;
    const int colbase = blockIdx.y * COLS;

    for (int e = t; e < 4 * KNN; e += 256)
        nj[e / KNN][e % KNN] = knn_idx[(size_t)(r0 + e / KNN) * KNN + (e % KNN)];
    for (int e = t; e < 4 * CIN; e += 256)
        hpt[e / CIN][e % CIN] = hin[(size_t)(r0 + e / CIN) * istr + (e % CIN)];
    __syncthreads();

    constexpr int CP = CIN / 2;                    // float2 units per row
    char* Db = (char*)D;
    for (int u = t; u < ROWS * CP; u += 256) {
        int row = u / CP, cp = u - row * CP;
        int p = row / KNN, kk = row - p * KNN;
        const float* src = &hin[(size_t)(base + nj[p][kk]) * istr + cp * 2];
        float d0 = src[0] - hpt[p][cp * 2];
        float d1 = src[1] - hpt[p][cp * 2 + 1];
        unsigned h0 = f2bf_rne(d0), h1 = f2bf_rne(d1);
        unsigned l0 = __float_as_uint(d0 - bf2f(h0)) >> 16;
        unsigned l1 = __float_as_uint(d1 - bf2f(h1)) >> 16;
        int byte = row * (CIN * 2) + cp * 4;
        byte ^= ((row & 7) << 4);
        *(unsigned*)(Db + byte)         = h0 | (h1 << 16);
        *(unsigned*)(Db + PLANE + byte) = l0 | (l1 << 16);
    }
    __syncthreads();

    const int l = t & 63, w = t >> 6, g = l >> 4, cl = l & 15;

    f32x4 acc[5][NTW];
    #pragma unroll
    for (int mt = 0; mt < 5; ++mt)
        #pragma unroll
        for (int nt = 0; nt < NTW; ++nt)
            acc[mt][nt] = (f32x4){0.f, 0.f, 0.f, 0.f};

    #pragma unroll 1
    for (int term = 0; term < 3; ++term) {
        const char*  Ab = Db + (term == 2 ? PLANE : 0);
        const short* Bs = (term == 1) ? wlo : whi;
        #pragma unroll 1
        for (int kc = 0; kc < CIN / 32; ++kc) {
            const int k0 = kc * 32 + g * 8;
            short8 a[5];
            #pragma unroll
            for (int mt = 0; mt < 5; ++mt) {
                int row  = mt * 16 + cl;
                int byte = row * (CIN * 2) + k0 * 2;
                byte ^= ((row & 7) << 4);
                a[mt] = *(const short8*)(Ab + byte);
            }
            short8 bfr[NTW];
            #pragma unroll
            for (int nt = 0; nt < NTW; ++nt) {
                int o = colbase + (w * NTW + nt) * 16 + cl;
                bfr[nt] = *(const short8*)(Bs + (size_t)o * CIN + k0);
            }
            #pragma unroll
            for (int mt = 0; mt < 5; ++mt)
                #pragma unroll
                for (int nt = 0; nt < NTW; ++nt)
                    acc[mt][nt] = __builtin_amdgcn_mfma_f32_16x16x32_bf16(
                        a[mt], bfr[nt], acc[mt][nt], 0, 0, 0);
        }
    }

    #pragma unroll
    for (int nt = 0; nt < NTW; ++nt) {
        float cm[5];
        #pragma unroll
        for (int mt = 0; mt < 5; ++mt) {
            f32x4 v = acc[mt][nt];
            cm[mt] = fmaxf(fmaxf(v[0], v[1]), fmaxf(v[2], v[3]));
        }
        float pm0 = -FLT_MAX, pm1 = -FLT_MAX, pm2 = -FLT_MAX, pm3 = -FLT_MAX;
        #pragma unroll
        for (int mt = 0; mt < 5; ++mt) {
            int p = (4 * mt + g) / 5;
            pm0 = (p == 0) ? fmaxf(pm0, cm[mt]) : pm0;
            pm1 = (p == 1) ? fmaxf(pm1, cm[mt]) : pm1;
            pm2 = (p == 2) ? fmaxf(pm2, cm[mt]) : pm2;
            pm3 = (p == 3) ? fmaxf(pm3, cm[mt]) : pm3;
        }
        pm0 = fmaxf(pm0, __shfl_xor(pm0, 16)); pm0 = fmaxf(pm0, __shfl_xor(pm0, 32));
        pm1 = fmaxf(pm1, __shfl_xor(pm1, 16)); pm1 = fmaxf(pm1, __shfl_xor(pm1, 32));
        pm2 = fmaxf(pm2, __shfl_xor(pm2, 16)); pm2 = fmaxf(pm2, __shfl_xor(pm2, 32));
        pm3 = fmaxf(pm3, __shfl_xor(pm3, 16)); pm3 = fmaxf(pm3, __shfl_xor(pm3, 32));
        float pm  = (g == 0) ? pm0 : (g == 1) ? pm1 : (g == 2) ? pm2 : pm3;
        int   col = colbase + (w * NTW + nt) * 16 + cl;
        float val = pm + ctr[(size_t)(r0 + g) * coutFull + col];
        val = val > 0.f ? val : 0.2f * val;
        hout[(size_t)(r0 + g) * FSTR + col] = val;
    }
}

// ---------------------------------------------------------------- EdgeConv L0 (CIN=3, fp32 VALU)
template<int CIN, int COUT, int PPB>
__global__ __launch_bounds__(256) void edge_kernel(const float* __restrict__ hin,
                                                   int istr,
                                                   const float* __restrict__ W,
                                                   const float* __restrict__ bias,
                                                   const int* __restrict__ knn_idx,
                                                   float* __restrict__ hout) {
    constexpr int TPP = COUT / 2;
    static_assert(PPB * TPP == 256, "block must be 256 threads");
    __shared__ float diff[PPB][KNN][CIN];
    __shared__ float hi[PPB][CIN];
    __shared__ int   nj[PPB][KNN];

    const int t    = threadIdx.x;
    const int r0   = blockIdx.x * PPB;
    const int base = (r0 >> 11) << 11;

    for (int e = t; e < PPB * KNN; e += 256) {
        int p = e / KNN, kk = e - p * KNN;
        nj[p][kk] = knn_idx[(size_t)(r0 + p) * KNN + kk];
    }
    for (int e = t; e < PPB * CIN; e += 256) {
        int p = e / CIN, c = e - p * CIN;
        hi[p][c] = hin[(size_t)(r0 + p) * istr + c];
    }
    __syncthreads();
    for (int e = t; e < PPB * KNN * CIN; e += 256) {
        int p  = e / (KNN * CIN);
        int rm = e - p * (KNN * CIN);
        int kk = rm / CIN, c = rm - kk * CIN;
        diff[p][kk][c] = hin[(size_t)(base + nj[p][kk]) * istr + c] - hi[p][c];
    }
    __syncthreads();

    const int p  = t / TPP;
    const int oo = t - p * TPP;
    const float* W0 = W + (size_t)oo * (2 * CIN);
    const float* W1 = W + (size_t)(oo + TPP) * (2 * CIN);

    float ctr0 = bias[oo], ctr1 = bias[oo + TPP];
    float acc[2][KNN];
    #pragma unroll
    for (int kk = 0; kk < KNN; ++kk) { acc[0][kk] = 0.f; acc[1][kk] = 0.f; }

    for (int c = 0; c < CIN; ++c) {
        float hv = hi[p][c];
        ctr0 += W0[CIN + c] * hv;
        ctr1 += W1[CIN + c] * hv;
    }
    for (int c = 0; c < CIN; ++c) {
        float w0 = W0[c], w1 = W1[c];
        #pragma unroll
        for (int kk = 0; kk < KNN; ++kk) {
            float d = diff[p][kk][c];
            acc[0][kk] += w0 * d;
            acc[1][kk] += w1 * d;
        }
    }

    float m0 = -FLT_MAX, m1 = -FLT_MAX;
    #pragma unroll
    for (int kk = 0; kk < KNN; ++kk) {
        m0 = fmaxf(m0, acc[0][kk] + ctr0);
        m1 = fmaxf(m1, acc[1][kk] + ctr1);
    }
    float r0v = m0 > 0.f ? m0 : 0.2f * m0;
    float r1v = m1 > 0.f ? m1 : 0.2f * m1;
    hout[(size_t)(r0 + p) * FSTR + oo]       = r0v;
    hout[(size_t)(r0 + p) * FSTR + oo + TPP] = r1v;
}

// ---------------------------------------------------------------- final GEMM via MFMA (bf16 hi/lo, 3-term) + col-max
// Block: 64 f-rows x 128 out-cols. K=512 in 8 chunks of 64. partial[mb][col] = max over 64 rows.
__global__ __launch_bounds__(256) void final_mfma(const float* __restrict__ f,
                                                  const short* __restrict__ wfhi,
                                                  const short* __restrict__ wflo,
                                                  float* __restrict__ partial) {
    constexpr int PLANE = 64 * 64 * 2;             // bytes per plane
    __shared__ short A[2 * 64 * 64];               // hi plane then lo plane (16 KB)
    const int t    = threadIdx.x;
    const int mb   = blockIdx.x;                   // 0..2047 (64-row chunk)
    const int ny   = blockIdx.y;                   // 0..7 (128-col chunk)
    const int row0 = mb * 64;
    const int l = t & 63, w = t >> 6, g = l >> 4, cl = l & 15;

    f32x4 acc[4][2];
    #pragma unroll
    for (int mt = 0; mt < 4; ++mt)
        #pragma unroll
        for (int nt = 0; nt < 2; ++nt)
            acc[mt][nt] = (f32x4){0.f, 0.f, 0.f, 0.f};

    char* Ab = (char*)A;
    #pragma unroll 1
    for (int kc = 0; kc < 8; ++kc) {
        for (int u = t; u < 64 * 32; u += 256) {   // 64 rows x 32 float2
            int row = u >> 5, cp = u & 31;
            const float* src = &f[(size_t)(row0 + row) * FSTR + kc * 64 + cp * 2];
            float d0 = src[0], d1 = src[1];
            unsigned h0 = f2bf_rne(d0), h1 = f2bf_rne(d1);
            unsigned l0 = __float_as_uint(d0 - bf2f(h0)) >> 16;
            unsigned l1 = __float_as_uint(d1 - bf2f(h1)) >> 16;
            int byte = row * 128 + cp * 4;
            byte ^= ((row & 7) << 4);
            *(unsigned*)(Ab + byte)         = h0 | (h1 << 16);
            *(unsigned*)(Ab + PLANE + byte) = l0 | (l1 << 16);
        }
        __syncthreads();

        short8 bh[2][2], bl[2][2];                 // [ks][nt]
        #pragma unroll
        for (int ks = 0; ks < 2; ++ks)
            #pragma unroll
            for (int nt = 0; nt < 2; ++nt) {
                int o = ny * 128 + (w * 2 + nt) * 16 + cl;
                size_t koff = (size_t)o * 512 + kc * 64 + ks * 32 + g * 8;
                bh[ks][nt] = *(const short8*)(wfhi + koff);
                bl[ks][nt] = *(const short8*)(wflo + koff);
            }
        short8 ah[2][4];                           // [ks][mt]
        #pragma unroll
        for (int ks = 0; ks < 2; ++ks)
            #pragma unroll
            for (int mt = 0; mt < 4; ++mt) {
                int row  = mt * 16 + cl;
                int byte = row * 128 + (ks * 32 + g * 8) * 2;
                byte ^= ((row & 7) << 4);
                ah[ks][mt] = *(const short8*)(Ab + byte);
            }
        #pragma unroll
        for (int ks = 0; ks < 2; ++ks)
            #pragma unroll
            for (int mt = 0; mt < 4; ++mt)
                #pragma unroll
                for (int nt = 0; nt < 2; ++nt)
                    acc[mt][nt] = __builtin_amdgcn_mfma_f32_16x16x32_bf16(
                        ah[ks][mt], bh[ks][nt], acc[mt][nt], 0, 0, 0);
        #pragma unroll
        for (int ks = 0; ks < 2; ++ks)
            #pragma unroll
            for (int mt = 0; mt < 4; ++mt)
                #pragma unroll
                for (int nt = 0; nt < 2; ++nt)
                    acc[mt][nt] = __builtin_amdgcn_mfma_f32_16x16x32_bf16(
                        ah[ks][mt], bl[ks][nt], acc[mt][nt], 0, 0, 0);
        short8 al[2][4];
        #pragma unroll
        for (int ks = 0; ks < 2; ++ks)
            #pragma unroll
            for (int mt = 0; mt < 4; ++mt) {
                int row  = mt * 16 + cl;
                int byte = row * 128 + (ks * 32 + g * 8) * 2;
                byte ^= ((row & 7) << 4);
                al[ks][mt] = *(const short8*)(Ab + PLANE + byte);
            }
        #pragma unroll
        for (int ks = 0; ks < 2; ++ks)
            #pragma unroll
            for (int mt = 0; mt < 4; ++mt)
                #pragma unroll
                for (int nt = 0; nt < 2; ++nt)
                    acc[mt][nt] = __builtin_amdgcn_mfma_f32_16x16x32_bf16(
                        al[ks][mt], bh[ks][nt], acc[mt][nt], 0, 0, 0);
        __syncthreads();
    }

    // epilogue: per column, max over the block's 64 rows
    #pragma unroll
    for (int nt = 0; nt < 2; ++nt) {
        float pm = -FLT_MAX;
        #pragma unroll
        for (int mt = 0; mt < 4; ++mt) {
            f32x4 v = acc[mt][nt];
            pm = fmaxf(pm, fmaxf(fmaxf(v[0], v[1]), fmaxf(v[2], v[3])));
        }
        pm = fmaxf(pm, __shfl_xor(pm, 16));
        pm = fmaxf(pm, __shfl_xor(pm, 32));
        if (g == 0) {
            int col = ny * 128 + (w * 2 + nt) * 16 + cl;
            partial[(size_t)mb * 1024 + col] = pm;
        }
    }
}

__global__ __launch_bounds__(256) void final_reduce(const float* __restrict__ partial,
                                                    const float* __restrict__ bf,
                                                    float* __restrict__ out) {
    int g = blockIdx.x * 256 + threadIdx.x;        // 8192
    int b = g >> 10, o = g & 1023;
    float m = -FLT_MAX;
    for (int mb = 0; mb < 32; ++mb)
        m = fmaxf(m, partial[((size_t)(b * 32 + mb)) * 1024 + o]);
    out[g] = m + bf[o];
}

// ---------------------------------------------------------------- launch
extern "C" void kernel_launch(void* const* d_in, const int* in_sizes, int n_in,
                              void* d_out, int out_size, void* d_ws, size_t ws_size,
                              hipStream_t stream) {
    const float* x  = (const float*)d_in[0];
    const float* W0 = (const float*)d_in[1];
    const float* b0 = (const float*)d_in[2];
    const float* W1 = (const float*)d_in[3];
    const float* b1 = (const float*)d_in[4];
    const float* W2 = (const float*)d_in[5];
    const float* b2 = (const float*)d_in[6];
    const float* W3 = (const float*)d_in[7];
    const float* b3 = (const float*)d_in[8];
    const float* Wf = (const float*)d_in[9];
    const float* bf = (const float*)d_in[10];
    (void)in_sizes; (void)n_in; (void)out_size; (void)ws_size;

    char* ws = (char*)d_ws;
    size_t off = 0;
    float* feats   = (float*)(ws + off); off += (size_t)BN * FSTR * 4;      // 32 MB
    float* sq      = (float*)(ws + off); off += (size_t)BN * 4;             // 64 KB
    int*   idx     = (int*)  (ws + off); off += (size_t)BN * KNN * 4;       // 1.25 MB
    float* ctrbuf  = (float*)(ws + off); off += (size_t)BN * 256 * 4;       // 16 MB
    float* partial = ctrbuf;                       // aliased: ctr done before final GEMM
    short* whi     = (short*)(ws + off); off += (size_t)45056 * 2;          // edge W hi planes
    short* wlo     = (short*)(ws + off); off += (size_t)45056 * 2;          // edge W lo planes
    short* wfhi    = (short*)(ws + off); off += (size_t)1024 * 512 * 2;     // 1 MB
    short* wflo    = (short*)(ws + off); off += (size_t)1024 * 512 * 2;     // 1 MB
    short* w1hi = whi,          *w1lo = wlo;                                // 64x64
    short* w2hi = whi + 4096,   *w2lo = wlo + 4096;                         // 128x64
    short* w3hi = whi + 12288,  *w3lo = wlo + 12288;                        // 256x128

    // W hi/lo prep
    wprep_kernel<<<16, 256, 0, stream>>>(W1, 64, 64 * 64, w1hi, w1lo);
    wprep_kernel<<<32, 256, 0, stream>>>(W2, 64, 128 * 64, w2hi, w2lo);
    wprep_kernel<<<128, 256, 0, stream>>>(W3, 128, 256 * 128, w3hi, w3lo);
    wfprep_kernel<<<2048, 256, 0, stream>>>(Wf, wfhi, wflo);

    // Layer 0: C=3 -> 64 @ feats[0:64]  (fp32 VALU)
    sq_kernel<3><<<BN / 256, 256, 0, stream>>>(x, 3, sq);
    knn_kernel<3><<<BN / 4, 256, 0, stream>>>(x, 3, sq, idx);
    edge_kernel<3, 64, 8><<<BN / 8, 256, 0, stream>>>(x, 3, W0, b0, idx, feats + 0);

    // Layer 1: 64 -> 64 @ feats[64:128]
    sq_kernel<64><<<BN / 256, 256, 0, stream>>>(feats + 0, FSTR, sq);
    knn_kernel<64><<<BN / 4, 256, 0, stream>>>(feats + 0, FSTR, sq, idx);
    ctr_kernel<64, 64><<<BN / 4, 256, 0, stream>>>(feats + 0, FSTR, W1, b1, ctrbuf);
    edge_mfma<64, 64, 1><<<dim3(BN / 4, 1), 256, 0, stream>>>(
        feats + 0, FSTR, w1hi, w1lo, ctrbuf, 64, idx, feats + 64);

    // Layer 2: 64 -> 128 @ feats[128:256]
    sq_kernel<64><<<BN / 256, 256, 0, stream>>>(feats + 64, FSTR, sq);
    knn_kernel<64><<<BN / 4, 256, 0, stream>>>(feats + 64, FSTR, sq, idx);
    ctr_kernel<64, 128><<<BN / 4, 256, 0, stream>>>(feats + 64, FSTR, W2, b2, ctrbuf);
    edge_mfma<64, 128, 2><<<dim3(BN / 4, 1), 256, 0, stream>>>(
        feats + 64, FSTR, w2hi, w2lo, ctrbuf, 128, idx, feats + 128);

    // Layer 3: 128 -> 256 @ feats[256:512]
    sq_kernel<128><<<BN / 256, 256, 0, stream>>>(feats + 128, FSTR, sq);
    knn_kernel<128><<<BN / 4, 256, 0, stream>>>(feats + 128, FSTR, sq, idx);
    ctr_kernel<128, 256><<<BN / 4, 256, 0, stream>>>(feats + 128, FSTR, W3, b3, ctrbuf);
    edge_mfma<128, 128, 2><<<dim3(BN / 4, 2), 256, 0, stream>>>(
        feats + 128, FSTR, w3hi, w3lo, ctrbuf, 256, idx, feats + 256);

    // Final 512 -> 1024 + global max pool (MFMA)
    final_mfma<<<dim3(BN / 64, 8), 256, 0, stream>>>(feats, wfhi, wflo, partial);
    final_reduce<<<32, 256, 0, stream>>>(partial, bf, (float*)d_out);
}

// Round 9
// 1955.943 us; speedup vs baseline: 2.2252x; 1.3274x over previous
//
#include <hip/hip_runtime.h>
#include <float.h>

constexpr int NB   = 8;      // batches
constexpr int NP   = 2048;   // points per batch
constexpr int BN   = NB * NP;
constexpr int KNN  = 20;     // neighbors
constexpr int FSTR = 512;    // feats row stride (64+64+128+256)

typedef short short8 __attribute__((ext_vector_type(8)));
typedef float f32x4  __attribute__((ext_vector_type(4)));

__device__ __forceinline__ unsigned f2bf_rne(float x) {
    unsigned u = __float_as_uint(x);
    unsigned r = (u >> 16) & 1;
    return (u + 0x7fffu + r) >> 16;
}
__device__ __forceinline__ float bf2f(unsigned h) { return __uint_as_float(h << 16); }

// ---------------------------------------------------------------- sq = |h|^2
template<int C>
__global__ __launch_bounds__(256) void sq_kernel(const float* __restrict__ h,
                                                 int istr,
                                                 float* __restrict__ sq) {
    int i = blockIdx.x * 256 + threadIdx.x;
    if (i >= BN) return;
    const float* p = h + (size_t)i * istr;
    float s = 0.f;
    #pragma unroll
    for (int c = 0; c < C; ++c) { float v = p[c]; s += v * v; }
    sq[i] = s;
}

// ---------------------------------------------------------------- kNN top-20 (C=3 path)
template<int C>
__global__ __launch_bounds__(256) void knn_kernel(const float* __restrict__ h,
                                                  int istr,
                                                  const float* __restrict__ sq,
                                                  int* __restrict__ knn_idx) {
    constexpr int GI = 4;
    __shared__ float negd[GI][NP];          // 32 KB
    const int t    = threadIdx.x;
    const int r0   = blockIdx.x * GI;
    const int base = (r0 >> 11) << 11;

    float hi[GI][3], sqi[GI];
    #pragma unroll
    for (int g = 0; g < GI; ++g) {
        const float* p = h + (size_t)(r0 + g) * istr;
        hi[g][0] = p[0]; hi[g][1] = p[1]; hi[g][2] = p[2];
        sqi[g] = sq[r0 + g];
    }
    for (int j = t; j < NP; j += 256) {
        const float* pj = h + (size_t)(base + j) * istr;
        float x0 = pj[0], x1 = pj[1], x2 = pj[2];
        float sqj = sq[base + j];
        #pragma unroll
        for (int g = 0; g < GI; ++g) {
            float d = hi[g][0]*x0 + hi[g][1]*x1 + hi[g][2]*x2;
            negd[g][j] = 2.f * d - sqi[g] - sqj;
        }
    }
    __syncthreads();

    const int w = t >> 6;
    const int l = t & 63;
    float* row = &negd[w][0];
    for (int it = 0; it < KNN; ++it) {
        float bv = -FLT_MAX; int bi = NP;
        for (int j = l; j < NP; j += 64) {
            float v = row[j];
            if (v > bv) { bv = v; bi = j; }
        }
        #pragma unroll
        for (int off = 1; off < 64; off <<= 1) {
            float ov = __shfl_xor(bv, off);
            int   oi = __shfl_xor(bi, off);
            if (ov > bv || (ov == bv && oi < bi)) { bv = ov; bi = oi; }
        }
        if (l == 0) knn_idx[(size_t)(r0 + w) * KNN + it] = bi;
        if (l == (bi & 63)) row[bi] = -FLT_MAX;
    }
}

// ---------------------------------------------------------------- kNN top-20 v3 (C=64/128)
// 512 thr / 8 rows. Wave w owns j-slices {w*64+p*512}; j-row streamed into regs
// (read once per block); i-rows read via wave-uniform addresses (scalarizable).
// Selection: row cached in 32 regs/lane, two-half incremental argmax.
template<int C>
__global__ __launch_bounds__(512) void knn3_kernel(const float* __restrict__ h, int istr,
                                                   const float* __restrict__ sq,
                                                   int* __restrict__ knn_idx) {
    __shared__ float negd[8][NP];                  // 64 KB
    const int t      = threadIdx.x;
    const int batch  = blockIdx.x & 7;             // XCD-pinned batch
    const int within = blockIdx.x >> 3;
    const int r0     = batch * NP + within * 8;
    const int base   = batch * NP;
    const int w = t >> 6, l = t & 63;
    constexpr int KQ = C / 4;                      // floats per k-quarter

    float sqi[8];
    #pragma unroll
    for (int i = 0; i < 8; ++i) sqi[i] = sq[r0 + i];

    #pragma unroll 1
    for (int p = 0; p < 4; ++p) {
        const int j = w * 64 + p * 512 + l;
        const float* bj = h + (size_t)(base + j) * istr;
        float acc[8];
        #pragma unroll
        for (int i = 0; i < 8; ++i) acc[i] = 0.f;
        #pragma unroll 1
        for (int kq = 0; kq < 4; ++kq) {
            float4 breg[KQ / 4];
            #pragma unroll
            for (int u = 0; u < KQ / 4; ++u)
                breg[u] = *(const float4*)(bj + kq * KQ + 4 * u);
            #pragma unroll
            for (int i = 0; i < 8; ++i) {
                const float* ar = h + (size_t)(r0 + i) * istr + kq * KQ;  // uniform
                float s = acc[i];
                #pragma unroll
                for (int u = 0; u < KQ / 4; ++u) {
                    s += ar[4*u+0] * breg[u].x;
                    s += ar[4*u+1] * breg[u].y;
                    s += ar[4*u+2] * breg[u].z;
                    s += ar[4*u+3] * breg[u].w;
                }
                acc[i] = s;
            }
        }
        float sqj = sq[base + j];
        #pragma unroll
        for (int i = 0; i < 8; ++i)
            negd[i][j] = 2.f * acc[i] - sqi[i] - sqj;
    }
    __syncthreads();

    // ---- selection: wave w owns row w; 32 values/lane in regs.
    const float* row = &negd[w][0];
    float v[32];
    #pragma unroll
    for (int u = 0; u < 32; ++u) v[u] = row[l + 64 * u];
    float m0 = v[0], m1 = v[16];
    int   u0 = 0,    u1 = 16;
    #pragma unroll
    for (int u = 1; u < 16; ++u)  { if (v[u] > m0) { m0 = v[u]; u0 = u; } }
    #pragma unroll
    for (int u = 17; u < 32; ++u) { if (v[u] > m1) { m1 = v[u]; u1 = u; } }

    int* out = knn_idx + (size_t)(r0 + w) * KNN;
    for (int it = 0; it < KNN; ++it) {
        float bv; int bu;
        if (m0 >= m1) { bv = m0; bu = u0; } else { bv = m1; bu = u1; }
        int bj = l + (bu << 6);
        #pragma unroll
        for (int off = 1; off < 64; off <<= 1) {
            float ov = __shfl_xor(bv, off);
            int   oj = __shfl_xor(bj, off);
            if (ov > bv || (ov == bv && oj < bj)) { bv = ov; bj = oj; }
        }
        if (l == 0) out[it] = bj;
        const int  ur  = bj >> 6;                  // wave-uniform
        const bool own = ((bj & 63) == l);
        if (ur < 16) {
            #pragma unroll
            for (int u = 0; u < 16; ++u)
                if (own && u == ur) v[u] = -FLT_MAX;
            m0 = v[0]; u0 = 0;
            #pragma unroll
            for (int u = 1; u < 16; ++u) if (v[u] > m0) { m0 = v[u]; u0 = u; }
        } else {
            #pragma unroll
            for (int u = 16; u < 32; ++u)
                if (own && u == ur) v[u] = -FLT_MAX;
            m1 = v[16]; u1 = 16;
            #pragma unroll
            for (int u = 17; u < 32; ++u) if (v[u] > m1) { m1 = v[u]; u1 = u; }
        }
    }
}

// ---------------------------------------------------------------- W hi/lo prep (edge W first halves)
__global__ __launch_bounds__(256) void wprep_kernel(const float* __restrict__ W,
                                                    int cin, int total,
                                                    short* __restrict__ whi,
                                                    short* __restrict__ wlo) {
    int e = blockIdx.x * 256 + threadIdx.x;
    if (e >= total) return;
    int o = e / cin, c = e - o * cin;
    float v = W[(size_t)o * (2 * cin) + c];
    unsigned h = f2bf_rne(v);
    float fh = bf2f(h);
    unsigned lo = __float_as_uint(v - fh) >> 16;   // truncate
    whi[e] = (short)h;
    wlo[e] = (short)lo;
}

// ---------------------------------------------------------------- Wf hi/lo prep (flat)
__global__ __launch_bounds__(256) void wfprep_kernel(const float* __restrict__ Wf,
                                                     short* __restrict__ whi,
                                                     short* __restrict__ wlo) {
    int e = blockIdx.x * 256 + threadIdx.x;        // < 1024*512
    float v = Wf[e];
    unsigned h = f2bf_rne(v);
    float fh = bf2f(h);
    unsigned lo = __float_as_uint(v - fh) >> 16;
    whi[e] = (short)h;
    wlo[e] = (short)lo;
}

// ---------------------------------------------------------------- ctr = W[:,C:2C]*h_i + b  (exact fp32)
template<int CIN, int COUT>
__global__ __launch_bounds__(256) void ctr_kernel(const float* __restrict__ h, int istr,
                                                  const float* __restrict__ W,
                                                  const float* __restrict__ bias,
                                                  float* __restrict__ ctr) {
    constexpr int PP = 256 / COUT;       // points per pass
    constexpr int R  = 4 / PP;           // passes
    __shared__ float hs[4][CIN];
    const int t  = threadIdx.x;
    const int r0 = blockIdx.x * 4;
    for (int e = t; e < 4 * CIN; e += 256) {
        int p = e / CIN, c = e - p * CIN;
        hs[p][c] = h[(size_t)(r0 + p) * istr + c];
    }
    __syncthreads();
    const int o  = t % COUT;
    const int pi = t / COUT;
    const float  bb = bias[o];
    const float* wr = W + (size_t)o * (2 * CIN) + CIN;
    #pragma unroll
    for (int rep = 0; rep < R; ++rep) {
        int p = rep * PP + pi;
        float s = bb;
        for (int c = 0; c < CIN; c += 4) {
            float4 wv = *(const float4*)(wr + c);
            float4 hv = *(const float4*)&hs[p][c];
            s += wv.x*hv.x + wv.y*hv.y + wv.z*hv.z + wv.w*hv.w;
        }
        ctr[(size_t)(r0 + p) * COUT + o] = s;
    }
}

// ---------------------------------------------------------------- EdgeConv via MFMA (bf16 hi/lo, 3-term)
template<int CIN, int COLS, int NTW>     // NTW = COLS/16/4 (N-tiles per wave)
__global__ __launch_bounds__(256) void edge_mfma(const float* __restrict__ hin, int istr,
                                                 const short* __restrict__ whi,
                                                 const short* __restrict__ wlo,
                                                 const float* __restrict__ ctr, int coutFull,
                                                 const int* __restrict__ knn_idx,
                                                 float* __restrict__ hout) {
    constexpr int ROWS  = 80;
    constexpr int PLANE = ROWS * CIN * 2;          // bytes per plane
    __shared__ short D[2 * ROWS * CIN];            // hi plane then lo plane
    __shared__ float hpt[4][CIN];
    __shared__ int   nj[4][KNN];

    const int t       = threadIdx.x;
    const int r0      = blockIdx.x * 4;
    const int base    = (r0 >> 11) << 11;
    const int colbase = blockIdx.y * COLS;

    for (int e = t; e < 4 * KNN; e += 256)
        nj[e / KNN][e % KNN] = knn_idx[(size_t)(r0 + e / KNN) * KNN + (e % KNN)];
    for (int e = t; e < 4 * CIN; e += 256)
        hpt[e / CIN][e % CIN] = hin[(size_t)(r0 + e / CIN) * istr + (e % CIN)];
    __syncthreads();

    constexpr int CP = CIN / 2;                    // float2 units per row
    char* Db = (char*)D;
    for (int u = t; u < ROWS * CP; u += 256) {
        int row = u / CP, cp = u - row * CP;
        int p = row / KNN, kk = row - p * KNN;
        const float* src = &hin[(size_t)(base + nj[p][kk]) * istr + cp * 2];
        float d0 = src[0] - hpt[p][cp * 2];
        float d1 = src[1] - hpt[p][cp * 2 + 1];
        unsigned h0 = f2bf_rne(d0), h1 = f2bf_rne(d1);
        unsigned l0 = __float_as_uint(d0 - bf2f(h0)) >> 16;
        unsigned l1 = __float_as_uint(d1 - bf2f(h1)) >> 16;
        int byte = row * (CIN * 2) + cp * 4;
        byte ^= ((row & 7) << 4);
        *(unsigned*)(Db + byte)         = h0 | (h1 << 16);
        *(unsigned*)(Db + PLANE + byte) = l0 | (l1 << 16);
    }
    __syncthreads();

    const int l = t & 63, w = t >> 6, g = l >> 4, cl = l & 15;

    f32x4 acc[5][NTW];
    #pragma unroll
    for (int mt = 0; mt < 5; ++mt)
        #pragma unroll
        for (int nt = 0; nt < NTW; ++nt)
            acc[mt][nt] = (f32x4){0.f, 0.f, 0.f, 0.f};

    #pragma unroll 1
    for (int term = 0; term < 3; ++term) {
        const char*  Ab = Db + (term == 2 ? PLANE : 0);
        const short* Bs = (term == 1) ? wlo : whi;
        #pragma unroll 1
        for (int kc = 0; kc < CIN / 32; ++kc) {
            const int k0 = kc * 32 + g * 8;
            short8 a[5];
            #pragma unroll
            for (int mt = 0; mt < 5; ++mt) {
                int row  = mt * 16 + cl;
                int byte = row * (CIN * 2) + k0 * 2;
                byte ^= ((row & 7) << 4);
                a[mt] = *(const short8*)(Ab + byte);
            }
            short8 bfr[NTW];
            #pragma unroll
            for (int nt = 0; nt < NTW; ++nt) {
                int o = colbase + (w * NTW + nt) * 16 + cl;
                bfr[nt] = *(const short8*)(Bs + (size_t)o * CIN + k0);
            }
            #pragma unroll
            for (int mt = 0; mt < 5; ++mt)
                #pragma unroll
                for (int nt = 0; nt < NTW; ++nt)
                    acc[mt][nt] = __builtin_amdgcn_mfma_f32_16x16x32_bf16(
                        a[mt], bfr[nt], acc[mt][nt], 0, 0, 0);
        }
    }

    #pragma unroll
    for (int nt = 0; nt < NTW; ++nt) {
        float cm[5];
        #pragma unroll
        for (int mt = 0; mt < 5; ++mt) {
            f32x4 v = acc[mt][nt];
            cm[mt] = fmaxf(fmaxf(v[0], v[1]), fmaxf(v[2], v[3]));
        }
        float pm0 = -FLT_MAX, pm1 = -FLT_MAX, pm2 = -FLT_MAX, pm3 = -FLT_MAX;
        #pragma unroll
        for (int mt = 0; mt < 5; ++mt) {
            int p = (4 * mt + g) / 5;
            pm0 = (p == 0) ? fmaxf(pm0, cm[mt]) : pm0;
            pm1 = (p == 1) ? fmaxf(pm1, cm[mt]) : pm1;
            pm2 = (p == 2) ? fmaxf(pm2, cm[mt]) : pm2;
            pm3 = (p == 3) ? fmaxf(pm3, cm[mt]) : pm3;
        }
        pm0 = fmaxf(pm0, __shfl_xor(pm0, 16)); pm0 = fmaxf(pm0, __shfl_xor(pm0, 32));
        pm1 = fmaxf(pm1, __shfl_xor(pm1, 16)); pm1 = fmaxf(pm1, __shfl_xor(pm1, 32));
        pm2 = fmaxf(pm2, __shfl_xor(pm2, 16)); pm2 = fmaxf(pm2, __shfl_xor(pm2, 32));
        pm3 = fmaxf(pm3, __shfl_xor(pm3, 16)); pm3 = fmaxf(pm3, __shfl_xor(pm3, 32));
        float pm  = (g == 0) ? pm0 : (g == 1) ? pm1 : (g == 2) ? pm2 : pm3;
        int   col = colbase + (w * NTW + nt) * 16 + cl;
        float val = pm + ctr[(size_t)(r0 + g) * coutFull + col];
        val = val > 0.f ? val : 0.2f * val;
        hout[(size_t)(r0 + g) * FSTR + col] = val;
    }
}

// ---------------------------------------------------------------- EdgeConv L0 (CIN=3, fp32 VALU)
template<int CIN, int COUT, int PPB>
__global__ __launch_bounds__(256) void edge_kernel(const float* __restrict__ hin,
                                                   int istr,
                                                   const float* __restrict__ W,
                                                   const float* __restrict__ bias,
                                                   const int* __restrict__ knn_idx,
                                                   float* __restrict__ hout) {
    constexpr int TPP = COUT / 2;
    static_assert(PPB * TPP == 256, "block must be 256 threads");
    __shared__ float diff[PPB][KNN][CIN];
    __shared__ float hi[PPB][CIN];
    __shared__ int   nj[PPB][KNN];

    const int t    = threadIdx.x;
    const int r0   = blockIdx.x * PPB;
    const int base = (r0 >> 11) << 11;

    for (int e = t; e < PPB * KNN; e += 256) {
        int p = e / KNN, kk = e - p * KNN;
        nj[p][kk] = knn_idx[(size_t)(r0 + p) * KNN + kk];
    }
    for (int e = t; e < PPB * CIN; e += 256) {
        int p = e / CIN, c = e - p * CIN;
        hi[p][c] = hin[(size_t)(r0 + p) * istr + c];
    }
    __syncthreads();
    for (int e = t; e < PPB * KNN * CIN; e += 256) {
        int p  = e / (KNN * CIN);
        int rm = e - p * (KNN * CIN);
        int kk = rm / CIN, c = rm - kk * CIN;
        diff[p][kk][c] = hin[(size_t)(base + nj[p][kk]) * istr + c] - hi[p][c];
    }
    __syncthreads();

    const int p  = t / TPP;
    const int oo = t - p * TPP;
    const float* W0 = W + (size_t)oo * (2 * CIN);
    const float* W1 = W + (size_t)(oo + TPP) * (2 * CIN);

    float ctr0 = bias[oo], ctr1 = bias[oo + TPP];
    float acc[2][KNN];
    #pragma unroll
    for (int kk = 0; kk < KNN; ++kk) { acc[0][kk] = 0.f; acc[1][kk] = 0.f; }

    for (int c = 0; c < CIN; ++c) {
        float hv = hi[p][c];
        ctr0 += W0[CIN + c] * hv;
        ctr1 += W1[CIN + c] * hv;
    }
    for (int c = 0; c < CIN; ++c) {
        float w0 = W0[c], w1 = W1[c];
        #pragma unroll
        for (int kk = 0; kk < KNN; ++kk) {
            float d = diff[p][kk][c];
            acc[0][kk] += w0 * d;
            acc[1][kk] += w1 * d;
        }
    }

    float m0 = -FLT_MAX, m1 = -FLT_MAX;
    #pragma unroll
    for (int kk = 0; kk < KNN; ++kk) {
        m0 = fmaxf(m0, acc[0][kk] + ctr0);
        m1 = fmaxf(m1, acc[1][kk] + ctr1);
    }
    float r0v = m0 > 0.f ? m0 : 0.2f * m0;
    float r1v = m1 > 0.f ? m1 : 0.2f * m1;
    hout[(size_t)(r0 + p) * FSTR + oo]       = r0v;
    hout[(size_t)(r0 + p) * FSTR + oo + TPP] = r1v;
}

// ---------------------------------------------------------------- final GEMM via MFMA (bf16 hi/lo, 3-term) + col-max
__global__ __launch_bounds__(256) void final_mfma(const float* __restrict__ f,
                                                  const short* __restrict__ wfhi,
                                                  const short* __restrict__ wflo,
                                                  float* __restrict__ partial) {
    constexpr int PLANE = 64 * 64 * 2;             // bytes per plane
    __shared__ short A[2 * 64 * 64];               // hi plane then lo plane (16 KB)
    const int t    = threadIdx.x;
    const int mb   = blockIdx.x;                   // 0..2047 (64-row chunk)
    const int ny   = blockIdx.y;                   // 0..7 (128-col chunk)
    const int row0 = mb * 64;
    const int l = t & 63, w = t >> 6, g = l >> 4, cl = l & 15;

    f32x4 acc[4][2];
    #pragma unroll
    for (int mt = 0; mt < 4; ++mt)
        #pragma unroll
        for (int nt = 0; nt < 2; ++nt)
            acc[mt][nt] = (f32x4){0.f, 0.f, 0.f, 0.f};

    char* Ab = (char*)A;
    #pragma unroll 1
    for (int kc = 0; kc < 8; ++kc) {
        for (int u = t; u < 64 * 32; u += 256) {   // 64 rows x 32 float2
            int row = u >> 5, cp = u & 31;
            const float* src = &f[(size_t)(row0 + row) * FSTR + kc * 64 + cp * 2];
            float d0 = src[0], d1 = src[1];
            unsigned h0 = f2bf_rne(d0), h1 = f2bf_rne(d1);
            unsigned l0 = __float_as_uint(d0 - bf2f(h0)) >> 16;
            unsigned l1 = __float_as_uint(d1 - bf2f(h1)) >> 16;
            int byte = row * 128 + cp * 4;
            byte ^= ((row & 7) << 4);
            *(unsigned*)(Ab + byte)         = h0 | (h1 << 16);
            *(unsigned*)(Ab + PLANE + byte) = l0 | (l1 << 16);
        }
        __syncthreads();

        short8 bh[2][2], bl[2][2];                 // [ks][nt]
        #pragma unroll
        for (int ks = 0; ks < 2; ++ks)
            #pragma unroll
            for (int nt = 0; nt < 2; ++nt) {
                int o = ny * 128 + (w * 2 + nt) * 16 + cl;
                size_t koff = (size_t)o * 512 + kc * 64 + ks * 32 + g * 8;
                bh[ks][nt] = *(const short8*)(wfhi + koff);
                bl[ks][nt] = *(const short8*)(wflo + koff);
            }
        short8 ah[2][4];                           // [ks][mt]
        #pragma unroll
        for (int ks = 0; ks < 2; ++ks)
            #pragma unroll
            for (int mt = 0; mt < 4; ++mt) {
                int row  = mt * 16 + cl;
                int byte = row * 128 + (ks * 32 + g * 8) * 2;
                byte ^= ((row & 7) << 4);
                ah[ks][mt] = *(const short8*)(Ab + byte);
            }
        #pragma unroll
        for (int ks = 0; ks < 2; ++ks)
            #pragma unroll
            for (int mt = 0; mt < 4; ++mt)
                #pragma unroll
                for (int nt = 0; nt < 2; ++nt)
                    acc[mt][nt] = __builtin_amdgcn_mfma_f32_16x16x32_bf16(
                        ah[ks][mt], bh[ks][nt], acc[mt][nt], 0, 0, 0);
        #pragma unroll
        for (int ks = 0; ks < 2; ++ks)
            #pragma unroll
            for (int mt = 0; mt < 4; ++mt)
                #pragma unroll
                for (int nt = 0; nt < 2; ++nt)
                    acc[mt][nt] = __builtin_amdgcn_mfma_f32_16x16x32_bf16(
                        ah[ks][mt], bl[ks][nt], acc[mt][nt], 0, 0, 0);
        short8 al[2][4];
        #pragma unroll
        for (int ks = 0; ks < 2; ++ks)
            #pragma unroll
            for (int mt = 0; mt < 4; ++mt) {
                int row  = mt * 16 + cl;
                int byte = row * 128 + (ks * 32 + g * 8) * 2;
                byte ^= ((row & 7) << 4);
                al[ks][mt] = *(const short8*)(Ab + PLANE + byte);
            }
        #pragma unroll
        for (int ks = 0; ks < 2; ++ks)
            #pragma unroll
            for (int mt = 0; mt < 4; ++mt)
                #pragma unroll
                for (int nt = 0; nt < 2; ++nt)
                    acc[mt][nt] = __builtin_amdgcn_mfma_f32_16x16x32_bf16(
                        al[ks][mt], bh[ks][nt], acc[mt][nt], 0, 0, 0);
        __syncthreads();
    }

    #pragma unroll
    for (int nt = 0; nt < 2; ++nt) {
        float pm = -FLT_MAX;
        #pragma unroll
        for (int mt = 0; mt < 4; ++mt) {
            f32x4 v = acc[mt][nt];
            pm = fmaxf(pm, fmaxf(fmaxf(v[0], v[1]), fmaxf(v[2], v[3])));
        }
        pm = fmaxf(pm, __shfl_xor(pm, 16));
        pm = fmaxf(pm, __shfl_xor(pm, 32));
        if (g == 0) {
            int col = ny * 128 + (w * 2 + nt) * 16 + cl;
            partial[(size_t)mb * 1024 + col] = pm;
        }
    }
}

__global__ __launch_bounds__(256) void final_reduce(const float* __restrict__ partial,
                                                    const float* __restrict__ bf,
                                                    float* __restrict__ out) {
    int g = blockIdx.x * 256 + threadIdx.x;        // 8192
    int b = g >> 10, o = g & 1023;
    float m = -FLT_MAX;
    for (int mb = 0; mb < 32; ++mb)
        m = fmaxf(m, partial[((size_t)(b * 32 + mb)) * 1024 + o]);
    out[g] = m + bf[o];
}

// ---------------------------------------------------------------- launch
extern "C" void kernel_launch(void* const* d_in, const int* in_sizes, int n_in,
                              void* d_out, int out_size, void* d_ws, size_t ws_size,
                              hipStream_t stream) {
    const float* x  = (const float*)d_in[0];
    const float* W0 = (const float*)d_in[1];
    const float* b0 = (const float*)d_in[2];
    const float* W1 = (const float*)d_in[3];
    const float* b1 = (const float*)d_in[4];
    const float* W2 = (const float*)d_in[5];
    const float* b2 = (const float*)d_in[6];
    const float* W3 = (const float*)d_in[7];
    const float* b3 = (const float*)d_in[8];
    const float* Wf = (const float*)d_in[9];
    const float* bf = (const float*)d_in[10];
    (void)in_sizes; (void)n_in; (void)out_size; (void)ws_size;

    char* ws = (char*)d_ws;
    size_t off = 0;
    float* feats   = (float*)(ws + off); off += (size_t)BN * FSTR * 4;      // 32 MB
    float* sq      = (float*)(ws + off); off += (size_t)BN * 4;             // 64 KB
    int*   idx     = (int*)  (ws + off); off += (size_t)BN * KNN * 4;       // 1.25 MB
    float* ctrbuf  = (float*)(ws + off); off += (size_t)BN * 256 * 4;       // 16 MB
    float* partial = ctrbuf;                       // aliased: ctr done before final GEMM
    short* whi     = (short*)(ws + off); off += (size_t)45056 * 2;          // edge W hi planes
    short* wlo     = (short*)(ws + off); off += (size_t)45056 * 2;          // edge W lo planes
    short* wfhi    = (short*)(ws + off); off += (size_t)1024 * 512 * 2;     // 1 MB
    short* wflo    = (short*)(ws + off); off += (size_t)1024 * 512 * 2;     // 1 MB
    short* w1hi = whi,          *w1lo = wlo;                                // 64x64
    short* w2hi = whi + 4096,   *w2lo = wlo + 4096;                         // 128x64
    short* w3hi = whi + 12288,  *w3lo = wlo + 12288;                        // 256x128

    // W hi/lo prep
    wprep_kernel<<<16, 256, 0, stream>>>(W1, 64, 64 * 64, w1hi, w1lo);
    wprep_kernel<<<32, 256, 0, stream>>>(W2, 64, 128 * 64, w2hi, w2lo);
    wprep_kernel<<<128, 256, 0, stream>>>(W3, 128, 256 * 128, w3hi, w3lo);
    wfprep_kernel<<<2048, 256, 0, stream>>>(Wf, wfhi, wflo);

    // Layer 0: C=3 -> 64 @ feats[0:64]  (fp32 VALU)
    sq_kernel<3><<<BN / 256, 256, 0, stream>>>(x, 3, sq);
    knn_kernel<3><<<BN / 4, 256, 0, stream>>>(x, 3, sq, idx);
    edge_kernel<3, 64, 8><<<BN / 8, 256, 0, stream>>>(x, 3, W0, b0, idx, feats + 0);

    // Layer 1: 64 -> 64 @ feats[64:128]
    sq_kernel<64><<<BN / 256, 256, 0, stream>>>(feats + 0, FSTR, sq);
    knn3_kernel<64><<<BN / 8, 512, 0, stream>>>(feats + 0, FSTR, sq, idx);
    ctr_kernel<64, 64><<<BN / 4, 256, 0, stream>>>(feats + 0, FSTR, W1, b1, ctrbuf);
    edge_mfma<64, 64, 1><<<dim3(BN / 4, 1), 256, 0, stream>>>(
        feats + 0, FSTR, w1hi, w1lo, ctrbuf, 64, idx, feats + 64);

    // Layer 2: 64 -> 128 @ feats[128:256]
    sq_kernel<64><<<BN / 256, 256, 0, stream>>>(feats + 64, FSTR, sq);
    knn3_kernel<64><<<BN / 8, 512, 0, stream>>>(feats + 64, FSTR, sq, idx);
    ctr_kernel<64, 128><<<BN / 4, 256, 0, stream>>>(feats + 64, FSTR, W2, b2, ctrbuf);
    edge_mfma<64, 128, 2><<<dim3(BN / 4, 1), 256, 0, stream>>>(
        feats + 64, FSTR, w2hi, w2lo, ctrbuf, 128, idx, feats + 128);

    // Layer 3: 128 -> 256 @ feats[256:512]
    sq_kernel<128><<<BN / 256, 256, 0, stream>>>(feats + 128, FSTR, sq);
    knn3_kernel<128><<<BN / 8, 512, 0, stream>>>(feats + 128, FSTR, sq, idx);
    ctr_kernel<128, 256><<<BN / 4, 256, 0, stream>>>(feats + 128, FSTR, W3, b3, ctrbuf);
    edge_mfma<128, 128, 2><<<dim3(BN / 4, 2), 256, 0, stream>>>(
        feats + 128, FSTR, w3hi, w3lo, ctrbuf, 256, idx, feats + 256);

    // Final 512 -> 1024 + global max pool (MFMA)
    final_mfma<<<dim3(BN / 64, 8), 256, 0, stream>>>(feats, wfhi, wflo, partial);
    final_reduce<<<32, 256, 0, stream>>>(partial, bf, (float*)d_out);
}

// Round 10
// 1205.585 us; speedup vs baseline: 3.6101x; 1.6224x over previous
//
#include <hip/hip_runtime.h>
#include <float.h>

constexpr int NB   = 8;      // batches
constexpr int NP   = 2048;   // points per batch
constexpr int BN   = NB * NP;
constexpr int KNN  = 20;     // neighbors
constexpr int FSTR = 512;    // feats row stride (64+64+128+256)

typedef short short8 __attribute__((ext_vector_type(8)));
typedef float f32x4  __attribute__((ext_vector_type(4)));

__device__ __forceinline__ unsigned f2bf_rne(float x) {
    unsigned u = __float_as_uint(x);
    unsigned r = (u >> 16) & 1;
    return (u + 0x7fffu + r) >> 16;
}
__device__ __forceinline__ float bf2f(unsigned h) { return __uint_as_float(h << 16); }

// ---------------------------------------------------------------- sq = |h|^2
template<int C>
__global__ __launch_bounds__(256) void sq_kernel(const float* __restrict__ h,
                                                 int istr,
                                                 float* __restrict__ sq) {
    int i = blockIdx.x * 256 + threadIdx.x;
    if (i >= BN) return;
    const float* p = h + (size_t)i * istr;
    float s = 0.f;
    #pragma unroll
    for (int c = 0; c < C; ++c) { float v = p[c]; s += v * v; }
    sq[i] = s;
}

// ---------------------------------------------------------------- kNN top-20 (C=3 path)
template<int C>
__global__ __launch_bounds__(256) void knn_kernel(const float* __restrict__ h,
                                                  int istr,
                                                  const float* __restrict__ sq,
                                                  int* __restrict__ knn_idx) {
    constexpr int GI = 4;
    __shared__ float negd[GI][NP];          // 32 KB
    const int t    = threadIdx.x;
    const int r0   = blockIdx.x * GI;
    const int base = (r0 >> 11) << 11;

    float hi[GI][3], sqi[GI];
    #pragma unroll
    for (int g = 0; g < GI; ++g) {
        const float* p = h + (size_t)(r0 + g) * istr;
        hi[g][0] = p[0]; hi[g][1] = p[1]; hi[g][2] = p[2];
        sqi[g] = sq[r0 + g];
    }
    for (int j = t; j < NP; j += 256) {
        const float* pj = h + (size_t)(base + j) * istr;
        float x0 = pj[0], x1 = pj[1], x2 = pj[2];
        float sqj = sq[base + j];
        #pragma unroll
        for (int g = 0; g < GI; ++g) {
            float d = hi[g][0]*x0 + hi[g][1]*x1 + hi[g][2]*x2;
            negd[g][j] = 2.f * d - sqi[g] - sqj;
        }
    }
    __syncthreads();

    const int w = t >> 6;
    const int l = t & 63;
    float* row = &negd[w][0];
    for (int it = 0; it < KNN; ++it) {
        float bv = -FLT_MAX; int bi = NP;
        for (int j = l; j < NP; j += 64) {
            float v = row[j];
            if (v > bv) { bv = v; bi = j; }
        }
        #pragma unroll
        for (int off = 1; off < 64; off <<= 1) {
            float ov = __shfl_xor(bv, off);
            int   oi = __shfl_xor(bi, off);
            if (ov > bv || (ov == bv && oi < bi)) { bv = ov; bi = oi; }
        }
        if (l == 0) knn_idx[(size_t)(r0 + w) * KNN + it] = bi;
        if (l == (bi & 63)) row[bi] = -FLT_MAX;
    }
}

// ---------------------------------------------------------------- kNN top-20 v3 (C=64/128)
template<int C>
__global__ __launch_bounds__(512) void knn3_kernel(const float* __restrict__ h, int istr,
                                                   const float* __restrict__ sq,
                                                   int* __restrict__ knn_idx) {
    __shared__ float negd[8][NP];                  // 64 KB
    const int t      = threadIdx.x;
    const int batch  = blockIdx.x & 7;             // XCD-pinned batch
    const int within = blockIdx.x >> 3;
    const int r0     = batch * NP + within * 8;
    const int base   = batch * NP;
    const int w = t >> 6, l = t & 63;
    constexpr int KQ = C / 4;                      // floats per k-quarter

    float sqi[8];
    #pragma unroll
    for (int i = 0; i < 8; ++i) sqi[i] = sq[r0 + i];

    #pragma unroll 1
    for (int p = 0; p < 4; ++p) {
        const int j = w * 64 + p * 512 + l;
        const float* bj = h + (size_t)(base + j) * istr;
        float acc[8];
        #pragma unroll
        for (int i = 0; i < 8; ++i) acc[i] = 0.f;
        #pragma unroll 1
        for (int kq = 0; kq < 4; ++kq) {
            float4 breg[KQ / 4];
            #pragma unroll
            for (int u = 0; u < KQ / 4; ++u)
                breg[u] = *(const float4*)(bj + kq * KQ + 4 * u);
            #pragma unroll
            for (int i = 0; i < 8; ++i) {
                const float* ar = h + (size_t)(r0 + i) * istr + kq * KQ;  // uniform
                float s = acc[i];
                #pragma unroll
                for (int u = 0; u < KQ / 4; ++u) {
                    s += ar[4*u+0] * breg[u].x;
                    s += ar[4*u+1] * breg[u].y;
                    s += ar[4*u+2] * breg[u].z;
                    s += ar[4*u+3] * breg[u].w;
                }
                acc[i] = s;
            }
        }
        float sqj = sq[base + j];
        #pragma unroll
        for (int i = 0; i < 8; ++i)
            negd[i][j] = 2.f * acc[i] - sqi[i] - sqj;
    }
    __syncthreads();

    const float* row = &negd[w][0];
    float v[32];
    #pragma unroll
    for (int u = 0; u < 32; ++u) v[u] = row[l + 64 * u];
    float m0 = v[0], m1 = v[16];
    int   u0 = 0,    u1 = 16;
    #pragma unroll
    for (int u = 1; u < 16; ++u)  { if (v[u] > m0) { m0 = v[u]; u0 = u; } }
    #pragma unroll
    for (int u = 17; u < 32; ++u) { if (v[u] > m1) { m1 = v[u]; u1 = u; } }

    int* out = knn_idx + (size_t)(r0 + w) * KNN;
    for (int it = 0; it < KNN; ++it) {
        float bv; int bu;
        if (m0 >= m1) { bv = m0; bu = u0; } else { bv = m1; bu = u1; }
        int bj = l + (bu << 6);
        #pragma unroll
        for (int off = 1; off < 64; off <<= 1) {
            float ov = __shfl_xor(bv, off);
            int   oj = __shfl_xor(bj, off);
            if (ov > bv || (ov == bv && oj < bj)) { bv = ov; bj = oj; }
        }
        if (l == 0) out[it] = bj;
        const int  ur  = bj >> 6;                  // wave-uniform
        const bool own = ((bj & 63) == l);
        if (ur < 16) {
            #pragma unroll
            for (int u = 0; u < 16; ++u)
                if (own && u == ur) v[u] = -FLT_MAX;
            m0 = v[0]; u0 = 0;
            #pragma unroll
            for (int u = 1; u < 16; ++u) if (v[u] > m0) { m0 = v[u]; u0 = u; }
        } else {
            #pragma unroll
            for (int u = 16; u < 32; ++u)
                if (own && u == ur) v[u] = -FLT_MAX;
            m1 = v[16]; u1 = 16;
            #pragma unroll
            for (int u = 17; u < 32; ++u) if (v[u] > m1) { m1 = v[u]; u1 = u; }
        }
    }
}

// ---------------------------------------------------------------- U/V' hi-lo prep
// B-matrix rows: [0:cout) = U = W[:,0:C]; [cout:2cout) = V' = W[:,C:2C] - W[:,0:C]
__global__ __launch_bounds__(256) void uvprep_kernel(const float* __restrict__ W,
                                                     int cin, int cout,
                                                     short* __restrict__ bhi,
                                                     short* __restrict__ blo) {
    int e = blockIdx.x * 256 + threadIdx.x;
    if (e >= cout * cin) return;
    int o = e / cin, c = e - o * cin;
    float u  = W[(size_t)o * (2 * cin) + c];
    float vv = W[(size_t)o * (2 * cin) + cin + c];
    float vp = vv - u;
    unsigned hu = f2bf_rne(u);
    unsigned lu = __float_as_uint(u - bf2f(hu)) >> 16;
    unsigned hv = f2bf_rne(vp);
    unsigned lv = __float_as_uint(vp - bf2f(hv)) >> 16;
    bhi[(size_t)o * cin + c] = (short)hu;
    blo[(size_t)o * cin + c] = (short)lu;
    bhi[(size_t)(cout + o) * cin + c] = (short)hv;
    blo[(size_t)(cout + o) * cin + c] = (short)lv;
}

// ---------------------------------------------------------------- Wf hi/lo prep (flat)
__global__ __launch_bounds__(256) void wfprep_kernel(const float* __restrict__ Wf,
                                                     short* __restrict__ whi,
                                                     short* __restrict__ wlo) {
    int e = blockIdx.x * 256 + threadIdx.x;        // < 1024*512
    float v = Wf[e];
    unsigned h = f2bf_rne(v);
    unsigned lo = __float_as_uint(v - bf2f(h)) >> 16;
    whi[e] = (short)h;
    wlo[e] = (short)lo;
}

// ---------------------------------------------------------------- node GEMM via MFMA (bf16 hi/lo, 3-term)
// out[r][n] = sum_c h[r][c] * B[n][c];  block = 64 rows x 128 cols, K = KC*64.
template<int KC>
__global__ __launch_bounds__(256) void gemm_node(const float* __restrict__ h, int istr,
                                                 const short* __restrict__ bhi_,
                                                 const short* __restrict__ blo_,
                                                 int nstr,
                                                 float* __restrict__ out) {
    constexpr int PLANE = 64 * 64 * 2;             // bytes per plane
    __shared__ short A[2 * 64 * 64];               // hi plane then lo plane (16 KB)
    const int t    = threadIdx.x;
    const int mb   = blockIdx.x;
    const int ny   = blockIdx.y;
    const int row0 = mb * 64;
    const int l = t & 63, w = t >> 6, g = l >> 4, cl = l & 15;

    f32x4 acc[4][2];
    #pragma unroll
    for (int mt = 0; mt < 4; ++mt)
        #pragma unroll
        for (int nt = 0; nt < 2; ++nt)
            acc[mt][nt] = (f32x4){0.f, 0.f, 0.f, 0.f};

    char* Ab = (char*)A;
    #pragma unroll 1
    for (int kc = 0; kc < KC; ++kc) {
        for (int u = t; u < 64 * 32; u += 256) {   // 64 rows x 32 float2
            int row = u >> 5, cp = u & 31;
            const float* src = &h[(size_t)(row0 + row) * istr + kc * 64 + cp * 2];
            float d0 = src[0], d1 = src[1];
            unsigned h0 = f2bf_rne(d0), h1 = f2bf_rne(d1);
            unsigned l0 = __float_as_uint(d0 - bf2f(h0)) >> 16;
            unsigned l1 = __float_as_uint(d1 - bf2f(h1)) >> 16;
            int byte = row * 128 + cp * 4;
            byte ^= ((row & 7) << 4);
            *(unsigned*)(Ab + byte)         = h0 | (h1 << 16);
            *(unsigned*)(Ab + PLANE + byte) = l0 | (l1 << 16);
        }
        __syncthreads();

        short8 bh[2][2], bl[2][2];                 // [ks][nt]
        #pragma unroll
        for (int ks = 0; ks < 2; ++ks)
            #pragma unroll
            for (int nt = 0; nt < 2; ++nt) {
                int o = ny * 128 + (w * 2 + nt) * 16 + cl;
                size_t koff = (size_t)o * (KC * 64) + kc * 64 + ks * 32 + g * 8;
                bh[ks][nt] = *(const short8*)(bhi_ + koff);
                bl[ks][nt] = *(const short8*)(blo_ + koff);
            }
        short8 ah[2][4];                           // [ks][mt]
        #pragma unroll
        for (int ks = 0; ks < 2; ++ks)
            #pragma unroll
            for (int mt = 0; mt < 4; ++mt) {
                int row  = mt * 16 + cl;
                int byte = row * 128 + (ks * 32 + g * 8) * 2;
                byte ^= ((row & 7) << 4);
                ah[ks][mt] = *(const short8*)(Ab + byte);
            }
        #pragma unroll
        for (int ks = 0; ks < 2; ++ks)
            #pragma unroll
            for (int mt = 0; mt < 4; ++mt)
                #pragma unroll
                for (int nt = 0; nt < 2; ++nt)
                    acc[mt][nt] = __builtin_amdgcn_mfma_f32_16x16x32_bf16(
                        ah[ks][mt], bh[ks][nt], acc[mt][nt], 0, 0, 0);
        #pragma unroll
        for (int ks = 0; ks < 2; ++ks)
            #pragma unroll
            for (int mt = 0; mt < 4; ++mt)
                #pragma unroll
                for (int nt = 0; nt < 2; ++nt)
                    acc[mt][nt] = __builtin_amdgcn_mfma_f32_16x16x32_bf16(
                        ah[ks][mt], bl[ks][nt], acc[mt][nt], 0, 0, 0);
        short8 al[2][4];
        #pragma unroll
        for (int ks = 0; ks < 2; ++ks)
            #pragma unroll
            for (int mt = 0; mt < 4; ++mt) {
                int row  = mt * 16 + cl;
                int byte = row * 128 + (ks * 32 + g * 8) * 2;
                byte ^= ((row & 7) << 4);
                al[ks][mt] = *(const short8*)(Ab + PLANE + byte);
            }
        #pragma unroll
        for (int ks = 0; ks < 2; ++ks)
            #pragma unroll
            for (int mt = 0; mt < 4; ++mt)
                #pragma unroll
                for (int nt = 0; nt < 2; ++nt)
                    acc[mt][nt] = __builtin_amdgcn_mfma_f32_16x16x32_bf16(
                        al[ks][mt], bh[ks][nt], acc[mt][nt], 0, 0, 0);
        __syncthreads();
    }

    // epilogue: store fp32 (C/D layout: col=lane&15, row=g*4+reg)
    #pragma unroll
    for (int nt = 0; nt < 2; ++nt) {
        int col = ny * 128 + (w * 2 + nt) * 16 + cl;
        #pragma unroll
        for (int mt = 0; mt < 4; ++mt) {
            #pragma unroll
            for (int j = 0; j < 4; ++j) {
                int row = row0 + mt * 16 + g * 4 + j;
                out[(size_t)row * nstr + col] = acc[mt][nt][j];
            }
        }
    }
}

// ---------------------------------------------------------------- gather-max epilogue
// out[p][o] = lrelu( max_k GC[j_k][o] + GC[p][COUT+o] + b[o] )
template<int COUT, int PPB>
__global__ __launch_bounds__(256) void gather_max(const float* __restrict__ GC, int nstr,
                                                  const int* __restrict__ knn_idx,
                                                  const float* __restrict__ bias,
                                                  float* __restrict__ hout) {
    static_assert(COUT * PPB == 256, "block 256");
    const int t  = threadIdx.x;
    const int pl = t / COUT;
    const int o  = t - pl * COUT;
    const int p  = blockIdx.x * PPB + pl;
    const int base = (p >> 11) << 11;
    const int* jrow = knn_idx + (size_t)p * KNN;

    float mx = -FLT_MAX;
    #pragma unroll
    for (int k = 0; k < KNN; ++k) {
        int j = jrow[k];                           // batch-local, wave-uniform
        mx = fmaxf(mx, GC[(size_t)(base + j) * nstr + o]);
    }
    float val = mx + GC[(size_t)p * nstr + COUT + o] + bias[o];
    val = val > 0.f ? val : 0.2f * val;
    hout[(size_t)p * FSTR + o] = val;
}

// ---------------------------------------------------------------- EdgeConv L0 (CIN=3, fp32 VALU)
template<int CIN, int COUT, int PPB>
__global__ __launch_bounds__(256) void edge_kernel(const float* __restrict__ hin,
                                                   int istr,
                                                   const float* __restrict__ W,
                                                   const float* __restrict__ bias,
                                                   const int* __restrict__ knn_idx,
                                                   float* __restrict__ hout) {
    constexpr int TPP = COUT / 2;
    static_assert(PPB * TPP == 256, "block must be 256 threads");
    __shared__ float diff[PPB][KNN][CIN];
    __shared__ float hi[PPB][CIN];
    __shared__ int   nj[PPB][KNN];

    const int t    = threadIdx.x;
    const int r0   = blockIdx.x * PPB;
    const int base = (r0 >> 11) << 11;

    for (int e = t; e < PPB * KNN; e += 256) {
        int p = e / KNN, kk = e - p * KNN;
        nj[p][kk] = knn_idx[(size_t)(r0 + p) * KNN + kk];
    }
    for (int e = t; e < PPB * CIN; e += 256) {
        int p = e / CIN, c = e - p * CIN;
        hi[p][c] = hin[(size_t)(r0 + p) * istr + c];
    }
    __syncthreads();
    for (int e = t; e < PPB * KNN * CIN; e += 256) {
        int p  = e / (KNN * CIN);
        int rm = e - p * (KNN * CIN);
        int kk = rm / CIN, c = rm - kk * CIN;
        diff[p][kk][c] = hin[(size_t)(base + nj[p][kk]) * istr + c] - hi[p][c];
    }
    __syncthreads();

    const int p  = t / TPP;
    const int oo = t - p * TPP;
    const float* W0 = W + (size_t)oo * (2 * CIN);
    const float* W1 = W + (size_t)(oo + TPP) * (2 * CIN);

    float ctr0 = bias[oo], ctr1 = bias[oo + TPP];
    float acc[2][KNN];
    #pragma unroll
    for (int kk = 0; kk < KNN; ++kk) { acc[0][kk] = 0.f; acc[1][kk] = 0.f; }

    for (int c = 0; c < CIN; ++c) {
        float hv = hi[p][c];
        ctr0 += W0[CIN + c] * hv;
        ctr1 += W1[CIN + c] * hv;
    }
    for (int c = 0; c < CIN; ++c) {
        float w0 = W0[c], w1 = W1[c];
        #pragma unroll
        for (int kk = 0; kk < KNN; ++kk) {
            float d = diff[p][kk][c];
            acc[0][kk] += w0 * d;
            acc[1][kk] += w1 * d;
        }
    }

    float m0 = -FLT_MAX, m1 = -FLT_MAX;
    #pragma unroll
    for (int kk = 0; kk < KNN; ++kk) {
        m0 = fmaxf(m0, acc[0][kk] + ctr0);
        m1 = fmaxf(m1, acc[1][kk] + ctr1);
    }
    float r0v = m0 > 0.f ? m0 : 0.2f * m0;
    float r1v = m1 > 0.f ? m1 : 0.2f * m1;
    hout[(size_t)(r0 + p) * FSTR + oo]       = r0v;
    hout[(size_t)(r0 + p) * FSTR + oo + TPP] = r1v;
}

// ---------------------------------------------------------------- final GEMM via MFMA (bf16 hi/lo, 3-term) + col-max
__global__ __launch_bounds__(256) void final_mfma(const float* __restrict__ f,
                                                  const short* __restrict__ wfhi,
                                                  const short* __restrict__ wflo,
                                                  float* __restrict__ partial) {
    constexpr int PLANE = 64 * 64 * 2;             // bytes per plane
    __shared__ short A[2 * 64 * 64];               // hi plane then lo plane (16 KB)
    const int t    = threadIdx.x;
    const int mb   = blockIdx.x;                   // 0..255 (64-row chunk)
    const int ny   = blockIdx.y;                   // 0..7 (128-col chunk)
    const int row0 = mb * 64;
    const int l = t & 63, w = t >> 6, g = l >> 4, cl = l & 15;

    f32x4 acc[4][2];
    #pragma unroll
    for (int mt = 0; mt < 4; ++mt)
        #pragma unroll
        for (int nt = 0; nt < 2; ++nt)
            acc[mt][nt] = (f32x4){0.f, 0.f, 0.f, 0.f};

    char* Ab = (char*)A;
    #pragma unroll 1
    for (int kc = 0; kc < 8; ++kc) {
        for (int u = t; u < 64 * 32; u += 256) {   // 64 rows x 32 float2
            int row = u >> 5, cp = u & 31;
            const float* src = &f[(size_t)(row0 + row) * FSTR + kc * 64 + cp * 2];
            float d0 = src[0], d1 = src[1];
            unsigned h0 = f2bf_rne(d0), h1 = f2bf_rne(d1);
            unsigned l0 = __float_as_uint(d0 - bf2f(h0)) >> 16;
            unsigned l1 = __float_as_uint(d1 - bf2f(h1)) >> 16;
            int byte = row * 128 + cp * 4;
            byte ^= ((row & 7) << 4);
            *(unsigned*)(Ab + byte)         = h0 | (h1 << 16);
            *(unsigned*)(Ab + PLANE + byte) = l0 | (l1 << 16);
        }
        __syncthreads();

        short8 bh[2][2], bl[2][2];                 // [ks][nt]
        #pragma unroll
        for (int ks = 0; ks < 2; ++ks)
            #pragma unroll
            for (int nt = 0; nt < 2; ++nt) {
                int o = ny * 128 + (w * 2 + nt) * 16 + cl;
                size_t koff = (size_t)o * 512 + kc * 64 + ks * 32 + g * 8;
                bh[ks][nt] = *(const short8*)(wfhi + koff);
                bl[ks][nt] = *(const short8*)(wflo + koff);
            }
        short8 ah[2][4];                           // [ks][mt]
        #pragma unroll
        for (int ks = 0; ks < 2; ++ks)
            #pragma unroll
            for (int mt = 0; mt < 4; ++mt) {
                int row  = mt * 16 + cl;
                int byte = row * 128 + (ks * 32 + g * 8) * 2;
                byte ^= ((row & 7) << 4);
                ah[ks][mt] = *(const short8*)(Ab + byte);
            }
        #pragma unroll
        for (int ks = 0; ks < 2; ++ks)
            #pragma unroll
            for (int mt = 0; mt < 4; ++mt)
                #pragma unroll
                for (int nt = 0; nt < 2; ++nt)
                    acc[mt][nt] = __builtin_amdgcn_mfma_f32_16x16x32_bf16(
                        ah[ks][mt], bh[ks][nt], acc[mt][nt], 0, 0, 0);
        #pragma unroll
        for (int ks = 0; ks < 2; ++ks)
            #pragma unroll
            for (int mt = 0; mt < 4; ++mt)
                #pragma unroll
                for (int nt = 0; nt < 2; ++nt)
                    acc[mt][nt] = __builtin_amdgcn_mfma_f32_16x16x32_bf16(
                        ah[ks][mt], bl[ks][nt], acc[mt][nt], 0, 0, 0);
        short8 al[2][4];
        #pragma unroll
        for (int ks = 0; ks < 2; ++ks)
            #pragma unroll
            for (int mt = 0; mt < 4; ++mt) {
                int row  = mt * 16 + cl;
                int byte = row * 128 + (ks * 32 + g * 8) * 2;
                byte ^= ((row & 7) << 4);
                al[ks][mt] = *(const short8*)(Ab + PLANE + byte);
            }
        #pragma unroll
        for (int ks = 0; ks < 2; ++ks)
            #pragma unroll
            for (int mt = 0; mt < 4; ++mt)
                #pragma unroll
                for (int nt = 0; nt < 2; ++nt)
                    acc[mt][nt] = __builtin_amdgcn_mfma_f32_16x16x32_bf16(
                        al[ks][mt], bh[ks][nt], acc[mt][nt], 0, 0, 0);
        __syncthreads();
    }

    #pragma unroll
    for (int nt = 0; nt < 2; ++nt) {
        float pm = -FLT_MAX;
        #pragma unroll
        for (int mt = 0; mt < 4; ++mt) {
            f32x4 v = acc[mt][nt];
            pm = fmaxf(pm, fmaxf(fmaxf(v[0], v[1]), fmaxf(v[2], v[3])));
        }
        pm = fmaxf(pm, __shfl_xor(pm, 16));
        pm = fmaxf(pm, __shfl_xor(pm, 32));
        if (g == 0) {
            int col = ny * 128 + (w * 2 + nt) * 16 + cl;
            partial[(size_t)mb * 1024 + col] = pm;
        }
    }
}

__global__ __launch_bounds__(256) void final_reduce(const float* __restrict__ partial,
                                                    const float* __restrict__ bf,
                                                    float* __restrict__ out) {
    int g = blockIdx.x * 256 + threadIdx.x;        // 8192
    int b = g >> 10, o = g & 1023;
    float m = -FLT_MAX;
    for (int mb = 0; mb < 32; ++mb)
        m = fmaxf(m, partial[((size_t)(b * 32 + mb)) * 1024 + o]);
    out[g] = m + bf[o];
}

// ---------------------------------------------------------------- launch
extern "C" void kernel_launch(void* const* d_in, const int* in_sizes, int n_in,
                              void* d_out, int out_size, void* d_ws, size_t ws_size,
                              hipStream_t stream) {
    const float* x  = (const float*)d_in[0];
    const float* W0 = (const float*)d_in[1];
    const float* b0 = (const float*)d_in[2];
    const float* W1 = (const float*)d_in[3];
    const float* b1 = (const float*)d_in[4];
    const float* W2 = (const float*)d_in[5];
    const float* b2 = (const float*)d_in[6];
    const float* W3 = (const float*)d_in[7];
    const float* b3 = (const float*)d_in[8];
    const float* Wf = (const float*)d_in[9];
    const float* bf = (const float*)d_in[10];
    (void)in_sizes; (void)n_in; (void)out_size; (void)ws_size;

    char* ws = (char*)d_ws;
    size_t off = 0;
    float* feats = (float*)(ws + off); off += (size_t)BN * FSTR * 4;        // 32 MB
    float* sq    = (float*)(ws + off); off += (size_t)BN * 4;               // 64 KB
    int*   idx   = (int*)  (ws + off); off += (size_t)BN * KNN * 4;         // 1.25 MB
    float* GC    = (float*)(ws + off); off += (size_t)BN * 512 * 4;         // 32 MB
    float* partial = GC;               // alias: GC free when final phase runs
    short* ebhi  = (short*)(ws + off); off += (size_t)90112 * 2;            // B planes (U;V')
    short* eblo  = (short*)(ws + off); off += (size_t)90112 * 2;
    short* wfhi  = (short*)(ws + off); off += (size_t)1024 * 512 * 2;       // 1 MB
    short* wflo  = (short*)(ws + off); off += (size_t)1024 * 512 * 2;       // 1 MB
    short* b1hi = ebhi,         *b1lo = eblo;                               // 128 x 64
    short* b2hi = ebhi + 8192,  *b2lo = eblo + 8192;                        // 256 x 64
    short* b3hi = ebhi + 24576, *b3lo = eblo + 24576;                       // 512 x 128

    // B-matrix prep (U and V' = V - U, hi/lo planes)
    uvprep_kernel<<<16, 256, 0, stream>>>(W1, 64, 64, b1hi, b1lo);
    uvprep_kernel<<<32, 256, 0, stream>>>(W2, 64, 128, b2hi, b2lo);
    uvprep_kernel<<<128, 256, 0, stream>>>(W3, 128, 256, b3hi, b3lo);
    wfprep_kernel<<<2048, 256, 0, stream>>>(Wf, wfhi, wflo);

    // Layer 0: C=3 -> 64 @ feats[0:64]  (fp32 VALU)
    sq_kernel<3><<<BN / 256, 256, 0, stream>>>(x, 3, sq);
    knn_kernel<3><<<BN / 4, 256, 0, stream>>>(x, 3, sq, idx);
    edge_kernel<3, 64, 8><<<BN / 8, 256, 0, stream>>>(x, 3, W0, b0, idx, feats + 0);

    // Layer 1: 64 -> 64 @ feats[64:128]
    sq_kernel<64><<<BN / 256, 256, 0, stream>>>(feats + 0, FSTR, sq);
    knn3_kernel<64><<<BN / 8, 512, 0, stream>>>(feats + 0, FSTR, sq, idx);
    gemm_node<1><<<dim3(BN / 64, 1), 256, 0, stream>>>(feats + 0, FSTR, b1hi, b1lo, 128, GC);
    gather_max<64, 4><<<BN / 4, 256, 0, stream>>>(GC, 128, idx, b1, feats + 64);

    // Layer 2: 64 -> 128 @ feats[128:256]
    sq_kernel<64><<<BN / 256, 256, 0, stream>>>(feats + 64, FSTR, sq);
    knn3_kernel<64><<<BN / 8, 512, 0, stream>>>(feats + 64, FSTR, sq, idx);
    gemm_node<1><<<dim3(BN / 64, 2), 256, 0, stream>>>(feats + 64, FSTR, b2hi, b2lo, 256, GC);
    gather_max<128, 2><<<BN / 2, 256, 0, stream>>>(GC, 256, idx, b2, feats + 128);

    // Layer 3: 128 -> 256 @ feats[256:512]
    sq_kernel<128><<<BN / 256, 256, 0, stream>>>(feats + 128, FSTR, sq);
    knn3_kernel<128><<<BN / 8, 512, 0, stream>>>(feats + 128, FSTR, sq, idx);
    gemm_node<2><<<dim3(BN / 64, 4), 256, 0, stream>>>(feats + 128, FSTR, b3hi, b3lo, 512, GC);
    gather_max<256, 1><<<BN, 256, 0, stream>>>(GC, 512, idx, b3, feats + 256);

    // Final 512 -> 1024 + global max pool (MFMA)
    final_mfma<<<dim3(BN / 64, 8), 256, 0, stream>>>(feats, wfhi, wflo, partial);
    final_reduce<<<32, 256, 0, stream>>>(partial, bf, (float*)d_out);
}

// Round 11
// 943.924 us; speedup vs baseline: 4.6109x; 1.2772x over previous
//
#include <hip/hip_runtime.h>
#include <float.h>

constexpr int NB   = 8;      // batches
constexpr int NP   = 2048;   // points per batch
constexpr int BN   = NB * NP;
constexpr int KNN  = 20;     // neighbors
constexpr int FSTR = 512;    // feats row stride (64+64+128+256)

typedef short short8 __attribute__((ext_vector_type(8)));
typedef float f32x4  __attribute__((ext_vector_type(4)));

__device__ __forceinline__ unsigned f2bf_rne(float x) {
    unsigned u = __float_as_uint(x);
    unsigned r = (u >> 16) & 1;
    return (u + 0x7fffu + r) >> 16;
}
__device__ __forceinline__ float bf2f(unsigned h) { return __uint_as_float(h << 16); }

// ---------------------------------------------------------------- sq = |h|^2
template<int C>
__global__ __launch_bounds__(256) void sq_kernel(const float* __restrict__ h,
                                                 int istr,
                                                 float* __restrict__ sq) {
    int i = blockIdx.x * 256 + threadIdx.x;
    if (i >= BN) return;
    const float* p = h + (size_t)i * istr;
    float s = 0.f;
    #pragma unroll
    for (int c = 0; c < C; ++c) { float v = p[c]; s += v * v; }
    sq[i] = s;
}

// ---------------------------------------------------------------- kNN top-20 (C=3 path)
template<int C>
__global__ __launch_bounds__(256) void knn_kernel(const float* __restrict__ h,
                                                  int istr,
                                                  const float* __restrict__ sq,
                                                  int* __restrict__ knn_idx) {
    constexpr int GI = 4;
    __shared__ float negd[GI][NP];          // 32 KB
    const int t    = threadIdx.x;
    const int r0   = blockIdx.x * GI;
    const int base = (r0 >> 11) << 11;

    float hi[GI][3], sqi[GI];
    #pragma unroll
    for (int g = 0; g < GI; ++g) {
        const float* p = h + (size_t)(r0 + g) * istr;
        hi[g][0] = p[0]; hi[g][1] = p[1]; hi[g][2] = p[2];
        sqi[g] = sq[r0 + g];
    }
    for (int j = t; j < NP; j += 256) {
        const float* pj = h + (size_t)(base + j) * istr;
        float x0 = pj[0], x1 = pj[1], x2 = pj[2];
        float sqj = sq[base + j];
        #pragma unroll
        for (int g = 0; g < GI; ++g) {
            float d = hi[g][0]*x0 + hi[g][1]*x1 + hi[g][2]*x2;
            negd[g][j] = 2.f * d - sqi[g] - sqj;
        }
    }
    __syncthreads();

    const int w = t >> 6;
    const int l = t & 63;
    float* row = &negd[w][0];
    for (int it = 0; it < KNN; ++it) {
        float bv = -FLT_MAX; int bi = NP;
        for (int j = l; j < NP; j += 64) {
            float v = row[j];
            if (v > bv) { bv = v; bi = j; }
        }
        #pragma unroll
        for (int off = 1; off < 64; off <<= 1) {
            float ov = __shfl_xor(bv, off);
            int   oi = __shfl_xor(bi, off);
            if (ov > bv || (ov == bv && oi < bi)) { bv = ov; bi = oi; }
        }
        if (l == 0) knn_idx[(size_t)(r0 + w) * KNN + it] = bi;
        if (l == (bi & 63)) row[bi] = -FLT_MAX;
    }
}

// ---------------------------------------------------------------- H hi/lo plane prep
__global__ __launch_bounds__(256) void hprep_kernel(const float* __restrict__ h, int istr,
                                                    int cin, int total,
                                                    short* __restrict__ hhi,
                                                    short* __restrict__ hlo) {
    int e = blockIdx.x * 256 + threadIdx.x;
    if (e >= total) return;
    int r = e / cin, c = e - r * cin;
    float v = h[(size_t)r * istr + c];
    unsigned hh = f2bf_rne(v);
    unsigned ll = __float_as_uint(v - bf2f(hh)) >> 16;
    hhi[e] = (short)hh;
    hlo[e] = (short)ll;
}

// ---------------------------------------------------------------- Gram via MFMA (bf16 hi/lo, 3-term)
// gram[big*NP + r][c] = 2*H_r·H_c - sq_r - sq_c for 4-batch group at g0.
// grid: (4 batches * 32 row-tiles, 16 col-tiles), 256 thr.
template<int KC>    // K = KC*64 = C
__global__ __launch_bounds__(256) void gram_mfma(const float* __restrict__ h, int istr,
                                                 const short* __restrict__ hhi,
                                                 const short* __restrict__ hlo,
                                                 const float* __restrict__ sq,
                                                 int g0,
                                                 float* __restrict__ gram) {
    constexpr int PLANE = 64 * 64 * 2;
    __shared__ short A[2 * 64 * 64];               // 16 KB
    const int t   = threadIdx.x;
    const int bx  = blockIdx.x;
    const int ct  = blockIdx.y;
    const int big = bx >> 5, rt = bx & 31;
    const int bbase = g0 + big * NP;               // batch base (global row)
    const int row0g = bbase + rt * 64;
    const int l = t & 63, w = t >> 6, g = l >> 4, cl = l & 15;

    f32x4 acc[4][2];
    #pragma unroll
    for (int mt = 0; mt < 4; ++mt)
        #pragma unroll
        for (int nt = 0; nt < 2; ++nt)
            acc[mt][nt] = (f32x4){0.f, 0.f, 0.f, 0.f};

    char* Ab = (char*)A;
    #pragma unroll 1
    for (int kc = 0; kc < KC; ++kc) {
        for (int u = t; u < 64 * 32; u += 256) {
            int row = u >> 5, cp = u & 31;
            const float* src = &h[(size_t)(row0g + row) * istr + kc * 64 + cp * 2];
            float d0 = src[0], d1 = src[1];
            unsigned h0 = f2bf_rne(d0), h1 = f2bf_rne(d1);
            unsigned l0 = __float_as_uint(d0 - bf2f(h0)) >> 16;
            unsigned l1 = __float_as_uint(d1 - bf2f(h1)) >> 16;
            int byte = row * 128 + cp * 4;
            byte ^= ((row & 7) << 4);
            *(unsigned*)(Ab + byte)         = h0 | (h1 << 16);
            *(unsigned*)(Ab + PLANE + byte) = l0 | (l1 << 16);
        }
        __syncthreads();

        short8 bh[2][2], bl[2][2];
        #pragma unroll
        for (int ks = 0; ks < 2; ++ks)
            #pragma unroll
            for (int nt = 0; nt < 2; ++nt) {
                int col = ct * 128 + (w * 2 + nt) * 16 + cl;
                size_t koff = (size_t)(bbase + col) * (KC * 64) + kc * 64 + ks * 32 + g * 8;
                bh[ks][nt] = *(const short8*)(hhi + koff);
                bl[ks][nt] = *(const short8*)(hlo + koff);
            }
        short8 ah[2][4];
        #pragma unroll
        for (int ks = 0; ks < 2; ++ks)
            #pragma unroll
            for (int mt = 0; mt < 4; ++mt) {
                int row  = mt * 16 + cl;
                int byte = row * 128 + (ks * 32 + g * 8) * 2;
                byte ^= ((row & 7) << 4);
                ah[ks][mt] = *(const short8*)(Ab + byte);
            }
        #pragma unroll
        for (int ks = 0; ks < 2; ++ks)
            #pragma unroll
            for (int mt = 0; mt < 4; ++mt)
                #pragma unroll
                for (int nt = 0; nt < 2; ++nt)
                    acc[mt][nt] = __builtin_amdgcn_mfma_f32_16x16x32_bf16(
                        ah[ks][mt], bh[ks][nt], acc[mt][nt], 0, 0, 0);
        #pragma unroll
        for (int ks = 0; ks < 2; ++ks)
            #pragma unroll
            for (int mt = 0; mt < 4; ++mt)
                #pragma unroll
                for (int nt = 0; nt < 2; ++nt)
                    acc[mt][nt] = __builtin_amdgcn_mfma_f32_16x16x32_bf16(
                        ah[ks][mt], bl[ks][nt], acc[mt][nt], 0, 0, 0);
        short8 al[2][4];
        #pragma unroll
        for (int ks = 0; ks < 2; ++ks)
            #pragma unroll
            for (int mt = 0; mt < 4; ++mt) {
                int row  = mt * 16 + cl;
                int byte = row * 128 + (ks * 32 + g * 8) * 2;
                byte ^= ((row & 7) << 4);
                al[ks][mt] = *(const short8*)(Ab + PLANE + byte);
            }
        #pragma unroll
        for (int ks = 0; ks < 2; ++ks)
            #pragma unroll
            for (int mt = 0; mt < 4; ++mt)
                #pragma unroll
                for (int nt = 0; nt < 2; ++nt)
                    acc[mt][nt] = __builtin_amdgcn_mfma_f32_16x16x32_bf16(
                        al[ks][mt], bh[ks][nt], acc[mt][nt], 0, 0, 0);
        __syncthreads();
    }

    // epilogue: negd = 2*acc - sq_r - sq_c
    #pragma unroll
    for (int nt = 0; nt < 2; ++nt) {
        int col = ct * 128 + (w * 2 + nt) * 16 + cl;
        float sqc = sq[bbase + col];
        #pragma unroll
        for (int mt = 0; mt < 4; ++mt) {
            #pragma unroll
            for (int j = 0; j < 4; ++j) {
                int rl = rt * 64 + mt * 16 + g * 4 + j;
                float val = 2.f * acc[mt][nt][j] - sq[bbase + rl] - sqc;
                gram[(size_t)(big * NP + rl) * NP + col] = val;
            }
        }
    }
}

// ---------------------------------------------------------------- top-20 selection from gram rows
// grid: 4*NP/8 blocks, 512 thr; wave w owns row blockIdx*8+w. v[32] in regs.
__global__ __launch_bounds__(512) void select_topk(const float* __restrict__ gram,
                                                   int g0,
                                                   int* __restrict__ knn_idx) {
    const int t = threadIdx.x, w = t >> 6, l = t & 63;
    const int rlocal = blockIdx.x * 8 + w;
    const float* row = gram + (size_t)rlocal * NP;

    float v[32];
    #pragma unroll
    for (int u = 0; u < 32; ++u) v[u] = row[l + 64 * u];
    float m0 = v[0], m1 = v[16];
    int   u0 = 0,    u1 = 16;
    #pragma unroll
    for (int u = 1; u < 16; ++u)  { if (v[u] > m0) { m0 = v[u]; u0 = u; } }
    #pragma unroll
    for (int u = 17; u < 32; ++u) { if (v[u] > m1) { m1 = v[u]; u1 = u; } }

    int* out = knn_idx + (size_t)(g0 + rlocal) * KNN;
    for (int it = 0; it < KNN; ++it) {
        float bv; int bu;
        if (m0 >= m1) { bv = m0; bu = u0; } else { bv = m1; bu = u1; }
        int bj = l + (bu << 6);
        #pragma unroll
        for (int off = 1; off < 64; off <<= 1) {
            float ov = __shfl_xor(bv, off);
            int   oj = __shfl_xor(bj, off);
            if (ov > bv || (ov == bv && oj < bj)) { bv = ov; bj = oj; }
        }
        if (l == 0) out[it] = bj;
        const int  ur  = bj >> 6;                  // wave-uniform
        const bool own = ((bj & 63) == l);
        if (ur < 16) {
            #pragma unroll
            for (int u = 0; u < 16; ++u)
                if (own && u == ur) v[u] = -FLT_MAX;
            m0 = v[0]; u0 = 0;
            #pragma unroll
            for (int u = 1; u < 16; ++u) if (v[u] > m0) { m0 = v[u]; u0 = u; }
        } else {
            #pragma unroll
            for (int u = 16; u < 32; ++u)
                if (own && u == ur) v[u] = -FLT_MAX;
            m1 = v[16]; u1 = 16;
            #pragma unroll
            for (int u = 17; u < 32; ++u) if (v[u] > m1) { m1 = v[u]; u1 = u; }
        }
    }
}

// ---------------------------------------------------------------- U/V' hi-lo prep
__global__ __launch_bounds__(256) void uvprep_kernel(const float* __restrict__ W,
                                                     int cin, int cout,
                                                     short* __restrict__ bhi,
                                                     short* __restrict__ blo) {
    int e = blockIdx.x * 256 + threadIdx.x;
    if (e >= cout * cin) return;
    int o = e / cin, c = e - o * cin;
    float u  = W[(size_t)o * (2 * cin) + c];
    float vv = W[(size_t)o * (2 * cin) + cin + c];
    float vp = vv - u;
    unsigned hu = f2bf_rne(u);
    unsigned lu = __float_as_uint(u - bf2f(hu)) >> 16;
    unsigned hv = f2bf_rne(vp);
    unsigned lv = __float_as_uint(vp - bf2f(hv)) >> 16;
    bhi[(size_t)o * cin + c] = (short)hu;
    blo[(size_t)o * cin + c] = (short)lu;
    bhi[(size_t)(cout + o) * cin + c] = (short)hv;
    blo[(size_t)(cout + o) * cin + c] = (short)lv;
}

// ---------------------------------------------------------------- Wf hi/lo prep (flat)
__global__ __launch_bounds__(256) void wfprep_kernel(const float* __restrict__ Wf,
                                                     short* __restrict__ whi,
                                                     short* __restrict__ wlo) {
    int e = blockIdx.x * 256 + threadIdx.x;
    float v = Wf[e];
    unsigned h = f2bf_rne(v);
    unsigned lo = __float_as_uint(v - bf2f(h)) >> 16;
    whi[e] = (short)h;
    wlo[e] = (short)lo;
}

// ---------------------------------------------------------------- node GEMM via MFMA (bf16 hi/lo, 3-term)
template<int KC>
__global__ __launch_bounds__(256) void gemm_node(const float* __restrict__ h, int istr,
                                                 const short* __restrict__ bhi_,
                                                 const short* __restrict__ blo_,
                                                 int nstr,
                                                 float* __restrict__ out) {
    constexpr int PLANE = 64 * 64 * 2;
    __shared__ short A[2 * 64 * 64];
    const int t    = threadIdx.x;
    const int mb   = blockIdx.x;
    const int ny   = blockIdx.y;
    const int row0 = mb * 64;
    const int l = t & 63, w = t >> 6, g = l >> 4, cl = l & 15;

    f32x4 acc[4][2];
    #pragma unroll
    for (int mt = 0; mt < 4; ++mt)
        #pragma unroll
        for (int nt = 0; nt < 2; ++nt)
            acc[mt][nt] = (f32x4){0.f, 0.f, 0.f, 0.f};

    char* Ab = (char*)A;
    #pragma unroll 1
    for (int kc = 0; kc < KC; ++kc) {
        for (int u = t; u < 64 * 32; u += 256) {
            int row = u >> 5, cp = u & 31;
            const float* src = &h[(size_t)(row0 + row) * istr + kc * 64 + cp * 2];
            float d0 = src[0], d1 = src[1];
            unsigned h0 = f2bf_rne(d0), h1 = f2bf_rne(d1);
            unsigned l0 = __float_as_uint(d0 - bf2f(h0)) >> 16;
            unsigned l1 = __float_as_uint(d1 - bf2f(h1)) >> 16;
            int byte = row * 128 + cp * 4;
            byte ^= ((row & 7) << 4);
            *(unsigned*)(Ab + byte)         = h0 | (h1 << 16);
            *(unsigned*)(Ab + PLANE + byte) = l0 | (l1 << 16);
        }
        __syncthreads();

        short8 bh[2][2], bl[2][2];
        #pragma unroll
        for (int ks = 0; ks < 2; ++ks)
            #pragma unroll
            for (int nt = 0; nt < 2; ++nt) {
                int o = ny * 128 + (w * 2 + nt) * 16 + cl;
                size_t koff = (size_t)o * (KC * 64) + kc * 64 + ks * 32 + g * 8;
                bh[ks][nt] = *(const short8*)(bhi_ + koff);
                bl[ks][nt] = *(const short8*)(blo_ + koff);
            }
        short8 ah[2][4];
        #pragma unroll
        for (int ks = 0; ks < 2; ++ks)
            #pragma unroll
            for (int mt = 0; mt < 4; ++mt) {
                int row  = mt * 16 + cl;
                int byte = row * 128 + (ks * 32 + g * 8) * 2;
                byte ^= ((row & 7) << 4);
                ah[ks][mt] = *(const short8*)(Ab + byte);
            }
        #pragma unroll
        for (int ks = 0; ks < 2; ++ks)
            #pragma unroll
            for (int mt = 0; mt < 4; ++mt)
                #pragma unroll
                for (int nt = 0; nt < 2; ++nt)
                    acc[mt][nt] = __builtin_amdgcn_mfma_f32_16x16x32_bf16(
                        ah[ks][mt], bh[ks][nt], acc[mt][nt], 0, 0, 0);
        #pragma unroll
        for (int ks = 0; ks < 2; ++ks)
            #pragma unroll
            for (int mt = 0; mt < 4; ++mt)
                #pragma unroll
                for (int nt = 0; nt < 2; ++nt)
                    acc[mt][nt] = __builtin_amdgcn_mfma_f32_16x16x32_bf16(
                        ah[ks][mt], bl[ks][nt], acc[mt][nt], 0, 0, 0);
        short8 al[2][4];
        #pragma unroll
        for (int ks = 0; ks < 2; ++ks)
            #pragma unroll
            for (int mt = 0; mt < 4; ++mt) {
                int row  = mt * 16 + cl;
                int byte = row * 128 + (ks * 32 + g * 8) * 2;
                byte ^= ((row & 7) << 4);
                al[ks][mt] = *(const short8*)(Ab + PLANE + byte);
            }
        #pragma unroll
        for (int ks = 0; ks < 2; ++ks)
            #pragma unroll
            for (int mt = 0; mt < 4; ++mt)
                #pragma unroll
                for (int nt = 0; nt < 2; ++nt)
                    acc[mt][nt] = __builtin_amdgcn_mfma_f32_16x16x32_bf16(
                        al[ks][mt], bh[ks][nt], acc[mt][nt], 0, 0, 0);
        __syncthreads();
    }

    #pragma unroll
    for (int nt = 0; nt < 2; ++nt) {
        int col = ny * 128 + (w * 2 + nt) * 16 + cl;
        #pragma unroll
        for (int mt = 0; mt < 4; ++mt) {
            #pragma unroll
            for (int j = 0; j < 4; ++j) {
                int row = row0 + mt * 16 + g * 4 + j;
                out[(size_t)row * nstr + col] = acc[mt][nt][j];
            }
        }
    }
}

// ---------------------------------------------------------------- gather-max epilogue
template<int COUT, int PPB>
__global__ __launch_bounds__(256) void gather_max(const float* __restrict__ GC, int nstr,
                                                  const int* __restrict__ knn_idx,
                                                  const float* __restrict__ bias,
                                                  float* __restrict__ hout) {
    static_assert(COUT * PPB == 256, "block 256");
    const int t  = threadIdx.x;
    const int pl = t / COUT;
    const int o  = t - pl * COUT;
    const int p  = blockIdx.x * PPB + pl;
    const int base = (p >> 11) << 11;
    const int* jrow = knn_idx + (size_t)p * KNN;

    float mx = -FLT_MAX;
    #pragma unroll
    for (int k = 0; k < KNN; ++k) {
        int j = jrow[k];
        mx = fmaxf(mx, GC[(size_t)(base + j) * nstr + o]);
    }
    float val = mx + GC[(size_t)p * nstr + COUT + o] + bias[o];
    val = val > 0.f ? val : 0.2f * val;
    hout[(size_t)p * FSTR + o] = val;
}

// ---------------------------------------------------------------- EdgeConv L0 (CIN=3, fp32 VALU)
template<int CIN, int COUT, int PPB>
__global__ __launch_bounds__(256) void edge_kernel(const float* __restrict__ hin,
                                                   int istr,
                                                   const float* __restrict__ W,
                                                   const float* __restrict__ bias,
                                                   const int* __restrict__ knn_idx,
                                                   float* __restrict__ hout) {
    constexpr int TPP = COUT / 2;
    static_assert(PPB * TPP == 256, "block must be 256 threads");
    __shared__ float diff[PPB][KNN][CIN];
    __shared__ float hi[PPB][CIN];
    __shared__ int   nj[PPB][KNN];

    const int t    = threadIdx.x;
    const int r0   = blockIdx.x * PPB;
    const int base = (r0 >> 11) << 11;

    for (int e = t; e < PPB * KNN; e += 256) {
        int p = e / KNN, kk = e - p * KNN;
        nj[p][kk] = knn_idx[(size_t)(r0 + p) * KNN + kk];
    }
    for (int e = t; e < PPB * CIN; e += 256) {
        int p = e / CIN, c = e - p * CIN;
        hi[p][c] = hin[(size_t)(r0 + p) * istr + c];
    }
    __syncthreads();
    for (int e = t; e < PPB * KNN * CIN; e += 256) {
        int p  = e / (KNN * CIN);
        int rm = e - p * (KNN * CIN);
        int kk = rm / CIN, c = rm - kk * CIN;
        diff[p][kk][c] = hin[(size_t)(base + nj[p][kk]) * istr + c] - hi[p][c];
    }
    __syncthreads();

    const int p  = t / TPP;
    const int oo = t - p * TPP;
    const float* W0 = W + (size_t)oo * (2 * CIN);
    const float* W1 = W + (size_t)(oo + TPP) * (2 * CIN);

    float ctr0 = bias[oo], ctr1 = bias[oo + TPP];
    float acc[2][KNN];
    #pragma unroll
    for (int kk = 0; kk < KNN; ++kk) { acc[0][kk] = 0.f; acc[1][kk] = 0.f; }

    for (int c = 0; c < CIN; ++c) {
        float hv = hi[p][c];
        ctr0 += W0[CIN + c] * hv;
        ctr1 += W1[CIN + c] * hv;
    }
    for (int c = 0; c < CIN; ++c) {
        float w0 = W0[c], w1 = W1[c];
        #pragma unroll
        for (int kk = 0; kk < KNN; ++kk) {
            float d = diff[p][kk][c];
            acc[0][kk] += w0 * d;
            acc[1][kk] += w1 * d;
        }
    }

    float m0 = -FLT_MAX, m1 = -FLT_MAX;
    #pragma unroll
    for (int kk = 0; kk < KNN; ++kk) {
        m0 = fmaxf(m0, acc[0][kk] + ctr0);
        m1 = fmaxf(m1, acc[1][kk] + ctr1);
    }
    float r0v = m0 > 0.f ? m0 : 0.2f * m0;
    float r1v = m1 > 0.f ? m1 : 0.2f * m1;
    hout[(size_t)(r0 + p) * FSTR + oo]       = r0v;
    hout[(size_t)(r0 + p) * FSTR + oo + TPP] = r1v;
}

// ---------------------------------------------------------------- final GEMM via MFMA (bf16 hi/lo, 3-term) + col-max
__global__ __launch_bounds__(256) void final_mfma(const float* __restrict__ f,
                                                  const short* __restrict__ wfhi,
                                                  const short* __restrict__ wflo,
                                                  float* __restrict__ partial) {
    constexpr int PLANE = 64 * 64 * 2;
    __shared__ short A[2 * 64 * 64];
    const int t    = threadIdx.x;
    const int mb   = blockIdx.x;
    const int ny   = blockIdx.y;
    const int row0 = mb * 64;
    const int l = t & 63, w = t >> 6, g = l >> 4, cl = l & 15;

    f32x4 acc[4][2];
    #pragma unroll
    for (int mt = 0; mt < 4; ++mt)
        #pragma unroll
        for (int nt = 0; nt < 2; ++nt)
            acc[mt][nt] = (f32x4){0.f, 0.f, 0.f, 0.f};

    char* Ab = (char*)A;
    #pragma unroll 1
    for (int kc = 0; kc < 8; ++kc) {
        for (int u = t; u < 64 * 32; u += 256) {
            int row = u >> 5, cp = u & 31;
            const float* src = &f[(size_t)(row0 + row) * FSTR + kc * 64 + cp * 2];
            float d0 = src[0], d1 = src[1];
            unsigned h0 = f2bf_rne(d0), h1 = f2bf_rne(d1);
            unsigned l0 = __float_as_uint(d0 - bf2f(h0)) >> 16;
            unsigned l1 = __float_as_uint(d1 - bf2f(h1)) >> 16;
            int byte = row * 128 + cp * 4;
            byte ^= ((row & 7) << 4);
            *(unsigned*)(Ab + byte)         = h0 | (h1 << 16);
            *(unsigned*)(Ab + PLANE + byte) = l0 | (l1 << 16);
        }
        __syncthreads();

        short8 bh[2][2], bl[2][2];
        #pragma unroll
        for (int ks = 0; ks < 2; ++ks)
            #pragma unroll
            for (int nt = 0; nt < 2; ++nt) {
                int o = ny * 128 + (w * 2 + nt) * 16 + cl;
                size_t koff = (size_t)o * 512 + kc * 64 + ks * 32 + g * 8;
                bh[ks][nt] = *(const short8*)(wfhi + koff);
                bl[ks][nt] = *(const short8*)(wflo + koff);
            }
        short8 ah[2][4];
        #pragma unroll
        for (int ks = 0; ks < 2; ++ks)
            #pragma unroll
            for (int mt = 0; mt < 4; ++mt) {
                int row  = mt * 16 + cl;
                int byte = row * 128 + (ks * 32 + g * 8) * 2;
                byte ^= ((row & 7) << 4);
                ah[ks][mt] = *(const short8*)(Ab + byte);
            }
        #pragma unroll
        for (int ks = 0; ks < 2; ++ks)
            #pragma unroll
            for (int mt = 0; mt < 4; ++mt)
                #pragma unroll
                for (int nt = 0; nt < 2; ++nt)
                    acc[mt][nt] = __builtin_amdgcn_mfma_f32_16x16x32_bf16(
                        ah[ks][mt], bh[ks][nt], acc[mt][nt], 0, 0, 0);
        #pragma unroll
        for (int ks = 0; ks < 2; ++ks)
            #pragma unroll
            for (int mt = 0; mt < 4; ++mt)
                #pragma unroll
                for (int nt = 0; nt < 2; ++nt)
                    acc[mt][nt] = __builtin_amdgcn_mfma_f32_16x16x32_bf16(
                        ah[ks][mt], bl[ks][nt], acc[mt][nt], 0, 0, 0);
        short8 al[2][4];
        #pragma unroll
        for (int ks = 0; ks < 2; ++ks)
            #pragma unroll
            for (int mt = 0; mt < 4; ++mt) {
                int row  = mt * 16 + cl;
                int byte = row * 128 + (ks * 32 + g * 8) * 2;
                byte ^= ((row & 7) << 4);
                al[ks][mt] = *(const short8*)(Ab + PLANE + byte);
            }
        #pragma unroll
        for (int ks = 0; ks < 2; ++ks)
            #pragma unroll
            for (int mt = 0; mt < 4; ++mt)
                #pragma unroll
                for (int nt = 0; nt < 2; ++nt)
                    acc[mt][nt] = __builtin_amdgcn_mfma_f32_16x16x32_bf16(
                        al[ks][mt], bh[ks][nt], acc[mt][nt], 0, 0, 0);
        __syncthreads();
    }

    #pragma unroll
    for (int nt = 0; nt < 2; ++nt) {
        float pm = -FLT_MAX;
        #pragma unroll
        for (int mt = 0; mt < 4; ++mt) {
            f32x4 v = acc[mt][nt];
            pm = fmaxf(pm, fmaxf(fmaxf(v[0], v[1]), fmaxf(v[2], v[3])));
        }
        pm = fmaxf(pm, __shfl_xor(pm, 16));
        pm = fmaxf(pm, __shfl_xor(pm, 32));
        if (g == 0) {
            int col = ny * 128 + (w * 2 + nt) * 16 + cl;
            partial[(size_t)mb * 1024 + col] = pm;
        }
    }
}

__global__ __launch_bounds__(256) void final_reduce(const float* __restrict__ partial,
                                                    const float* __restrict__ bf,
                                                    float* __restrict__ out) {
    int g = blockIdx.x * 256 + threadIdx.x;
    int b = g >> 10, o = g & 1023;
    float m = -FLT_MAX;
    for (int mb = 0; mb < 32; ++mb)
        m = fmaxf(m, partial[((size_t)(b * 32 + mb)) * 1024 + o]);
    out[g] = m + bf[o];
}

// ---------------------------------------------------------------- launch
extern "C" void kernel_launch(void* const* d_in, const int* in_sizes, int n_in,
                              void* d_out, int out_size, void* d_ws, size_t ws_size,
                              hipStream_t stream) {
    const float* x  = (const float*)d_in[0];
    const float* W0 = (const float*)d_in[1];
    const float* b0 = (const float*)d_in[2];
    const float* W1 = (const float*)d_in[3];
    const float* b1 = (const float*)d_in[4];
    const float* W2 = (const float*)d_in[5];
    const float* b2 = (const float*)d_in[6];
    const float* W3 = (const float*)d_in[7];
    const float* b3 = (const float*)d_in[8];
    const float* Wf = (const float*)d_in[9];
    const float* bf = (const float*)d_in[10];
    (void)in_sizes; (void)n_in; (void)out_size; (void)ws_size;

    char* ws = (char*)d_ws;
    size_t off = 0;
    float* feats = (float*)(ws + off); off += (size_t)BN * FSTR * 4;        // 32 MB
    float* sq    = (float*)(ws + off); off += (size_t)BN * 4;               // 64 KB
    int*   idx   = (int*)  (ws + off); off += (size_t)BN * KNN * 4;         // 1.25 MB
    float* GC    = (float*)(ws + off); off += (size_t)BN * 512 * 4;         // 32 MB
    float* partial = GC;               // alias: GC free when final phase runs
    short* hhi   = (short*)(ws + off); off += (size_t)BN * 128 * 2;         // 4 MB
    short* hlo   = (short*)(ws + off); off += (size_t)BN * 128 * 2;         // 4 MB
    short* ebhi  = (short*)(ws + off); off += (size_t)90112 * 2;
    short* eblo  = (short*)(ws + off); off += (size_t)90112 * 2;
    short* wfhi  = (short*)(ws + off); off += (size_t)1024 * 512 * 2;       // 1 MB
    short* wflo  = (short*)(ws + off); off += (size_t)1024 * 512 * 2;       // 1 MB
    float* gram  = (float*)(ws + off); off += (size_t)4 * NP * NP * 4;      // 64 MB
    short* b1hi = ebhi,         *b1lo = eblo;                               // 128 x 64
    short* b2hi = ebhi + 8192,  *b2lo = eblo + 8192;                        // 256 x 64
    short* b3hi = ebhi + 24576, *b3lo = eblo + 24576;                       // 512 x 128

    // weight preps
    uvprep_kernel<<<16, 256, 0, stream>>>(W1, 64, 64, b1hi, b1lo);
    uvprep_kernel<<<32, 256, 0, stream>>>(W2, 64, 128, b2hi, b2lo);
    uvprep_kernel<<<128, 256, 0, stream>>>(W3, 128, 256, b3hi, b3lo);
    wfprep_kernel<<<2048, 256, 0, stream>>>(Wf, wfhi, wflo);

    // Layer 0: C=3 -> 64 @ feats[0:64]  (fp32 VALU)
    sq_kernel<3><<<BN / 256, 256, 0, stream>>>(x, 3, sq);
    knn_kernel<3><<<BN / 4, 256, 0, stream>>>(x, 3, sq, idx);
    edge_kernel<3, 64, 8><<<BN / 8, 256, 0, stream>>>(x, 3, W0, b0, idx, feats + 0);

    // Layer 1: 64 -> 64 @ feats[64:128]
    sq_kernel<64><<<BN / 256, 256, 0, stream>>>(feats + 0, FSTR, sq);
    hprep_kernel<<<(BN * 64) / 256, 256, 0, stream>>>(feats + 0, FSTR, 64, BN * 64, hhi, hlo);
    for (int grp = 0; grp < 2; ++grp) {
        int g0 = grp * 4 * NP;
        gram_mfma<1><<<dim3(128, 16), 256, 0, stream>>>(feats + 0, FSTR, hhi, hlo, sq, g0, gram);
        select_topk<<<4 * NP / 8, 512, 0, stream>>>(gram, g0, idx);
    }
    gemm_node<1><<<dim3(BN / 64, 1), 256, 0, stream>>>(feats + 0, FSTR, b1hi, b1lo, 128, GC);
    gather_max<64, 4><<<BN / 4, 256, 0, stream>>>(GC, 128, idx, b1, feats + 64);

    // Layer 2: 64 -> 128 @ feats[128:256]
    sq_kernel<64><<<BN / 256, 256, 0, stream>>>(feats + 64, FSTR, sq);
    hprep_kernel<<<(BN * 64) / 256, 256, 0, stream>>>(feats + 64, FSTR, 64, BN * 64, hhi, hlo);
    for (int grp = 0; grp < 2; ++grp) {
        int g0 = grp * 4 * NP;
        gram_mfma<1><<<dim3(128, 16), 256, 0, stream>>>(feats + 64, FSTR, hhi, hlo, sq, g0, gram);
        select_topk<<<4 * NP / 8, 512, 0, stream>>>(gram, g0, idx);
    }
    gemm_node<1><<<dim3(BN / 64, 2), 256, 0, stream>>>(feats + 64, FSTR, b2hi, b2lo, 256, GC);
    gather_max<128, 2><<<BN / 2, 256, 0, stream>>>(GC, 256, idx, b2, feats + 128);

    // Layer 3: 128 -> 256 @ feats[256:512]
    sq_kernel<128><<<BN / 256, 256, 0, stream>>>(feats + 128, FSTR, sq);
    hprep_kernel<<<(BN * 128) / 256, 256, 0, stream>>>(feats + 128, FSTR, 128, BN * 128, hhi, hlo);
    for (int grp = 0; grp < 2; ++grp) {
        int g0 = grp * 4 * NP;
        gram_mfma<2><<<dim3(128, 16), 256, 0, stream>>>(feats + 128, FSTR, hhi, hlo, sq, g0, gram);
        select_topk<<<4 * NP / 8, 512, 0, stream>>>(gram, g0, idx);
    }
    gemm_node<2><<<dim3(BN / 64, 4), 256, 0, stream>>>(feats + 128, FSTR, b3hi, b3lo, 512, GC);
    gather_max<256, 1><<<BN, 256, 0, stream>>>(GC, 512, idx, b3, feats + 256);

    // Final 512 -> 1024 + global max pool (MFMA)
    final_mfma<<<dim3(BN / 64, 8), 256, 0, stream>>>(feats, wfhi, wflo, partial);
    final_reduce<<<32, 256, 0, stream>>>(partial, bf, (float*)d_out);
}

// Round 12
// 865.464 us; speedup vs baseline: 5.0289x; 1.0907x over previous
//
#include <hip/hip_runtime.h>
#include <float.h>

constexpr int NB   = 8;      // batches
constexpr int NP   = 2048;   // points per batch
constexpr int BN   = NB * NP;
constexpr int KNN  = 20;     // neighbors
constexpr int FSTR = 512;    // feats row stride (64+64+128+256)

typedef short short8 __attribute__((ext_vector_type(8)));
typedef float f32x4  __attribute__((ext_vector_type(4)));

__device__ __forceinline__ unsigned f2bf_rne(float x) {
    unsigned u = __float_as_uint(x);
    unsigned r = (u >> 16) & 1;
    return (u + 0x7fffu + r) >> 16;
}
__device__ __forceinline__ float bf2f(unsigned h) { return __uint_as_float(h << 16); }

// ---------------------------------------------------------------- sq = |h|^2
template<int C>
__global__ __launch_bounds__(256) void sq_kernel(const float* __restrict__ h,
                                                 int istr,
                                                 float* __restrict__ sq) {
    int i = blockIdx.x * 256 + threadIdx.x;
    if (i >= BN) return;
    const float* p = h + (size_t)i * istr;
    float s = 0.f;
    #pragma unroll
    for (int c = 0; c < C; ++c) { float v = p[c]; s += v * v; }
    sq[i] = s;
}

// ---------------------------------------------------------------- kNN top-20 (C=3 path)
// Distance row into LDS, then register-resident two-half incremental argmax
// (same proven scheme as select_topk).
template<int C>
__global__ __launch_bounds__(256) void knn_kernel(const float* __restrict__ h,
                                                  int istr,
                                                  const float* __restrict__ sq,
                                                  int* __restrict__ knn_idx) {
    constexpr int GI = 4;
    __shared__ float negd[GI][NP];          // 32 KB
    const int t    = threadIdx.x;
    const int r0   = blockIdx.x * GI;
    const int base = (r0 >> 11) << 11;

    float hi[GI][3], sqi[GI];
    #pragma unroll
    for (int g = 0; g < GI; ++g) {
        const float* p = h + (size_t)(r0 + g) * istr;
        hi[g][0] = p[0]; hi[g][1] = p[1]; hi[g][2] = p[2];
        sqi[g] = sq[r0 + g];
    }
    for (int j = t; j < NP; j += 256) {
        const float* pj = h + (size_t)(base + j) * istr;
        float x0 = pj[0], x1 = pj[1], x2 = pj[2];
        float sqj = sq[base + j];
        #pragma unroll
        for (int g = 0; g < GI; ++g) {
            float d = hi[g][0]*x0 + hi[g][1]*x1 + hi[g][2]*x2;
            negd[g][j] = 2.f * d - sqi[g] - sqj;
        }
    }
    __syncthreads();

    // ---- selection: wave w owns row w; v[32] in regs, two-half incremental argmax.
    const int w = t >> 6;
    const int l = t & 63;
    const float* row = &negd[w][0];
    float v[32];
    #pragma unroll
    for (int u = 0; u < 32; ++u) v[u] = row[l + 64 * u];
    float m0 = v[0], m1 = v[16];
    int   u0 = 0,    u1 = 16;
    #pragma unroll
    for (int u = 1; u < 16; ++u)  { if (v[u] > m0) { m0 = v[u]; u0 = u; } }
    #pragma unroll
    for (int u = 17; u < 32; ++u) { if (v[u] > m1) { m1 = v[u]; u1 = u; } }

    int* out = knn_idx + (size_t)(r0 + w) * KNN;
    for (int it = 0; it < KNN; ++it) {
        float bv; int bu;
        if (m0 >= m1) { bv = m0; bu = u0; } else { bv = m1; bu = u1; }
        int bj = l + (bu << 6);
        #pragma unroll
        for (int off = 1; off < 64; off <<= 1) {
            float ov = __shfl_xor(bv, off);
            int   oj = __shfl_xor(bj, off);
            if (ov > bv || (ov == bv && oj < bj)) { bv = ov; bj = oj; }
        }
        if (l == 0) out[it] = bj;
        const int  ur  = bj >> 6;                  // wave-uniform
        const bool own = ((bj & 63) == l);
        if (ur < 16) {
            #pragma unroll
            for (int u = 0; u < 16; ++u)
                if (own && u == ur) v[u] = -FLT_MAX;
            m0 = v[0]; u0 = 0;
            #pragma unroll
            for (int u = 1; u < 16; ++u) if (v[u] > m0) { m0 = v[u]; u0 = u; }
        } else {
            #pragma unroll
            for (int u = 16; u < 32; ++u)
                if (own && u == ur) v[u] = -FLT_MAX;
            m1 = v[16]; u1 = 16;
            #pragma unroll
            for (int u = 17; u < 32; ++u) if (v[u] > m1) { m1 = v[u]; u1 = u; }
        }
    }
}

// ---------------------------------------------------------------- H hi/lo plane prep
__global__ __launch_bounds__(256) void hprep_kernel(const float* __restrict__ h, int istr,
                                                    int cin, int total,
                                                    short* __restrict__ hhi,
                                                    short* __restrict__ hlo) {
    int e = blockIdx.x * 256 + threadIdx.x;
    if (e >= total) return;
    int r = e / cin, c = e - r * cin;
    float v = h[(size_t)r * istr + c];
    unsigned hh = f2bf_rne(v);
    unsigned ll = __float_as_uint(v - bf2f(hh)) >> 16;
    hhi[e] = (short)hh;
    hlo[e] = (short)ll;
}

// ---------------------------------------------------------------- Gram via MFMA (bf16 hi/lo, 3-term)
template<int KC>    // K = KC*64 = C
__global__ __launch_bounds__(256) void gram_mfma(const float* __restrict__ h, int istr,
                                                 const short* __restrict__ hhi,
                                                 const short* __restrict__ hlo,
                                                 const float* __restrict__ sq,
                                                 int g0,
                                                 float* __restrict__ gram) {
    constexpr int PLANE = 64 * 64 * 2;
    __shared__ short A[2 * 64 * 64];               // 16 KB
    const int t   = threadIdx.x;
    const int bx  = blockIdx.x;
    const int ct  = blockIdx.y;
    const int big = bx >> 5, rt = bx & 31;
    const int bbase = g0 + big * NP;               // batch base (global row)
    const int row0g = bbase + rt * 64;
    const int l = t & 63, w = t >> 6, g = l >> 4, cl = l & 15;

    f32x4 acc[4][2];
    #pragma unroll
    for (int mt = 0; mt < 4; ++mt)
        #pragma unroll
        for (int nt = 0; nt < 2; ++nt)
            acc[mt][nt] = (f32x4){0.f, 0.f, 0.f, 0.f};

    char* Ab = (char*)A;
    #pragma unroll 1
    for (int kc = 0; kc < KC; ++kc) {
        for (int u = t; u < 64 * 32; u += 256) {
            int row = u >> 5, cp = u & 31;
            const float* src = &h[(size_t)(row0g + row) * istr + kc * 64 + cp * 2];
            float d0 = src[0], d1 = src[1];
            unsigned h0 = f2bf_rne(d0), h1 = f2bf_rne(d1);
            unsigned l0 = __float_as_uint(d0 - bf2f(h0)) >> 16;
            unsigned l1 = __float_as_uint(d1 - bf2f(h1)) >> 16;
            int byte = row * 128 + cp * 4;
            byte ^= ((row & 7) << 4);
            *(unsigned*)(Ab + byte)         = h0 | (h1 << 16);
            *(unsigned*)(Ab + PLANE + byte) = l0 | (l1 << 16);
        }
        __syncthreads();

        short8 bh[2][2], bl[2][2];
        #pragma unroll
        for (int ks = 0; ks < 2; ++ks)
            #pragma unroll
            for (int nt = 0; nt < 2; ++nt) {
                int col = ct * 128 + (w * 2 + nt) * 16 + cl;
                size_t koff = (size_t)(bbase + col) * (KC * 64) + kc * 64 + ks * 32 + g * 8;
                bh[ks][nt] = *(const short8*)(hhi + koff);
                bl[ks][nt] = *(const short8*)(hlo + koff);
            }
        short8 ah[2][4];
        #pragma unroll
        for (int ks = 0; ks < 2; ++ks)
            #pragma unroll
            for (int mt = 0; mt < 4; ++mt) {
                int row  = mt * 16 + cl;
                int byte = row * 128 + (ks * 32 + g * 8) * 2;
                byte ^= ((row & 7) << 4);
                ah[ks][mt] = *(const short8*)(Ab + byte);
            }
        #pragma unroll
        for (int ks = 0; ks < 2; ++ks)
            #pragma unroll
            for (int mt = 0; mt < 4; ++mt)
                #pragma unroll
                for (int nt = 0; nt < 2; ++nt)
                    acc[mt][nt] = __builtin_amdgcn_mfma_f32_16x16x32_bf16(
                        ah[ks][mt], bh[ks][nt], acc[mt][nt], 0, 0, 0);
        #pragma unroll
        for (int ks = 0; ks < 2; ++ks)
            #pragma unroll
            for (int mt = 0; mt < 4; ++mt)
                #pragma unroll
                for (int nt = 0; nt < 2; ++nt)
                    acc[mt][nt] = __builtin_amdgcn_mfma_f32_16x16x32_bf16(
                        ah[ks][mt], bl[ks][nt], acc[mt][nt], 0, 0, 0);
        short8 al[2][4];
        #pragma unroll
        for (int ks = 0; ks < 2; ++ks)
            #pragma unroll
            for (int mt = 0; mt < 4; ++mt) {
                int row  = mt * 16 + cl;
                int byte = row * 128 + (ks * 32 + g * 8) * 2;
                byte ^= ((row & 7) << 4);
                al[ks][mt] = *(const short8*)(Ab + PLANE + byte);
            }
        #pragma unroll
        for (int ks = 0; ks < 2; ++ks)
            #pragma unroll
            for (int mt = 0; mt < 4; ++mt)
                #pragma unroll
                for (int nt = 0; nt < 2; ++nt)
                    acc[mt][nt] = __builtin_amdgcn_mfma_f32_16x16x32_bf16(
                        al[ks][mt], bh[ks][nt], acc[mt][nt], 0, 0, 0);
        __syncthreads();
    }

    // epilogue: negd = 2*acc - sq_r - sq_c
    #pragma unroll
    for (int nt = 0; nt < 2; ++nt) {
        int col = ct * 128 + (w * 2 + nt) * 16 + cl;
        float sqc = sq[bbase + col];
        #pragma unroll
        for (int mt = 0; mt < 4; ++mt) {
            #pragma unroll
            for (int j = 0; j < 4; ++j) {
                int rl = rt * 64 + mt * 16 + g * 4 + j;
                float val = 2.f * acc[mt][nt][j] - sq[bbase + rl] - sqc;
                gram[(size_t)(big * NP + rl) * NP + col] = val;
            }
        }
    }
}

// ---------------------------------------------------------------- top-20 selection from gram rows
__global__ __launch_bounds__(512) void select_topk(const float* __restrict__ gram,
                                                   int g0,
                                                   int* __restrict__ knn_idx) {
    const int t = threadIdx.x, w = t >> 6, l = t & 63;
    const int rlocal = blockIdx.x * 8 + w;
    const float* row = gram + (size_t)rlocal * NP;

    float v[32];
    #pragma unroll
    for (int u = 0; u < 32; ++u) v[u] = row[l + 64 * u];
    float m0 = v[0], m1 = v[16];
    int   u0 = 0,    u1 = 16;
    #pragma unroll
    for (int u = 1; u < 16; ++u)  { if (v[u] > m0) { m0 = v[u]; u0 = u; } }
    #pragma unroll
    for (int u = 17; u < 32; ++u) { if (v[u] > m1) { m1 = v[u]; u1 = u; } }

    int* out = knn_idx + (size_t)(g0 + rlocal) * KNN;
    for (int it = 0; it < KNN; ++it) {
        float bv; int bu;
        if (m0 >= m1) { bv = m0; bu = u0; } else { bv = m1; bu = u1; }
        int bj = l + (bu << 6);
        #pragma unroll
        for (int off = 1; off < 64; off <<= 1) {
            float ov = __shfl_xor(bv, off);
            int   oj = __shfl_xor(bj, off);
            if (ov > bv || (ov == bv && oj < bj)) { bv = ov; bj = oj; }
        }
        if (l == 0) out[it] = bj;
        const int  ur  = bj >> 6;
        const bool own = ((bj & 63) == l);
        if (ur < 16) {
            #pragma unroll
            for (int u = 0; u < 16; ++u)
                if (own && u == ur) v[u] = -FLT_MAX;
            m0 = v[0]; u0 = 0;
            #pragma unroll
            for (int u = 1; u < 16; ++u) if (v[u] > m0) { m0 = v[u]; u0 = u; }
        } else {
            #pragma unroll
            for (int u = 16; u < 32; ++u)
                if (own && u == ur) v[u] = -FLT_MAX;
            m1 = v[16]; u1 = 16;
            #pragma unroll
            for (int u = 17; u < 32; ++u) if (v[u] > m1) { m1 = v[u]; u1 = u; }
        }
    }
}

// ---------------------------------------------------------------- U/V' hi-lo prep
__global__ __launch_bounds__(256) void uvprep_kernel(const float* __restrict__ W,
                                                     int cin, int cout,
                                                     short* __restrict__ bhi,
                                                     short* __restrict__ blo) {
    int e = blockIdx.x * 256 + threadIdx.x;
    if (e >= cout * cin) return;
    int o = e / cin, c = e - o * cin;
    float u  = W[(size_t)o * (2 * cin) + c];
    float vv = W[(size_t)o * (2 * cin) + cin + c];
    float vp = vv - u;
    unsigned hu = f2bf_rne(u);
    unsigned lu = __float_as_uint(u - bf2f(hu)) >> 16;
    unsigned hv = f2bf_rne(vp);
    unsigned lv = __float_as_uint(vp - bf2f(hv)) >> 16;
    bhi[(size_t)o * cin + c] = (short)hu;
    blo[(size_t)o * cin + c] = (short)lu;
    bhi[(size_t)(cout + o) * cin + c] = (short)hv;
    blo[(size_t)(cout + o) * cin + c] = (short)lv;
}

// ---------------------------------------------------------------- Wf hi/lo prep (flat)
__global__ __launch_bounds__(256) void wfprep_kernel(const float* __restrict__ Wf,
                                                     short* __restrict__ whi,
                                                     short* __restrict__ wlo) {
    int e = blockIdx.x * 256 + threadIdx.x;
    float v = Wf[e];
    unsigned h = f2bf_rne(v);
    unsigned lo = __float_as_uint(v - bf2f(h)) >> 16;
    whi[e] = (short)h;
    wlo[e] = (short)lo;
}

// ---------------------------------------------------------------- node GEMM via MFMA (bf16 hi/lo, 3-term)
template<int KC>
__global__ __launch_bounds__(256) void gemm_node(const float* __restrict__ h, int istr,
                                                 const short* __restrict__ bhi_,
                                                 const short* __restrict__ blo_,
                                                 int nstr,
                                                 float* __restrict__ out) {
    constexpr int PLANE = 64 * 64 * 2;
    __shared__ short A[2 * 64 * 64];
    const int t    = threadIdx.x;
    const int mb   = blockIdx.x;
    const int ny   = blockIdx.y;
    const int row0 = mb * 64;
    const int l = t & 63, w = t >> 6, g = l >> 4, cl = l & 15;

    f32x4 acc[4][2];
    #pragma unroll
    for (int mt = 0; mt < 4; ++mt)
        #pragma unroll
        for (int nt = 0; nt < 2; ++nt)
            acc[mt][nt] = (f32x4){0.f, 0.f, 0.f, 0.f};

    char* Ab = (char*)A;
    #pragma unroll 1
    for (int kc = 0; kc < KC; ++kc) {
        for (int u = t; u < 64 * 32; u += 256) {
            int row = u >> 5, cp = u & 31;
            const float* src = &h[(size_t)(row0 + row) * istr + kc * 64 + cp * 2];
            float d0 = src[0], d1 = src[1];
            unsigned h0 = f2bf_rne(d0), h1 = f2bf_rne(d1);
            unsigned l0 = __float_as_uint(d0 - bf2f(h0)) >> 16;
            unsigned l1 = __float_as_uint(d1 - bf2f(h1)) >> 16;
            int byte = row * 128 + cp * 4;
            byte ^= ((row & 7) << 4);
            *(unsigned*)(Ab + byte)         = h0 | (h1 << 16);
            *(unsigned*)(Ab + PLANE + byte) = l0 | (l1 << 16);
        }
        __syncthreads();

        short8 bh[2][2], bl[2][2];
        #pragma unroll
        for (int ks = 0; ks < 2; ++ks)
            #pragma unroll
            for (int nt = 0; nt < 2; ++nt) {
                int o = ny * 128 + (w * 2 + nt) * 16 + cl;
                size_t koff = (size_t)o * (KC * 64) + kc * 64 + ks * 32 + g * 8;
                bh[ks][nt] = *(const short8*)(bhi_ + koff);
                bl[ks][nt] = *(const short8*)(blo_ + koff);
            }
        short8 ah[2][4];
        #pragma unroll
        for (int ks = 0; ks < 2; ++ks)
            #pragma unroll
            for (int mt = 0; mt < 4; ++mt) {
                int row  = mt * 16 + cl;
                int byte = row * 128 + (ks * 32 + g * 8) * 2;
                byte ^= ((row & 7) << 4);
                ah[ks][mt] = *(const short8*)(Ab + byte);
            }
        #pragma unroll
        for (int ks = 0; ks < 2; ++ks)
            #pragma unroll
            for (int mt = 0; mt < 4; ++mt)
                #pragma unroll
                for (int nt = 0; nt < 2; ++nt)
                    acc[mt][nt] = __builtin_amdgcn_mfma_f32_16x16x32_bf16(
                        ah[ks][mt], bh[ks][nt], acc[mt][nt], 0, 0, 0);
        #pragma unroll
        for (int ks = 0; ks < 2; ++ks)
            #pragma unroll
            for (int mt = 0; mt < 4; ++mt)
                #pragma unroll
                for (int nt = 0; nt < 2; ++nt)
                    acc[mt][nt] = __builtin_amdgcn_mfma_f32_16x16x32_bf16(
                        ah[ks][mt], bl[ks][nt], acc[mt][nt], 0, 0, 0);
        short8 al[2][4];
        #pragma unroll
        for (int ks = 0; ks < 2; ++ks)
            #pragma unroll
            for (int mt = 0; mt < 4; ++mt) {
                int row  = mt * 16 + cl;
                int byte = row * 128 + (ks * 32 + g * 8) * 2;
                byte ^= ((row & 7) << 4);
                al[ks][mt] = *(const short8*)(Ab + PLANE + byte);
            }
        #pragma unroll
        for (int ks = 0; ks < 2; ++ks)
            #pragma unroll
            for (int mt = 0; mt < 4; ++mt)
                #pragma unroll
                for (int nt = 0; nt < 2; ++nt)
                    acc[mt][nt] = __builtin_amdgcn_mfma_f32_16x16x32_bf16(
                        al[ks][mt], bh[ks][nt], acc[mt][nt], 0, 0, 0);
        __syncthreads();
    }

    #pragma unroll
    for (int nt = 0; nt < 2; ++nt) {
        int col = ny * 128 + (w * 2 + nt) * 16 + cl;
        #pragma unroll
        for (int mt = 0; mt < 4; ++mt) {
            #pragma unroll
            for (int j = 0; j < 4; ++j) {
                int row = row0 + mt * 16 + g * 4 + j;
                out[(size_t)row * nstr + col] = acc[mt][nt][j];
            }
        }
    }
}

// ---------------------------------------------------------------- gather-max epilogue
template<int COUT, int PPB>
__global__ __launch_bounds__(256) void gather_max(const float* __restrict__ GC, int nstr,
                                                  const int* __restrict__ knn_idx,
                                                  const float* __restrict__ bias,
                                                  float* __restrict__ hout) {
    static_assert(COUT * PPB == 256, "block 256");
    const int t  = threadIdx.x;
    const int pl = t / COUT;
    const int o  = t - pl * COUT;
    const int p  = blockIdx.x * PPB + pl;
    const int base = (p >> 11) << 11;
    const int* jrow = knn_idx + (size_t)p * KNN;

    float mx = -FLT_MAX;
    #pragma unroll
    for (int k = 0; k < KNN; ++k) {
        int j = jrow[k];
        mx = fmaxf(mx, GC[(size_t)(base + j) * nstr + o]);
    }
    float val = mx + GC[(size_t)p * nstr + COUT + o] + bias[o];
    val = val > 0.f ? val : 0.2f * val;
    hout[(size_t)p * FSTR + o] = val;
}

// ---------------------------------------------------------------- EdgeConv L0 (CIN=3, fp32 VALU)
template<int CIN, int COUT, int PPB>
__global__ __launch_bounds__(256) void edge_kernel(const float* __restrict__ hin,
                                                   int istr,
                                                   const float* __restrict__ W,
                                                   const float* __restrict__ bias,
                                                   const int* __restrict__ knn_idx,
                                                   float* __restrict__ hout) {
    constexpr int TPP = COUT / 2;
    static_assert(PPB * TPP == 256, "block must be 256 threads");
    __shared__ float diff[PPB][KNN][CIN];
    __shared__ float hi[PPB][CIN];
    __shared__ int   nj[PPB][KNN];

    const int t    = threadIdx.x;
    const int r0   = blockIdx.x * PPB;
    const int base = (r0 >> 11) << 11;

    for (int e = t; e < PPB * KNN; e += 256) {
        int p = e / KNN, kk = e - p * KNN;
        nj[p][kk] = knn_idx[(size_t)(r0 + p) * KNN + kk];
    }
    for (int e = t; e < PPB * CIN; e += 256) {
        int p = e / CIN, c = e - p * CIN;
        hi[p][c] = hin[(size_t)(r0 + p) * istr + c];
    }
    __syncthreads();
    for (int e = t; e < PPB * KNN * CIN; e += 256) {
        int p  = e / (KNN * CIN);
        int rm = e - p * (KNN * CIN);
        int kk = rm / CIN, c = rm - kk * CIN;
        diff[p][kk][c] = hin[(size_t)(base + nj[p][kk]) * istr + c] - hi[p][c];
    }
    __syncthreads();

    const int p  = t / TPP;
    const int oo = t - p * TPP;
    const float* W0 = W + (size_t)oo * (2 * CIN);
    const float* W1 = W + (size_t)(oo + TPP) * (2 * CIN);

    float ctr0 = bias[oo], ctr1 = bias[oo + TPP];
    float acc[2][KNN];
    #pragma unroll
    for (int kk = 0; kk < KNN; ++kk) { acc[0][kk] = 0.f; acc[1][kk] = 0.f; }

    for (int c = 0; c < CIN; ++c) {
        float hv = hi[p][c];
        ctr0 += W0[CIN + c] * hv;
        ctr1 += W1[CIN + c] * hv;
    }
    for (int c = 0; c < CIN; ++c) {
        float w0 = W0[c], w1 = W1[c];
        #pragma unroll
        for (int kk = 0; kk < KNN; ++kk) {
            float d = diff[p][kk][c];
            acc[0][kk] += w0 * d;
            acc[1][kk] += w1 * d;
        }
    }

    float m0 = -FLT_MAX, m1 = -FLT_MAX;
    #pragma unroll
    for (int kk = 0; kk < KNN; ++kk) {
        m0 = fmaxf(m0, acc[0][kk] + ctr0);
        m1 = fmaxf(m1, acc[1][kk] + ctr1);
    }
    float r0v = m0 > 0.f ? m0 : 0.2f * m0;
    float r1v = m1 > 0.f ? m1 : 0.2f * m1;
    hout[(size_t)(r0 + p) * FSTR + oo]       = r0v;
    hout[(size_t)(r0 + p) * FSTR + oo + TPP] = r1v;
}

// ---------------------------------------------------------------- final GEMM via MFMA (bf16 hi/lo, 3-term) + col-max
__global__ __launch_bounds__(256) void final_mfma(const float* __restrict__ f,
                                                  const short* __restrict__ wfhi,
                                                  const short* __restrict__ wflo,
                                                  float* __restrict__ partial) {
    constexpr int PLANE = 64 * 64 * 2;
    __shared__ short A[2 * 64 * 64];
    const int t    = threadIdx.x;
    const int mb   = blockIdx.x;
    const int ny   = blockIdx.y;
    const int row0 = mb * 64;
    const int l = t & 63, w = t >> 6, g = l >> 4, cl = l & 15;

    f32x4 acc[4][2];
    #pragma unroll
    for (int mt = 0; mt < 4; ++mt)
        #pragma unroll
        for (int nt = 0; nt < 2; ++nt)
            acc[mt][nt] = (f32x4){0.f, 0.f, 0.f, 0.f};

    char* Ab = (char*)A;
    #pragma unroll 1
    for (int kc = 0; kc < 8; ++kc) {
        for (int u = t; u < 64 * 32; u += 256) {
            int row = u >> 5, cp = u & 31;
            const float* src = &f[(size_t)(row0 + row) * FSTR + kc * 64 + cp * 2];
            float d0 = src[0], d1 = src[1];
            unsigned h0 = f2bf_rne(d0), h1 = f2bf_rne(d1);
            unsigned l0 = __float_as_uint(d0 - bf2f(h0)) >> 16;
            unsigned l1 = __float_as_uint(d1 - bf2f(h1)) >> 16;
            int byte = row * 128 + cp * 4;
            byte ^= ((row & 7) << 4);
            *(unsigned*)(Ab + byte)         = h0 | (h1 << 16);
            *(unsigned*)(Ab + PLANE + byte) = l0 | (l1 << 16);
        }
        __syncthreads();

        short8 bh[2][2], bl[2][2];
        #pragma unroll
        for (int ks = 0; ks < 2; ++ks)
            #pragma unroll
            for (int nt = 0; nt < 2; ++nt) {
                int o = ny * 128 + (w * 2 + nt) * 16 + cl;
                size_t koff = (size_t)o * 512 + kc * 64 + ks * 32 + g * 8;
                bh[ks][nt] = *(const short8*)(wfhi + koff);
                bl[ks][nt] = *(const short8*)(wflo + koff);
            }
        short8 ah[2][4];
        #pragma unroll
        for (int ks = 0; ks < 2; ++ks)
            #pragma unroll
            for (int mt = 0; mt < 4; ++mt) {
                int row  = mt * 16 + cl;
                int byte = row * 128 + (ks * 32 + g * 8) * 2;
                byte ^= ((row & 7) << 4);
                ah[ks][mt] = *(const short8*)(Ab + byte);
            }
        #pragma unroll
        for (int ks = 0; ks < 2; ++ks)
            #pragma unroll
            for (int mt = 0; mt < 4; ++mt)
                #pragma unroll
                for (int nt = 0; nt < 2; ++nt)
                    acc[mt][nt] = __builtin_amdgcn_mfma_f32_16x16x32_bf16(
                        ah[ks][mt], bh[ks][nt], acc[mt][nt], 0, 0, 0);
        #pragma unroll
        for (int ks = 0; ks < 2; ++ks)
            #pragma unroll
            for (int mt = 0; mt < 4; ++mt)
                #pragma unroll
                for (int nt = 0; nt < 2; ++nt)
                    acc[mt][nt] = __builtin_amdgcn_mfma_f32_16x16x32_bf16(
                        ah[ks][mt], bl[ks][nt], acc[mt][nt], 0, 0, 0);
        short8 al[2][4];
        #pragma unroll
        for (int ks = 0; ks < 2; ++ks)
            #pragma unroll
            for (int mt = 0; mt < 4; ++mt) {
                int row  = mt * 16 + cl;
                int byte = row * 128 + (ks * 32 + g * 8) * 2;
                byte ^= ((row & 7) << 4);
                al[ks][mt] = *(const short8*)(Ab + PLANE + byte);
            }
        #pragma unroll
        for (int ks = 0; ks < 2; ++ks)
            #pragma unroll
            for (int mt = 0; mt < 4; ++mt)
                #pragma unroll
                for (int nt = 0; nt < 2; ++nt)
                    acc[mt][nt] = __builtin_amdgcn_mfma_f32_16x16x32_bf16(
                        al[ks][mt], bh[ks][nt], acc[mt][nt], 0, 0, 0);
        __syncthreads();
    }

    #pragma unroll
    for (int nt = 0; nt < 2; ++nt) {
        float pm = -FLT_MAX;
        #pragma unroll
        for (int mt = 0; mt < 4; ++mt) {
            f32x4 v = acc[mt][nt];
            pm = fmaxf(pm, fmaxf(fmaxf(v[0], v[1]), fmaxf(v[2], v[3])));
        }
        pm = fmaxf(pm, __shfl_xor(pm, 16));
        pm = fmaxf(pm, __shfl_xor(pm, 32));
        if (g == 0) {
            int col = ny * 128 + (w * 2 + nt) * 16 + cl;
            partial[(size_t)mb * 1024 + col] = pm;
        }
    }
}

__global__ __launch_bounds__(256) void final_reduce(const float* __restrict__ partial,
                                                    const float* __restrict__ bf,
                                                    float* __restrict__ out) {
    int g = blockIdx.x * 256 + threadIdx.x;
    int b = g >> 10, o = g & 1023;
    float m = -FLT_MAX;
    for (int mb = 0; mb < 32; ++mb)
        m = fmaxf(m, partial[((size_t)(b * 32 + mb)) * 1024 + o]);
    out[g] = m + bf[o];
}

// ---------------------------------------------------------------- launch
extern "C" void kernel_launch(void* const* d_in, const int* in_sizes, int n_in,
                              void* d_out, int out_size, void* d_ws, size_t ws_size,
                              hipStream_t stream) {
    const float* x  = (const float*)d_in[0];
    const float* W0 = (const float*)d_in[1];
    const float* b0 = (const float*)d_in[2];
    const float* W1 = (const float*)d_in[3];
    const float* b1 = (const float*)d_in[4];
    const float* W2 = (const float*)d_in[5];
    const float* b2 = (const float*)d_in[6];
    const float* W3 = (const float*)d_in[7];
    const float* b3 = (const float*)d_in[8];
    const float* Wf = (const float*)d_in[9];
    const float* bf = (const float*)d_in[10];
    (void)in_sizes; (void)n_in; (void)out_size; (void)ws_size;

    char* ws = (char*)d_ws;
    size_t off = 0;
    float* feats = (float*)(ws + off); off += (size_t)BN * FSTR * 4;        // 32 MB
    float* sq    = (float*)(ws + off); off += (size_t)BN * 4;               // 64 KB
    int*   idx   = (int*)  (ws + off); off += (size_t)BN * KNN * 4;         // 1.25 MB
    float* GC    = (float*)(ws + off); off += (size_t)BN * 512 * 4;         // 32 MB
    float* partial = GC;               // alias: GC free when final phase runs
    short* hhi   = (short*)(ws + off); off += (size_t)BN * 128 * 2;         // 4 MB
    short* hlo   = (short*)(ws + off); off += (size_t)BN * 128 * 2;         // 4 MB
    short* ebhi  = (short*)(ws + off); off += (size_t)90112 * 2;
    short* eblo  = (short*)(ws + off); off += (size_t)90112 * 2;
    short* wfhi  = (short*)(ws + off); off += (size_t)1024 * 512 * 2;       // 1 MB
    short* wflo  = (short*)(ws + off); off += (size_t)1024 * 512 * 2;       // 1 MB
    float* gram  = (float*)(ws + off); off += (size_t)4 * NP * NP * 4;      // 64 MB
    short* b1hi = ebhi,         *b1lo = eblo;                               // 128 x 64
    short* b2hi = ebhi + 8192,  *b2lo = eblo + 8192;                        // 256 x 64
    short* b3hi = ebhi + 24576, *b3lo = eblo + 24576;                       // 512 x 128

    // weight preps
    uvprep_kernel<<<16, 256, 0, stream>>>(W1, 64, 64, b1hi, b1lo);
    uvprep_kernel<<<32, 256, 0, stream>>>(W2, 64, 128, b2hi, b2lo);
    uvprep_kernel<<<128, 256, 0, stream>>>(W3, 128, 256, b3hi, b3lo);
    wfprep_kernel<<<2048, 256, 0, stream>>>(Wf, wfhi, wflo);

    // Layer 0: C=3 -> 64 @ feats[0:64]  (fp32 VALU)
    sq_kernel<3><<<BN / 256, 256, 0, stream>>>(x, 3, sq);
    knn_kernel<3><<<BN / 4, 256, 0, stream>>>(x, 3, sq, idx);
    edge_kernel<3, 64, 8><<<BN / 8, 256, 0, stream>>>(x, 3, W0, b0, idx, feats + 0);

    // Layer 1: 64 -> 64 @ feats[64:128]
    sq_kernel<64><<<BN / 256, 256, 0, stream>>>(feats + 0, FSTR, sq);
    hprep_kernel<<<(BN * 64) / 256, 256, 0, stream>>>(feats + 0, FSTR, 64, BN * 64, hhi, hlo);
    for (int grp = 0; grp < 2; ++grp) {
        int g0 = grp * 4 * NP;
        gram_mfma<1><<<dim3(128, 16), 256, 0, stream>>>(feats + 0, FSTR, hhi, hlo, sq, g0, gram);
        select_topk<<<4 * NP / 8, 512, 0, stream>>>(gram, g0, idx);
    }
    gemm_node<1><<<dim3(BN / 64, 1), 256, 0, stream>>>(feats + 0, FSTR, b1hi, b1lo, 128, GC);
    gather_max<64, 4><<<BN / 4, 256, 0, stream>>>(GC, 128, idx, b1, feats + 64);

    // Layer 2: 64 -> 128 @ feats[128:256]
    sq_kernel<64><<<BN / 256, 256, 0, stream>>>(feats + 64, FSTR, sq);
    hprep_kernel<<<(BN * 64) / 256, 256, 0, stream>>>(feats + 64, FSTR, 64, BN * 64, hhi, hlo);
    for (int grp = 0; grp < 2; ++grp) {
        int g0 = grp * 4 * NP;
        gram_mfma<1><<<dim3(128, 16), 256, 0, stream>>>(feats + 64, FSTR, hhi, hlo, sq, g0, gram);
        select_topk<<<4 * NP / 8, 512, 0, stream>>>(gram, g0, idx);
    }
    gemm_node<1><<<dim3(BN / 64, 2), 256, 0, stream>>>(feats + 64, FSTR, b2hi, b2lo, 256, GC);
    gather_max<128, 2><<<BN / 2, 256, 0, stream>>>(GC, 256, idx, b2, feats + 128);

    // Layer 3: 128 -> 256 @ feats[256:512]
    sq_kernel<128><<<BN / 256, 256, 0, stream>>>(feats + 128, FSTR, sq);
    hprep_kernel<<<(BN * 128) / 256, 256, 0, stream>>>(feats + 128, FSTR, 128, BN * 128, hhi, hlo);
    for (int grp = 0; grp < 2; ++grp) {
        int g0 = grp * 4 * NP;
        gram_mfma<2><<<dim3(128, 16), 256, 0, stream>>>(feats + 128, FSTR, hhi, hlo, sq, g0, gram);
        select_topk<<<4 * NP / 8, 512, 0, stream>>>(gram, g0, idx);
    }
    gemm_node<2><<<dim3(BN / 64, 4), 256, 0, stream>>>(feats + 128, FSTR, b3hi, b3lo, 512, GC);
    gather_max<256, 1><<<BN, 256, 0, stream>>>(GC, 512, idx, b3, feats + 256);

    // Final 512 -> 1024 + global max pool (MFMA)
    final_mfma<<<dim3(BN / 64, 8), 256, 0, stream>>>(feats, wfhi, wflo, partial);
    final_reduce<<<32, 256, 0, stream>>>(partial, bf, (float*)d_out);
}